// Round 6
// baseline (540.689 us; speedup 1.0000x reference)
//
#include <hip/hip_runtime.h>
#include <hip/hip_bf16.h>

// Hypergraph conv:  Xp = X@W;  Xe = mean_{v in e} Xp[v];
// Xv[v] = (sum_{e ∋ v} homo[e]*Xe[e]) / (sum_{e ∋ v} homo[e]);  out = rowL2norm(Xp+Xv)
//
// R5 counters: scatter_slab 138us @ 25% HBM, latency-bound; slab prefix table
// cost 32MB writes (hist) + 64MB stream (colscan) + 32MB random reads (scatter).
// v3: global-counter base allocation — hist flushes LDS counts straight into
// tot[bin] (L2-resident atomics, batched ~55/thread); scatter ranks in LDS,
// bin base = atomicAdd(run[bin], cnt) once per present bin (u16 base in LDS:
// requires max segment degree < 65536 — true by huge margin for this data;
// ws-size-gated fallback path has no such assumption).

#define RBINS 32768  // bins per LDS pass, u16-packed -> 64 KB LDS

__device__ __forceinline__ float bf2f(unsigned short u) {
    union { unsigned int i; float f; } x;
    x.i = ((unsigned int)u) << 16;
    return x.f;
}

__device__ __forceinline__ unsigned short f2bf(float f) {
    union { unsigned int i; float ff; } x;
    x.ff = f;
    unsigned int r = x.i + 0x7fff + ((x.i >> 16) & 1);  // round-to-nearest-even
    return (unsigned short)(r >> 16);
}

__device__ __forceinline__ float loadF(const void* p, size_t i, int bf16mode) {
    return bf16mode ? bf2f(((const unsigned short*)p)[i]) : ((const float*)p)[i];
}

__device__ __forceinline__ int loadI(const void* p, size_t i, int i64mode) {
    return i64mode ? ((const int*)p)[2 * i] : ((const int*)p)[i];
}

// ---------------- dtype sniff: flags[0]=floats-are-bf16, flags[1]=indices-are-i64
__global__ void sniff_kernel(const void* X, const void* vtx, int* flags) {
    if (threadIdx.x != 0 || blockIdx.x != 0) return;
    const unsigned short* u = (const unsigned short*)X;
    int sane = 0;
    for (int i = 0; i < 64; ++i) {
        unsigned short lo = u[2 * i];
        int e = (lo >> 7) & 0xFF;
        if (e >= 110 && e <= 137) ++sane;
    }
    flags[0] = (sane >= 32) ? 1 : 0;
    const int* w = (const int*)vtx;
    int zeros = 0;
    for (int i = 0; i < 64; ++i)
        if (w[2 * i + 1] == 0) ++zeros;
    flags[1] = (zeros >= 32) ? 1 : 0;
}

// ---------------- GEMM v2: W in LDS, 4-row unroll; writes Xp f32 + Xpb bf16 ---
__global__ __launch_bounds__(256)
void gemm_kernel(const void* __restrict__ X, const void* __restrict__ W,
                 const int* __restrict__ flags,
                 float* __restrict__ Xp, unsigned short* __restrict__ Xpb, int N) {
    __shared__ float Ws[64 * 64];   // Ws[k*64+c]: lanes hit bank c%32 (2-way, free)
    __shared__ float Xs[16][64];    // 4 waves x 4 rows
    const int bmode = flags[0];
    int tid = threadIdx.x;
    for (int j = tid; j < 4096; j += 256) Ws[j] = loadF(W, j, bmode);
    __syncthreads();
    int lane = tid & 63, w = tid >> 6;
    int wid = (blockIdx.x * 256 + tid) >> 6;
    int nw  = (gridDim.x * 256) >> 6;
    for (int r0 = wid * 4; r0 < N; r0 += nw * 4) {
        if (r0 + 4 <= N) {
            float acc0 = 0.f, acc1 = 0.f, acc2 = 0.f, acc3 = 0.f;
#pragma unroll
            for (int j = 0; j < 4; ++j)
                Xs[w * 4 + j][lane] = loadF(X, (size_t)(r0 + j) * 64 + lane, bmode);
            // same wave writes & reads its own Xs rows: no barrier needed
#pragma unroll
            for (int k4 = 0; k4 < 16; ++k4) {
                float4 x0 = *(const float4*)&Xs[w * 4 + 0][k4 * 4];
                float4 x1 = *(const float4*)&Xs[w * 4 + 1][k4 * 4];
                float4 x2 = *(const float4*)&Xs[w * 4 + 2][k4 * 4];
                float4 x3 = *(const float4*)&Xs[w * 4 + 3][k4 * 4];
#pragma unroll
                for (int kk = 0; kk < 4; ++kk) {
                    float wv = Ws[(k4 * 4 + kk) * 64 + lane];
                    float e0 = (&x0.x)[kk], e1 = (&x1.x)[kk];
                    float e2 = (&x2.x)[kk], e3 = (&x3.x)[kk];
                    acc0 = fmaf(e0, wv, acc0);
                    acc1 = fmaf(e1, wv, acc1);
                    acc2 = fmaf(e2, wv, acc2);
                    acc3 = fmaf(e3, wv, acc3);
                }
            }
            float a[4] = {acc0, acc1, acc2, acc3};
#pragma unroll
            for (int j = 0; j < 4; ++j) {
                Xp[(size_t)(r0 + j) * 64 + lane]  = a[j];
                Xpb[(size_t)(r0 + j) * 64 + lane] = f2bf(a[j]);
            }
        } else {
            for (int r = r0; r < N; ++r) {
                Xs[w * 4][lane] = loadF(X, (size_t)r * 64 + lane, bmode);
                float acc = 0.f;
                for (int k = 0; k < 64; ++k)
                    acc = fmaf(Xs[w * 4][k], Ws[k * 64 + lane], acc);
                Xp[(size_t)r * 64 + lane]  = acc;
                Xpb[(size_t)r * 64 + lane] = f2bf(acc);
            }
        }
    }
}

// ------------- hist: per-(chunk,range) LDS hist -> atomicAdd into tot[bin] ----
__global__ __launch_bounds__(1024, 2)
void hist_slab_kernel(const void* __restrict__ edges,
                      const void* __restrict__ vertex,
                      const int* __restrict__ flags,
                      int* __restrict__ tot,
                      int nnz, int E, int N, int B, int ce, int NRE) {
    __shared__ unsigned int cnt[RBINS / 2];  // u16-packed, 64 KB
    int b = blockIdx.x % B;
    int s = blockIdx.x / B;
    const void* keys; int r0, nb_, base;
    if (s < NRE) { keys = edges;  r0 = s * RBINS;         nb_ = min(RBINS, E - r0); base = r0; }
    else         { keys = vertex; r0 = (s - NRE) * RBINS; nb_ = min(RBINS, N - r0); base = E + r0; }
    int tid = threadIdx.x;
    for (int j = tid; j < RBINS / 2; j += 1024) cnt[j] = 0;
    __syncthreads();
    int imode = flags[1];
    int c0 = b * ce, c1 = min(nnz, c0 + ce);
    for (int i = c0 + tid; i < c1; i += 1024) {
        int k = loadI(keys, i, imode) - r0;
        if ((unsigned)k < (unsigned)nb_)
            atomicAdd(&cnt[k >> 1], (k & 1) ? 0x10000u : 1u);
    }
    __syncthreads();
    // flush present bins (batched independent atomics: ~55/thread, pipelined)
    int np = (nb_ + 1) >> 1;
    for (int j = tid; j < np; j += 1024) {
        unsigned int c = cnt[j];
        int c0_ = (int)(c & 0xffffu), c1_ = (int)(c >> 16);
        if (c0_) atomicAdd(&tot[base + 2 * j], c0_);
        if (c1_) atomicAdd(&tot[base + 2 * j + 1], c1_);
    }
}

// ---------------- parallel exclusive scan, 3 phases (tile = 2048) ------------
__global__ void scan_part_kernel(const int* __restrict__ tot, int* __restrict__ part, int M) {
    int g = blockIdx.x, tid = threadIdx.x;
    int base = g * 2048;
    int sum = 0;
    for (int j = tid; j < 2048; j += 256) {
        int i = base + j;
        sum += (i < M) ? tot[i] : 0;
    }
#pragma unroll
    for (int d = 32; d >= 1; d >>= 1) sum += __shfl_xor(sum, d, 64);
    __shared__ int wsums[4];
    int lane = tid & 63, w = tid >> 6;
    if (lane == 0) wsums[w] = sum;
    __syncthreads();
    if (tid == 0) part[g] = wsums[0] + wsums[1] + wsums[2] + wsums[3];
}

__global__ void scan_root_kernel(int* __restrict__ part, int G,
                                 int* __restrict__ off, int M) {
    // single block of 1024; G <= 1024
    int tid = threadIdx.x, lane = tid & 63, w = tid >> 6;
    int x = (tid < G) ? part[tid] : 0;
    int s = x;
#pragma unroll
    for (int d = 1; d < 64; d <<= 1) {
        int t = __shfl_up(s, d, 64);
        if (lane >= d) s += t;
    }
    __shared__ int ws[16];
    if (lane == 63) ws[w] = s;
    __syncthreads();
    if (w == 0 && lane < 16) {
        int v = ws[lane];
#pragma unroll
        for (int d = 1; d < 16; d <<= 1) {
            int t = __shfl_up(v, d, 64);
            if (lane >= d) v += t;
        }
        ws[lane] = v;
    }
    __syncthreads();
    int excl = s - x + (w > 0 ? ws[w - 1] : 0);
    if (tid < G) part[tid] = excl;
    if (tid == 1023) off[M] = ws[15];  // grand total = 2*NNZ
}

// also re-zeroes tot[] so scatter can reuse it as its running allocator
__global__ void scan_apply_kernel(int* __restrict__ tot, const int* __restrict__ part,
                                  int* __restrict__ off, int M) {
    int g = blockIdx.x, tid = threadIdx.x, lane = tid & 63, w = tid >> 6;
    int base = g * 2048 + tid * 8;
    int e[8]; int s = 0;
#pragma unroll
    for (int j = 0; j < 8; ++j) {
        int i = base + j;
        e[j] = (i < M) ? tot[i] : 0;
        s += e[j];
    }
    int si = s;
#pragma unroll
    for (int d = 1; d < 64; d <<= 1) {
        int t = __shfl_up(si, d, 64);
        if (lane >= d) si += t;
    }
    __shared__ int wsum[4];
    if (lane == 63) wsum[w] = si;
    __syncthreads();
    int wbase = 0;
    for (int ww = 0; ww < w; ++ww) wbase += wsum[ww];
    int run = part[g] + wbase + si - s;
#pragma unroll
    for (int j = 0; j < 8; ++j) {
        int i = base + j;
        if (i < M) { off[i] = run; tot[i] = 0; }
        run += e[j];
    }
}

// -------- scatter: LDS ranks (reg-stash) + per-bin base via atomic alloc ------
#define MAX_IPT 16  // max items per thread: requires ce <= MAX_IPT*1024
__global__ __launch_bounds__(1024, 2)
void scatter_slab_kernel(const void* __restrict__ edges,
                         const void* __restrict__ vertex,
                         const int* __restrict__ flags,
                         int* __restrict__ run, const int* __restrict__ off,
                         int* __restrict__ dest,
                         int nnz, int E, int N, int B, int ce, int NRE) {
    __shared__ unsigned int cnt[RBINS / 2];  // counts, then u16 base_rel
    int b = blockIdx.x % B;
    int s = blockIdx.x / B;
    const void* keys; const void* pay; int r0, nb_, base;
    if (s < NRE) { keys = edges;  pay = vertex; r0 = s * RBINS;         nb_ = min(RBINS, E - r0); base = r0; }
    else         { keys = vertex; pay = edges;  r0 = (s - NRE) * RBINS; nb_ = min(RBINS, N - r0); base = E + r0; }
    int tid = threadIdx.x;
    for (int j = tid; j < RBINS / 2; j += 1024) cnt[j] = 0;
    __syncthreads();
    int imode = flags[1];
    int c0 = b * ce, c1 = min(nnz, c0 + ce);

    // loop1: in-LDS ranks, stashed in registers
    unsigned short rank[MAX_IPT];
    int t = 0;
    for (int i = c0 + tid; i < c1; i += 1024, ++t) {
        int k = loadI(keys, i, imode) - r0;
        if ((unsigned)k < (unsigned)nb_) {
            unsigned int old = atomicAdd(&cnt[k >> 1], (k & 1) ? 0x10000u : 1u);
            rank[t] = (unsigned short)((k & 1) ? (old >> 16) : (old & 0xffffu));
        }
    }
    __syncthreads();

    // loop2: allocate base per present bin; overwrite count slot with base_rel
    // (u16: safe while max segment degree < 65536)
    int np = (nb_ + 1) >> 1;
    for (int j = tid; j < np; j += 1024) {
        unsigned int c = cnt[j];
        unsigned int b0 = 0, b1 = 0;
        int c0_ = (int)(c & 0xffffu), c1_ = (int)(c >> 16);
        if (c0_) b0 = (unsigned int)atomicAdd(&run[base + 2 * j], c0_);
        if (c1_) b1 = (unsigned int)atomicAdd(&run[base + 2 * j + 1], c1_);
        cnt[j] = (b0 & 0xffffu) | (b1 << 16);
    }
    __syncthreads();

    // loop3: re-read keys (L2-hot), read payload, write to final slot
    t = 0;
    for (int i = c0 + tid; i < c1; i += 1024, ++t) {
        int k = loadI(keys, i, imode) - r0;
        if ((unsigned)k < (unsigned)nb_) {
            unsigned int c = cnt[k >> 1];
            int brel = (int)((k & 1) ? (c >> 16) : (c & 0xffffu));
            int pos  = off[base + k] + brel + (int)rank[t];
            dest[pos] = loadI(pay, i, imode);
        }
    }
}

// ---------------- fallback (global-atomic) CSR build -------------------------
__global__ void hist_atomic_kernel(const void* __restrict__ edges,
                                   const void* __restrict__ vertex,
                                   const int* __restrict__ flags,
                                   int* __restrict__ tot, int E, int nnz) {
    int i = blockIdx.x * blockDim.x + threadIdx.x;
    if (i >= nnz) return;
    int imode = flags[1];
    atomicAdd(&tot[loadI(edges, i, imode)], 1);
    atomicAdd(&tot[E + loadI(vertex, i, imode)], 1);
}

__global__ void copy_kernel(const int* __restrict__ src, int* __restrict__ dst, int n) {
    int i = blockIdx.x * blockDim.x + threadIdx.x;
    if (i < n) dst[i] = src[i];
}

__global__ void scatter_atomic_kernel(const void* __restrict__ edges,
                                      const void* __restrict__ vertex,
                                      const int* __restrict__ flags,
                                      int* __restrict__ cur, int* __restrict__ dest,
                                      int E, int nnz) {
    int i = blockIdx.x * blockDim.x + threadIdx.x;
    if (i >= nnz) return;
    int imode = flags[1];
    int e = loadI(edges, i, imode);
    int v = loadI(vertex, i, imode);
    dest[atomicAdd(&cur[e], 1)]     = v;
    dest[atomicAdd(&cur[E + v], 1)] = e;
}

// ---------------- Xe[e,:] = mean over incident vertices of Xpb[v,:] ----------
__global__ void edge_mean_kernel(const unsigned short* __restrict__ Xpb,
                                 const int* __restrict__ off,
                                 const int* __restrict__ sorted,
                                 unsigned short* __restrict__ Xe, int E) {
    int wid  = (blockIdx.x * blockDim.x + threadIdx.x) >> 6;
    int lane = threadIdx.x & 63;
    if (wid >= E) return;
    int start = off[wid], end = off[wid + 1];
    float acc = 0.f;
    int j = start;
    for (; j + 3 < end; j += 4) {
        int v0 = sorted[j], v1 = sorted[j + 1], v2 = sorted[j + 2], v3 = sorted[j + 3];
        float a0 = bf2f(Xpb[(size_t)v0 * 64 + lane]);
        float a1 = bf2f(Xpb[(size_t)v1 * 64 + lane]);
        float a2 = bf2f(Xpb[(size_t)v2 * 64 + lane]);
        float a3 = bf2f(Xpb[(size_t)v3 * 64 + lane]);
        acc += (a0 + a1) + (a2 + a3);
    }
    for (; j < end; ++j) acc += bf2f(Xpb[(size_t)sorted[j] * 64 + lane]);
    float cnt = (float)(end - start);
    Xe[(size_t)wid * 64 + lane] = f2bf(acc / fmaxf(cnt, 1.f));
}

// ---- out[v,:] = rowL2norm( Xp[v,:] + (sum homo[e]*Xe[e,:]) / (sum homo[e]) )
__global__ void vertex_out_kernel(const float* __restrict__ Xp,
                                  const unsigned short* __restrict__ Xe,
                                  const int* __restrict__ off,
                                  const int* __restrict__ sorted,
                                  const void* __restrict__ homo,
                                  const int* __restrict__ flags,
                                  float* __restrict__ out, int E, int N) {
    int wid  = (blockIdx.x * blockDim.x + threadIdx.x) >> 6;
    int lane = threadIdx.x & 63;
    if (wid >= N) return;
    int bmode = flags[0];
    int start = off[E + wid], end = off[E + wid + 1];
    float acc = 0.f, hsum = 0.f;
    int j = start;
    for (; j + 3 < end; j += 4) {
        int e0 = sorted[j], e1 = sorted[j + 1], e2 = sorted[j + 2], e3 = sorted[j + 3];
        float h0 = loadF(homo, e0, bmode), h1 = loadF(homo, e1, bmode);
        float h2 = loadF(homo, e2, bmode), h3 = loadF(homo, e3, bmode);
        float a0 = bf2f(Xe[(size_t)e0 * 64 + lane]);
        float a1 = bf2f(Xe[(size_t)e1 * 64 + lane]);
        float a2 = bf2f(Xe[(size_t)e2 * 64 + lane]);
        float a3 = bf2f(Xe[(size_t)e3 * 64 + lane]);
        acc  += h0 * a0 + h1 * a1 + h2 * a2 + h3 * a3;
        hsum += (h0 + h1) + (h2 + h3);
    }
    for (; j < end; ++j) {
        int e = sorted[j];
        float h = loadF(homo, e, bmode);
        acc  += h * bf2f(Xe[(size_t)e * 64 + lane]);
        hsum += h;
    }
    float xv  = (end > start && hsum > 0.f) ? acc / hsum : 0.f;
    float res = Xp[(size_t)wid * 64 + lane] + xv;

    float ss = res * res;
#pragma unroll
    for (int d = 32; d >= 1; d >>= 1) ss += __shfl_xor(ss, d, 64);
    float rn    = sqrtf(ss);
    float scale = (rn > 0.f) ? 1.f / fmaxf(rn, 1e-30f) : 0.f;
    out[(size_t)wid * 64 + lane] = res * scale;
}

extern "C" void kernel_launch(void* const* d_in, const int* in_sizes, int n_in,
                              void* d_out, int out_size, void* d_ws, size_t ws_size,
                              hipStream_t stream) {
    const void* X      = d_in[0];
    const void* W      = d_in[1];
    const void* homo   = d_in[2];
    const void* vertex = d_in[3];
    const void* edges  = d_in[4];
    float* out = (float*)d_out;

    const int N   = in_sizes[0] / 64;
    const int E   = in_sizes[2];
    const int NNZ = in_sizes[3];
    const int M   = E + N;

    const int B   = 128;                      // chunks; ce <= 16*1024 for reg stash
    const int ce  = (NNZ + B - 1) / B;
    const int NRE = (E + RBINS - 1) / RBINS;
    const int NRV = (N + RBINS - 1) / RBINS;
    const int G   = (M + 2047) / 2048;        // scan tiles (<= 1024)

    char*  ws = (char*)d_ws;
    size_t o  = 0;
    auto alloc = [&](size_t bytes) -> void* {
        void* p = ws + o;
        o += (bytes + 255) & ~(size_t)255;
        return p;
    };
    int*            flags = (int*)alloc(2 * 4);
    int*            off   = (int*)alloc((size_t)(M + 1) * 4);   // conc offsets
    int*            tot   = (int*)alloc((size_t)M * 4);         // totals, then run
    int*            part  = (int*)alloc((size_t)(G + 1) * 4);
    int*            sorted= (int*)alloc((size_t)2 * NNZ * 4);   // [0,NNZ)=v-by-e, [NNZ,2NNZ)=e-by-v
    float*          Xp    = (float*)alloc((size_t)N * 64 * 4);
    unsigned short* Xpb   = (unsigned short*)alloc((size_t)N * 64 * 2);
    unsigned short* Xe    = (unsigned short*)alloc((size_t)E * 64 * 2);
    size_t o_common = o;
    bool fast = (o <= ws_size) && (ce <= MAX_IPT * 1024) && (G <= 1024);
    (void)n_in; (void)out_size;

    sniff_kernel<<<1, 64, 0, stream>>>(X, vertex, flags);
    gemm_kernel<<<512, 256, 0, stream>>>(X, W, flags, Xp, Xpb, N);

    hipMemsetAsync(tot, 0, (size_t)M * 4, stream);
    if (fast) {
        hist_slab_kernel<<<B * (NRE + NRV), 1024, 0, stream>>>(
            edges, vertex, flags, tot, NNZ, E, N, B, ce, NRE);
        scan_part_kernel<<<G, 256, 0, stream>>>(tot, part, M);
        scan_root_kernel<<<1, 1024, 0, stream>>>(part, G, off, M);
        scan_apply_kernel<<<G, 256, 0, stream>>>(tot, part, off, M);  // zeroes tot
        scatter_slab_kernel<<<B * (NRE + NRV), 1024, 0, stream>>>(
            edges, vertex, flags, tot, off, sorted, NNZ, E, N, B, ce, NRE);
    } else {
        o = o_common;
        int* cur = (int*)alloc((size_t)M * 4);
        int nb = (NNZ + 255) / 256;
        hist_atomic_kernel<<<nb, 256, 0, stream>>>(edges, vertex, flags, tot, E, NNZ);
        scan_part_kernel<<<G, 256, 0, stream>>>(tot, part, M);
        scan_root_kernel<<<1, 1024, 0, stream>>>(part, G, off, M);
        scan_apply_kernel<<<G, 256, 0, stream>>>(tot, part, off, M);
        copy_kernel<<<(M + 255) / 256, 256, 0, stream>>>(off, cur, M);
        scatter_atomic_kernel<<<nb, 256, 0, stream>>>(edges, vertex, flags, cur, sorted, E, NNZ);
    }

    edge_mean_kernel<<<(E + 3) / 4, 256, 0, stream>>>(Xpb, off, sorted, Xe, E);
    vertex_out_kernel<<<(N + 3) / 4, 256, 0, stream>>>(Xp, Xe, off, sorted,
                                                       homo, flags, out, E, N);
}

// Round 7
// 352.788 us; speedup vs baseline: 1.5326x; 1.5326x over previous
//
#include <hip/hip_runtime.h>
#include <hip/hip_bf16.h>

// Hypergraph conv:  Xp = X@W;  Xe = mean_{v in e} Xp[v];
// Xv[v] = (sum_{e ∋ v} homo[e]*Xe[e]) / (sum_{e ∋ v} homo[e]);  out = rowL2norm(Xp+Xv)
//
// R6 lesson: fine-bin chunk-partitioned scatter bounces dest lines across XCDs
// (WRITE 202MB for 16MB of data). v4: two-level bucket sort. Coarse buckets
// (128 edges / 512 vertices) allocated contiguously; pass2 gives each bucket
// to ONE block, so final scatter writes are block-owned (no line bouncing).

#define SE_LOG 7          // edges per bucket = 128
#define SV_LOG 9          // vertices per bucket = 512
#define MAXB   2048       // max coarse buckets per side (LDS counters)
#define CH     16384      // incidences per pass-1 block

__device__ __forceinline__ float bf2f(unsigned short u) {
    union { unsigned int i; float f; } x;
    x.i = ((unsigned int)u) << 16;
    return x.f;
}

__device__ __forceinline__ unsigned short f2bf(float f) {
    union { unsigned int i; float ff; } x;
    x.ff = f;
    unsigned int r = x.i + 0x7fff + ((x.i >> 16) & 1);
    return (unsigned short)(r >> 16);
}

__device__ __forceinline__ float loadF(const void* p, size_t i, int bf16mode) {
    return bf16mode ? bf2f(((const unsigned short*)p)[i]) : ((const float*)p)[i];
}

__device__ __forceinline__ int loadI(const void* p, size_t i, int i64mode) {
    return i64mode ? ((const int*)p)[2 * i] : ((const int*)p)[i];
}

// ---------------- dtype sniff: flags[0]=floats-are-bf16, flags[1]=indices-are-i64
__global__ void sniff_kernel(const void* X, const void* vtx, int* flags) {
    if (threadIdx.x != 0 || blockIdx.x != 0) return;
    const unsigned short* u = (const unsigned short*)X;
    int sane = 0;
    for (int i = 0; i < 64; ++i) {
        unsigned short lo = u[2 * i];
        int e = (lo >> 7) & 0xFF;
        if (e >= 110 && e <= 137) ++sane;
    }
    flags[0] = (sane >= 32) ? 1 : 0;
    const int* w = (const int*)vtx;
    int zeros = 0;
    for (int i = 0; i < 64; ++i)
        if (w[2 * i + 1] == 0) ++zeros;
    flags[1] = (zeros >= 32) ? 1 : 0;
}

// ---------------- GEMM: W in LDS, 4-row unroll; writes Xp f32 + Xpb bf16 ------
__global__ __launch_bounds__(256)
void gemm_kernel(const void* __restrict__ X, const void* __restrict__ W,
                 const int* __restrict__ flags,
                 float* __restrict__ Xp, unsigned short* __restrict__ Xpb, int N) {
    __shared__ float Ws[64 * 64];
    __shared__ float Xs[16][64];
    const int bmode = flags[0];
    int tid = threadIdx.x;
    for (int j = tid; j < 4096; j += 256) Ws[j] = loadF(W, j, bmode);
    __syncthreads();
    int lane = tid & 63, w = tid >> 6;
    int wid = (blockIdx.x * 256 + tid) >> 6;
    int nw  = (gridDim.x * 256) >> 6;
    for (int r0 = wid * 4; r0 < N; r0 += nw * 4) {
        if (r0 + 4 <= N) {
            float acc0 = 0.f, acc1 = 0.f, acc2 = 0.f, acc3 = 0.f;
#pragma unroll
            for (int j = 0; j < 4; ++j)
                Xs[w * 4 + j][lane] = loadF(X, (size_t)(r0 + j) * 64 + lane, bmode);
#pragma unroll
            for (int k4 = 0; k4 < 16; ++k4) {
                float4 x0 = *(const float4*)&Xs[w * 4 + 0][k4 * 4];
                float4 x1 = *(const float4*)&Xs[w * 4 + 1][k4 * 4];
                float4 x2 = *(const float4*)&Xs[w * 4 + 2][k4 * 4];
                float4 x3 = *(const float4*)&Xs[w * 4 + 3][k4 * 4];
#pragma unroll
                for (int kk = 0; kk < 4; ++kk) {
                    float wv = Ws[(k4 * 4 + kk) * 64 + lane];
                    acc0 = fmaf((&x0.x)[kk], wv, acc0);
                    acc1 = fmaf((&x1.x)[kk], wv, acc1);
                    acc2 = fmaf((&x2.x)[kk], wv, acc2);
                    acc3 = fmaf((&x3.x)[kk], wv, acc3);
                }
            }
            float a[4] = {acc0, acc1, acc2, acc3};
#pragma unroll
            for (int j = 0; j < 4; ++j) {
                Xp[(size_t)(r0 + j) * 64 + lane]  = a[j];
                Xpb[(size_t)(r0 + j) * 64 + lane] = f2bf(a[j]);
            }
        } else {
            for (int r = r0; r < N; ++r) {
                Xs[w * 4][lane] = loadF(X, (size_t)r * 64 + lane, bmode);
                float acc = 0.f;
                for (int k = 0; k < 64; ++k)
                    acc = fmaf(Xs[w * 4][k], Ws[k * 64 + lane], acc);
                Xp[(size_t)r * 64 + lane]  = acc;
                Xpb[(size_t)r * 64 + lane] = f2bf(acc);
            }
        }
    }
}

// ---------------- coarse-bucket histogram (tiny LDS, high occupancy) ----------
__global__ __launch_bounds__(1024)
void bhist_kernel(const void* __restrict__ edges, const void* __restrict__ vertex,
                  const int* __restrict__ flags, int* __restrict__ btot,
                  int nnz, int NBE, int NBV, int GC) {
    __shared__ int cnt[MAXB];
    int blk  = blockIdx.x;
    int side = (blk >= GC) ? 1 : 0;
    int b    = side ? blk - GC : blk;
    const void* keys = side ? vertex : edges;
    int sblog = side ? SV_LOG : SE_LOG;
    int nb    = side ? NBV : NBE;
    int bas   = side ? NBE : 0;
    int tid = threadIdx.x;
    for (int j = tid; j < nb; j += 1024) cnt[j] = 0;
    __syncthreads();
    int imode = flags[1];
    int c0 = b * CH, c1 = min(nnz, c0 + CH);
    for (int i = c0 + tid; i < c1; i += 1024)
        atomicAdd(&cnt[loadI(keys, i, imode) >> sblog], 1);
    __syncthreads();
    for (int j = tid; j < nb; j += 1024)
        if (cnt[j]) atomicAdd(&btot[bas + j], cnt[j]);
}

// ---------------- tiny scan over bucket totals -> bases + cursors ------------
__global__ void bscan_kernel(const int* __restrict__ btot, int* __restrict__ bbase,
                             int* __restrict__ bcur, int NBT) {
    __shared__ int wsum[16];
    __shared__ int carry_s;
    int tid = threadIdx.x, lane = tid & 63, w = tid >> 6;
    if (tid == 0) carry_s = 0;
    __syncthreads();
    for (int base = 0; base < NBT; base += 1024) {
        int i = base + tid;
        int x = (i < NBT) ? btot[i] : 0;
        int s = x;
#pragma unroll
        for (int d = 1; d < 64; d <<= 1) {
            int t = __shfl_up(s, d, 64);
            if (lane >= d) s += t;
        }
        if (lane == 63) wsum[w] = s;
        __syncthreads();
        if (w == 0 && lane < 16) {
            int v = wsum[lane];
#pragma unroll
            for (int d = 1; d < 16; d <<= 1) {
                int t = __shfl_up(v, d, 64);
                if (lane >= d) v += t;
            }
            wsum[lane] = v;
        }
        __syncthreads();
        int carry = carry_s;
        int excl  = carry + (w > 0 ? wsum[w - 1] : 0) + s - x;
        if (i < NBT) { bbase[i] = excl; bcur[i] = excl; }
        __syncthreads();
        if (tid == 1023) carry_s = carry + wsum[15];
        __syncthreads();
    }
    if (tid == 0) bbase[NBT] = carry_s;
}

// ------- pass1: chunk -> coarse buckets, packed (local_bin<<psh | payload) ----
__global__ __launch_bounds__(1024)
void bscatter_kernel(const void* __restrict__ edges, const void* __restrict__ vertex,
                     const int* __restrict__ flags, int* __restrict__ bcur,
                     int* __restrict__ buck, int nnz, int NBE, int NBV, int GC,
                     int bitsN, int bitsE) {
    __shared__ int cnt[MAXB];
    __shared__ int gb[MAXB];
    int blk  = blockIdx.x;
    int side = (blk >= GC) ? 1 : 0;
    int b    = side ? blk - GC : blk;
    const void* keys = side ? vertex : edges;
    const void* pay  = side ? edges  : vertex;
    int sblog = side ? SV_LOG : SE_LOG;
    int psh   = side ? bitsE : bitsN;
    int nb    = side ? NBV : NBE;
    int bas   = side ? NBE : 0;
    int tid = threadIdx.x;
    for (int j = tid; j < nb; j += 1024) cnt[j] = 0;
    __syncthreads();
    int imode = flags[1];
    int c0 = b * CH, c1 = min(nnz, c0 + CH);
    for (int i = c0 + tid; i < c1; i += 1024)
        atomicAdd(&cnt[loadI(keys, i, imode) >> sblog], 1);
    __syncthreads();
    for (int j = tid; j < nb; j += 1024) {
        int c = cnt[j];
        gb[j] = c ? atomicAdd(&bcur[bas + j], c) : 0;
        cnt[j] = 0;
    }
    __syncthreads();
    int lmask = (1 << sblog) - 1;
    for (int i = c0 + tid; i < c1; i += 1024) {
        int k   = loadI(keys, i, imode);
        int bkt = k >> sblog;
        int r   = atomicAdd(&cnt[bkt], 1);
        buck[gb[bkt] + r] = ((k & lmask) << psh) | loadI(pay, i, imode);
    }
}

// ------- pass2: one block per bucket: local count/scan -> off[] + dest[] ------
__global__ __launch_bounds__(1024)
void bfinal_kernel(const int* __restrict__ buck, const int* __restrict__ bbase,
                   int* __restrict__ off, int* __restrict__ dest,
                   int NBE, int NBV, int E, int N, int bitsN, int bitsE) {
    __shared__ int cnt[1 << SV_LOG];
    __shared__ int sexc[1 << SV_LOG];
    __shared__ int wsum[16];
    int g    = blockIdx.x;
    int side = (g >= NBE) ? 1 : 0;
    int b    = side ? g - NBE : g;
    int sblog = side ? SV_LOG : SE_LOG;
    int psh   = side ? bitsE : bitsN;
    int pmask = (1 << psh) - 1;
    int nside = side ? N : E;
    int bin0  = b << sblog;
    int nbins = min(1 << sblog, nside - bin0);
    int goff0 = (side ? E : 0) + bin0;
    int s0 = bbase[g], s1 = bbase[g + 1], size = s1 - s0;
    int tid = threadIdx.x, lane = tid & 63, w = tid >> 6;
    for (int j = tid; j < nbins; j += 1024) cnt[j] = 0;
    __syncthreads();
    for (int j = tid; j < size; j += 1024)
        atomicAdd(&cnt[buck[s0 + j] >> psh], 1);
    __syncthreads();
    {   // exclusive scan over nbins (<= 512 < 1024)
        int x = (tid < nbins) ? cnt[tid] : 0;
        int s = x;
#pragma unroll
        for (int d = 1; d < 64; d <<= 1) {
            int t = __shfl_up(s, d, 64);
            if (lane >= d) s += t;
        }
        if (lane == 63) wsum[w] = s;
        __syncthreads();
        if (w == 0 && lane < 16) {
            int v = wsum[lane];
#pragma unroll
            for (int d = 1; d < 16; d <<= 1) {
                int t = __shfl_up(v, d, 64);
                if (lane >= d) v += t;
            }
            wsum[lane] = v;
        }
        __syncthreads();
        int excl = s - x + (w > 0 ? wsum[w - 1] : 0);
        if (tid < nbins) { sexc[tid] = excl; off[goff0 + tid] = s0 + excl; }
    }
    if (side == 1 && b == NBV - 1 && tid == 0) off[E + N] = s1;
    __syncthreads();
    for (int j = tid; j < nbins; j += 1024) cnt[j] = sexc[j];
    __syncthreads();
    for (int j = tid; j < size; j += 1024) {
        int p = buck[s0 + j];
        int r = atomicAdd(&cnt[p >> psh], 1);
        dest[s0 + r] = p & pmask;   // block-owned region: L2-absorbed, no bouncing
    }
}

// ---------------- fallback (global-atomic) CSR build -------------------------
__global__ void hist_atomic_kernel(const void* __restrict__ edges,
                                   const void* __restrict__ vertex,
                                   const int* __restrict__ flags,
                                   int* __restrict__ tot, int E, int nnz) {
    int i = blockIdx.x * blockDim.x + threadIdx.x;
    if (i >= nnz) return;
    int imode = flags[1];
    atomicAdd(&tot[loadI(edges, i, imode)], 1);
    atomicAdd(&tot[E + loadI(vertex, i, imode)], 1);
}

__global__ void scan_part_kernel(const int* __restrict__ tot, int* __restrict__ part, int M) {
    int g = blockIdx.x, tid = threadIdx.x;
    int base = g * 2048;
    int sum = 0;
    for (int j = tid; j < 2048; j += 256) {
        int i = base + j;
        sum += (i < M) ? tot[i] : 0;
    }
#pragma unroll
    for (int d = 32; d >= 1; d >>= 1) sum += __shfl_xor(sum, d, 64);
    __shared__ int wsums[4];
    int lane = tid & 63, w = tid >> 6;
    if (lane == 0) wsums[w] = sum;
    __syncthreads();
    if (tid == 0) part[g] = wsums[0] + wsums[1] + wsums[2] + wsums[3];
}

__global__ void scan_root_kernel(int* __restrict__ part, int G,
                                 int* __restrict__ off, int M) {
    int tid = threadIdx.x, lane = tid & 63, w = tid >> 6;
    int x = (tid < G) ? part[tid] : 0;
    int s = x;
#pragma unroll
    for (int d = 1; d < 64; d <<= 1) {
        int t = __shfl_up(s, d, 64);
        if (lane >= d) s += t;
    }
    __shared__ int ws[16];
    if (lane == 63) ws[w] = s;
    __syncthreads();
    if (w == 0 && lane < 16) {
        int v = ws[lane];
#pragma unroll
        for (int d = 1; d < 16; d <<= 1) {
            int t = __shfl_up(v, d, 64);
            if (lane >= d) v += t;
        }
        ws[lane] = v;
    }
    __syncthreads();
    int excl = s - x + (w > 0 ? ws[w - 1] : 0);
    if (tid < G) part[tid] = excl;
    if (tid == 1023) off[M] = ws[15];
}

__global__ void scan_apply_kernel(int* __restrict__ tot, const int* __restrict__ part,
                                  int* __restrict__ off, int M) {
    int g = blockIdx.x, tid = threadIdx.x, lane = tid & 63, w = tid >> 6;
    int base = g * 2048 + tid * 8;
    int e[8]; int s = 0;
#pragma unroll
    for (int j = 0; j < 8; ++j) {
        int i = base + j;
        e[j] = (i < M) ? tot[i] : 0;
        s += e[j];
    }
    int si = s;
#pragma unroll
    for (int d = 1; d < 64; d <<= 1) {
        int t = __shfl_up(si, d, 64);
        if (lane >= d) si += t;
    }
    __shared__ int wsum[4];
    if (lane == 63) wsum[w] = si;
    __syncthreads();
    int wbase = 0;
    for (int ww = 0; ww < w; ++ww) wbase += wsum[ww];
    int run = part[g] + wbase + si - s;
#pragma unroll
    for (int j = 0; j < 8; ++j) {
        int i = base + j;
        if (i < M) off[i] = run;
        run += e[j];
    }
}

__global__ void copy_kernel(const int* __restrict__ src, int* __restrict__ dst, int n) {
    int i = blockIdx.x * blockDim.x + threadIdx.x;
    if (i < n) dst[i] = src[i];
}

__global__ void scatter_atomic_kernel(const void* __restrict__ edges,
                                      const void* __restrict__ vertex,
                                      const int* __restrict__ flags,
                                      int* __restrict__ cur, int* __restrict__ dest,
                                      int E, int nnz) {
    int i = blockIdx.x * blockDim.x + threadIdx.x;
    if (i >= nnz) return;
    int imode = flags[1];
    int e = loadI(edges, i, imode);
    int v = loadI(vertex, i, imode);
    dest[atomicAdd(&cur[e], 1)]     = v;
    dest[atomicAdd(&cur[E + v], 1)] = e;
}

// ---------------- Xe[e,:] = mean over incident vertices of Xpb[v,:] ----------
__global__ void edge_mean_kernel(const unsigned short* __restrict__ Xpb,
                                 const int* __restrict__ off,
                                 const int* __restrict__ sorted,
                                 unsigned short* __restrict__ Xe, int E) {
    int wid  = (blockIdx.x * blockDim.x + threadIdx.x) >> 6;
    int lane = threadIdx.x & 63;
    if (wid >= E) return;
    int start = off[wid], end = off[wid + 1];
    float acc = 0.f;
    int j = start;
    for (; j + 3 < end; j += 4) {
        int v0 = sorted[j], v1 = sorted[j + 1], v2 = sorted[j + 2], v3 = sorted[j + 3];
        float a0 = bf2f(Xpb[(size_t)v0 * 64 + lane]);
        float a1 = bf2f(Xpb[(size_t)v1 * 64 + lane]);
        float a2 = bf2f(Xpb[(size_t)v2 * 64 + lane]);
        float a3 = bf2f(Xpb[(size_t)v3 * 64 + lane]);
        acc += (a0 + a1) + (a2 + a3);
    }
    for (; j < end; ++j) acc += bf2f(Xpb[(size_t)sorted[j] * 64 + lane]);
    float cnt = (float)(end - start);
    Xe[(size_t)wid * 64 + lane] = f2bf(acc / fmaxf(cnt, 1.f));
}

// ---- out[v,:] = rowL2norm( Xp[v,:] + (sum homo[e]*Xe[e,:]) / (sum homo[e]) )
__global__ void vertex_out_kernel(const float* __restrict__ Xp,
                                  const unsigned short* __restrict__ Xe,
                                  const int* __restrict__ off,
                                  const int* __restrict__ sorted,
                                  const void* __restrict__ homo,
                                  const int* __restrict__ flags,
                                  float* __restrict__ out, int E, int N) {
    int wid  = (blockIdx.x * blockDim.x + threadIdx.x) >> 6;
    int lane = threadIdx.x & 63;
    if (wid >= N) return;
    int bmode = flags[0];
    int start = off[E + wid], end = off[E + wid + 1];
    float acc = 0.f, hsum = 0.f;
    int j = start;
    for (; j + 3 < end; j += 4) {
        int e0 = sorted[j], e1 = sorted[j + 1], e2 = sorted[j + 2], e3 = sorted[j + 3];
        float h0 = loadF(homo, e0, bmode), h1 = loadF(homo, e1, bmode);
        float h2 = loadF(homo, e2, bmode), h3 = loadF(homo, e3, bmode);
        float a0 = bf2f(Xe[(size_t)e0 * 64 + lane]);
        float a1 = bf2f(Xe[(size_t)e1 * 64 + lane]);
        float a2 = bf2f(Xe[(size_t)e2 * 64 + lane]);
        float a3 = bf2f(Xe[(size_t)e3 * 64 + lane]);
        acc  += h0 * a0 + h1 * a1 + h2 * a2 + h3 * a3;
        hsum += (h0 + h1) + (h2 + h3);
    }
    for (; j < end; ++j) {
        int e = sorted[j];
        float h = loadF(homo, e, bmode);
        acc  += h * bf2f(Xe[(size_t)e * 64 + lane]);
        hsum += h;
    }
    float xv  = (end > start && hsum > 0.f) ? acc / hsum : 0.f;
    float res = Xp[(size_t)wid * 64 + lane] + xv;

    float ss = res * res;
#pragma unroll
    for (int d = 32; d >= 1; d >>= 1) ss += __shfl_xor(ss, d, 64);
    float rn    = sqrtf(ss);
    float scale = (rn > 0.f) ? 1.f / fmaxf(rn, 1e-30f) : 0.f;
    out[(size_t)wid * 64 + lane] = res * scale;
}

static inline int ceil_bits(int n) {
    int v = n - 1;
    if (v < 1) v = 1;
    int b = 0;
    while ((1 << b) <= v) ++b;
    return b;
}

extern "C" void kernel_launch(void* const* d_in, const int* in_sizes, int n_in,
                              void* d_out, int out_size, void* d_ws, size_t ws_size,
                              hipStream_t stream) {
    const void* X      = d_in[0];
    const void* W      = d_in[1];
    const void* homo   = d_in[2];
    const void* vertex = d_in[3];
    const void* edges  = d_in[4];
    float* out = (float*)d_out;

    const int N   = in_sizes[0] / 64;
    const int E   = in_sizes[2];
    const int NNZ = in_sizes[3];
    const int M   = E + N;

    const int NBE = (E + (1 << SE_LOG) - 1) >> SE_LOG;
    const int NBV = (N + (1 << SV_LOG) - 1) >> SV_LOG;
    const int NBT = NBE + NBV;
    const int GC  = (NNZ + CH - 1) / CH;
    const int bitsN = ceil_bits(N);
    const int bitsE = ceil_bits(E);
    const int G   = (M + 2047) / 2048;  // fallback scan tiles

    char*  ws = (char*)d_ws;
    size_t o  = 0;
    auto alloc = [&](size_t bytes) -> void* {
        void* p = ws + o;
        o += (bytes + 255) & ~(size_t)255;
        return p;
    };
    int*            flags = (int*)alloc(2 * 4);
    int*            off   = (int*)alloc((size_t)(M + 1) * 4);
    int*            bbase = (int*)alloc((size_t)(NBT + 1) * 4);
    int*            bcur  = (int*)alloc((size_t)NBT * 4);
    int*            btot  = (int*)alloc((size_t)NBT * 4);
    int*            buck  = (int*)alloc((size_t)2 * NNZ * 4);
    int*            sorted= (int*)alloc((size_t)2 * NNZ * 4);
    float*          Xp    = (float*)alloc((size_t)N * 64 * 4);
    unsigned short* Xpb   = (unsigned short*)alloc((size_t)N * 64 * 2);
    unsigned short* Xe    = (unsigned short*)alloc((size_t)E * 64 * 2);
    size_t o_common = o;
    bool fast = (o <= ws_size) && NBE <= MAXB && NBV <= MAXB &&
                (SE_LOG + bitsN <= 32) && (SV_LOG + bitsE <= 32) && G <= 1024;
    (void)n_in; (void)out_size;

    sniff_kernel<<<1, 64, 0, stream>>>(X, vertex, flags);
    gemm_kernel<<<512, 256, 0, stream>>>(X, W, flags, Xp, Xpb, N);

    if (fast) {
        hipMemsetAsync(btot, 0, (size_t)NBT * 4, stream);
        bhist_kernel<<<2 * GC, 1024, 0, stream>>>(edges, vertex, flags, btot,
                                                  NNZ, NBE, NBV, GC);
        bscan_kernel<<<1, 1024, 0, stream>>>(btot, bbase, bcur, NBT);
        bscatter_kernel<<<2 * GC, 1024, 0, stream>>>(edges, vertex, flags, bcur,
                                                     buck, NNZ, NBE, NBV, GC,
                                                     bitsN, bitsE);
        bfinal_kernel<<<NBT, 1024, 0, stream>>>(buck, bbase, off, sorted,
                                                NBE, NBV, E, N, bitsN, bitsE);
    } else {
        o = o_common;
        int* tot  = (int*)alloc((size_t)M * 4);
        int* part = (int*)alloc((size_t)(G + 1) * 4);
        int* cur  = (int*)alloc((size_t)M * 4);
        hipMemsetAsync(tot, 0, (size_t)M * 4, stream);
        int nb = (NNZ + 255) / 256;
        hist_atomic_kernel<<<nb, 256, 0, stream>>>(edges, vertex, flags, tot, E, NNZ);
        scan_part_kernel<<<G, 256, 0, stream>>>(tot, part, M);
        scan_root_kernel<<<1, 1024, 0, stream>>>(part, G, off, M);
        scan_apply_kernel<<<G, 256, 0, stream>>>(tot, part, off, M);
        copy_kernel<<<(M + 255) / 256, 256, 0, stream>>>(off, cur, M);
        scatter_atomic_kernel<<<nb, 256, 0, stream>>>(edges, vertex, flags, cur, sorted, E, NNZ);
    }

    edge_mean_kernel<<<(E + 3) / 4, 256, 0, stream>>>(Xpb, off, sorted, Xe, E);
    vertex_out_kernel<<<(N + 3) / 4, 256, 0, stream>>>(Xp, Xe, off, sorted,
                                                       homo, flags, out, E, N);
}

// Round 8
// 313.471 us; speedup vs baseline: 1.7248x; 1.1254x over previous
//
#include <hip/hip_runtime.h>
#include <hip/hip_bf16.h>

// Hypergraph conv:  Xp = X@W;  Xe = mean_{v in e} Xp[v];
// Xv[v] = (sum_{e ∋ v} homo[e]*Xe[e]) / (sum_{e ∋ v} homo[e]);  out = rowL2norm(Xp+Xv)
//
// R7 counters: vertex_out 102us @ VALUBusy 50%, HBM 9% -> issue/latency bound
// on per-incidence instruction stream. R8: gather kernels process 4 incidences
// per wave-instruction (4 groups of 16 lanes, 4 channels/lane via uint2 loads
// of bf16 rows); homo pre-converted to f32; 32-bit gather offsets.
// Sort pipeline (two-level bucket sort, R7) unchanged.

#define SE_LOG 7          // edges per bucket = 128
#define SV_LOG 9          // vertices per bucket = 512
#define MAXB   2048       // max coarse buckets per side (LDS counters)
#define CH     16384      // incidences per pass-1 block

__device__ __forceinline__ float bf2f(unsigned short u) {
    union { unsigned int i; float f; } x;
    x.i = ((unsigned int)u) << 16;
    return x.f;
}

__device__ __forceinline__ float bflo(unsigned int u) {
    union { unsigned int i; float f; } x;
    x.i = u << 16;
    return x.f;
}

__device__ __forceinline__ float bfhi(unsigned int u) {
    union { unsigned int i; float f; } x;
    x.i = u & 0xffff0000u;
    return x.f;
}

__device__ __forceinline__ unsigned short f2bf(float f) {
    union { unsigned int i; float ff; } x;
    x.ff = f;
    unsigned int r = x.i + 0x7fff + ((x.i >> 16) & 1);
    return (unsigned short)(r >> 16);
}

__device__ __forceinline__ float loadF(const void* p, size_t i, int bf16mode) {
    return bf16mode ? bf2f(((const unsigned short*)p)[i]) : ((const float*)p)[i];
}

__device__ __forceinline__ int loadI(const void* p, size_t i, int i64mode) {
    return i64mode ? ((const int*)p)[2 * i] : ((const int*)p)[i];
}

// ---------------- dtype sniff: flags[0]=floats-are-bf16, flags[1]=indices-are-i64
__global__ void sniff_kernel(const void* X, const void* vtx, int* flags) {
    if (threadIdx.x != 0 || blockIdx.x != 0) return;
    const unsigned short* u = (const unsigned short*)X;
    int sane = 0;
    for (int i = 0; i < 64; ++i) {
        unsigned short lo = u[2 * i];
        int e = (lo >> 7) & 0xFF;
        if (e >= 110 && e <= 137) ++sane;
    }
    flags[0] = (sane >= 32) ? 1 : 0;
    const int* w = (const int*)vtx;
    int zeros = 0;
    for (int i = 0; i < 64; ++i)
        if (w[2 * i + 1] == 0) ++zeros;
    flags[1] = (zeros >= 32) ? 1 : 0;
}

// ---------------- homo -> f32 (kills per-incidence dtype select) -------------
__global__ void homof_kernel(const void* __restrict__ homo,
                             const int* __restrict__ flags,
                             float* __restrict__ homof, int E) {
    int i = blockIdx.x * blockDim.x + threadIdx.x;
    if (i < E) homof[i] = loadF(homo, i, flags[0]);
}

// ---------------- GEMM: W in LDS, 4-row unroll; writes Xp f32 + Xpb bf16 ------
__global__ __launch_bounds__(256)
void gemm_kernel(const void* __restrict__ X, const void* __restrict__ W,
                 const int* __restrict__ flags,
                 float* __restrict__ Xp, unsigned short* __restrict__ Xpb, int N) {
    __shared__ float Ws[64 * 64];
    __shared__ float Xs[16][64];
    const int bmode = flags[0];
    int tid = threadIdx.x;
    for (int j = tid; j < 4096; j += 256) Ws[j] = loadF(W, j, bmode);
    __syncthreads();
    int lane = tid & 63, w = tid >> 6;
    int wid = (blockIdx.x * 256 + tid) >> 6;
    int nw  = (gridDim.x * 256) >> 6;
    for (int r0 = wid * 4; r0 < N; r0 += nw * 4) {
        if (r0 + 4 <= N) {
            float acc0 = 0.f, acc1 = 0.f, acc2 = 0.f, acc3 = 0.f;
#pragma unroll
            for (int j = 0; j < 4; ++j)
                Xs[w * 4 + j][lane] = loadF(X, (size_t)(r0 + j) * 64 + lane, bmode);
#pragma unroll
            for (int k4 = 0; k4 < 16; ++k4) {
                float4 x0 = *(const float4*)&Xs[w * 4 + 0][k4 * 4];
                float4 x1 = *(const float4*)&Xs[w * 4 + 1][k4 * 4];
                float4 x2 = *(const float4*)&Xs[w * 4 + 2][k4 * 4];
                float4 x3 = *(const float4*)&Xs[w * 4 + 3][k4 * 4];
#pragma unroll
                for (int kk = 0; kk < 4; ++kk) {
                    float wv = Ws[(k4 * 4 + kk) * 64 + lane];
                    acc0 = fmaf((&x0.x)[kk], wv, acc0);
                    acc1 = fmaf((&x1.x)[kk], wv, acc1);
                    acc2 = fmaf((&x2.x)[kk], wv, acc2);
                    acc3 = fmaf((&x3.x)[kk], wv, acc3);
                }
            }
            float a[4] = {acc0, acc1, acc2, acc3};
#pragma unroll
            for (int j = 0; j < 4; ++j) {
                Xp[(size_t)(r0 + j) * 64 + lane]  = a[j];
                Xpb[(size_t)(r0 + j) * 64 + lane] = f2bf(a[j]);
            }
        } else {
            for (int r = r0; r < N; ++r) {
                Xs[w * 4][lane] = loadF(X, (size_t)r * 64 + lane, bmode);
                float acc = 0.f;
                for (int k = 0; k < 64; ++k)
                    acc = fmaf(Xs[w * 4][k], Ws[k * 64 + lane], acc);
                Xp[(size_t)r * 64 + lane]  = acc;
                Xpb[(size_t)r * 64 + lane] = f2bf(acc);
            }
        }
    }
}

// ---------------- coarse-bucket histogram (tiny LDS, high occupancy) ----------
__global__ __launch_bounds__(1024)
void bhist_kernel(const void* __restrict__ edges, const void* __restrict__ vertex,
                  const int* __restrict__ flags, int* __restrict__ btot,
                  int nnz, int NBE, int NBV, int GC) {
    __shared__ int cnt[MAXB];
    int blk  = blockIdx.x;
    int side = (blk >= GC) ? 1 : 0;
    int b    = side ? blk - GC : blk;
    const void* keys = side ? vertex : edges;
    int sblog = side ? SV_LOG : SE_LOG;
    int nb    = side ? NBV : NBE;
    int bas   = side ? NBE : 0;
    int tid = threadIdx.x;
    for (int j = tid; j < nb; j += 1024) cnt[j] = 0;
    __syncthreads();
    int imode = flags[1];
    int c0 = b * CH, c1 = min(nnz, c0 + CH);
    for (int i = c0 + tid; i < c1; i += 1024)
        atomicAdd(&cnt[loadI(keys, i, imode) >> sblog], 1);
    __syncthreads();
    for (int j = tid; j < nb; j += 1024)
        if (cnt[j]) atomicAdd(&btot[bas + j], cnt[j]);
}

// ---------------- tiny scan over bucket totals -> bases + cursors ------------
__global__ void bscan_kernel(const int* __restrict__ btot, int* __restrict__ bbase,
                             int* __restrict__ bcur, int NBT) {
    __shared__ int wsum[16];
    __shared__ int carry_s;
    int tid = threadIdx.x, lane = tid & 63, w = tid >> 6;
    if (tid == 0) carry_s = 0;
    __syncthreads();
    for (int base = 0; base < NBT; base += 1024) {
        int i = base + tid;
        int x = (i < NBT) ? btot[i] : 0;
        int s = x;
#pragma unroll
        for (int d = 1; d < 64; d <<= 1) {
            int t = __shfl_up(s, d, 64);
            if (lane >= d) s += t;
        }
        if (lane == 63) wsum[w] = s;
        __syncthreads();
        if (w == 0 && lane < 16) {
            int v = wsum[lane];
#pragma unroll
            for (int d = 1; d < 16; d <<= 1) {
                int t = __shfl_up(v, d, 64);
                if (lane >= d) v += t;
            }
            wsum[lane] = v;
        }
        __syncthreads();
        int carry = carry_s;
        int excl  = carry + (w > 0 ? wsum[w - 1] : 0) + s - x;
        if (i < NBT) { bbase[i] = excl; bcur[i] = excl; }
        __syncthreads();
        if (tid == 1023) carry_s = carry + wsum[15];
        __syncthreads();
    }
    if (tid == 0) bbase[NBT] = carry_s;
}

// ------- pass1: chunk -> coarse buckets, packed (local_bin<<psh | payload) ----
__global__ __launch_bounds__(1024)
void bscatter_kernel(const void* __restrict__ edges, const void* __restrict__ vertex,
                     const int* __restrict__ flags, int* __restrict__ bcur,
                     int* __restrict__ buck, int nnz, int NBE, int NBV, int GC,
                     int bitsN, int bitsE) {
    __shared__ int cnt[MAXB];
    __shared__ int gb[MAXB];
    int blk  = blockIdx.x;
    int side = (blk >= GC) ? 1 : 0;
    int b    = side ? blk - GC : blk;
    const void* keys = side ? vertex : edges;
    const void* pay  = side ? edges  : vertex;
    int sblog = side ? SV_LOG : SE_LOG;
    int psh   = side ? bitsE : bitsN;
    int nb    = side ? NBV : NBE;
    int bas   = side ? NBE : 0;
    int tid = threadIdx.x;
    for (int j = tid; j < nb; j += 1024) cnt[j] = 0;
    __syncthreads();
    int imode = flags[1];
    int c0 = b * CH, c1 = min(nnz, c0 + CH);
    for (int i = c0 + tid; i < c1; i += 1024)
        atomicAdd(&cnt[loadI(keys, i, imode) >> sblog], 1);
    __syncthreads();
    for (int j = tid; j < nb; j += 1024) {
        int c = cnt[j];
        gb[j] = c ? atomicAdd(&bcur[bas + j], c) : 0;
        cnt[j] = 0;
    }
    __syncthreads();
    int lmask = (1 << sblog) - 1;
    for (int i = c0 + tid; i < c1; i += 1024) {
        int k   = loadI(keys, i, imode);
        int bkt = k >> sblog;
        int r   = atomicAdd(&cnt[bkt], 1);
        buck[gb[bkt] + r] = ((k & lmask) << psh) | loadI(pay, i, imode);
    }
}

// ------- pass2: one block per bucket: local count/scan -> off[] + dest[] ------
__global__ __launch_bounds__(1024)
void bfinal_kernel(const int* __restrict__ buck, const int* __restrict__ bbase,
                   int* __restrict__ off, int* __restrict__ dest,
                   int NBE, int NBV, int E, int N, int bitsN, int bitsE) {
    __shared__ int cnt[1 << SV_LOG];
    __shared__ int sexc[1 << SV_LOG];
    __shared__ int wsum[16];
    int g    = blockIdx.x;
    int side = (g >= NBE) ? 1 : 0;
    int b    = side ? g - NBE : g;
    int sblog = side ? SV_LOG : SE_LOG;
    int psh   = side ? bitsE : bitsN;
    int pmask = (1 << psh) - 1;
    int nside = side ? N : E;
    int bin0  = b << sblog;
    int nbins = min(1 << sblog, nside - bin0);
    int goff0 = (side ? E : 0) + bin0;
    int s0 = bbase[g], s1 = bbase[g + 1], size = s1 - s0;
    int tid = threadIdx.x, lane = tid & 63, w = tid >> 6;
    for (int j = tid; j < nbins; j += 1024) cnt[j] = 0;
    __syncthreads();
    for (int j = tid; j < size; j += 1024)
        atomicAdd(&cnt[buck[s0 + j] >> psh], 1);
    __syncthreads();
    {   // exclusive scan over nbins (<= 512 < 1024)
        int x = (tid < nbins) ? cnt[tid] : 0;
        int s = x;
#pragma unroll
        for (int d = 1; d < 64; d <<= 1) {
            int t = __shfl_up(s, d, 64);
            if (lane >= d) s += t;
        }
        if (lane == 63) wsum[w] = s;
        __syncthreads();
        if (w == 0 && lane < 16) {
            int v = wsum[lane];
#pragma unroll
            for (int d = 1; d < 16; d <<= 1) {
                int t = __shfl_up(v, d, 64);
                if (lane >= d) v += t;
            }
            wsum[lane] = v;
        }
        __syncthreads();
        int excl = s - x + (w > 0 ? wsum[w - 1] : 0);
        if (tid < nbins) { sexc[tid] = excl; off[goff0 + tid] = s0 + excl; }
    }
    if (side == 1 && b == NBV - 1 && tid == 0) off[E + N] = s1;
    __syncthreads();
    for (int j = tid; j < nbins; j += 1024) cnt[j] = sexc[j];
    __syncthreads();
    for (int j = tid; j < size; j += 1024) {
        int p = buck[s0 + j];
        int r = atomicAdd(&cnt[p >> psh], 1);
        dest[s0 + r] = p & pmask;   // block-owned region: L2-absorbed, no bouncing
    }
}

// ---------------- fallback (global-atomic) CSR build -------------------------
__global__ void hist_atomic_kernel(const void* __restrict__ edges,
                                   const void* __restrict__ vertex,
                                   const int* __restrict__ flags,
                                   int* __restrict__ tot, int E, int nnz) {
    int i = blockIdx.x * blockDim.x + threadIdx.x;
    if (i >= nnz) return;
    int imode = flags[1];
    atomicAdd(&tot[loadI(edges, i, imode)], 1);
    atomicAdd(&tot[E + loadI(vertex, i, imode)], 1);
}

__global__ void scan_part_kernel(const int* __restrict__ tot, int* __restrict__ part, int M) {
    int g = blockIdx.x, tid = threadIdx.x;
    int base = g * 2048;
    int sum = 0;
    for (int j = tid; j < 2048; j += 256) {
        int i = base + j;
        sum += (i < M) ? tot[i] : 0;
    }
#pragma unroll
    for (int d = 32; d >= 1; d >>= 1) sum += __shfl_xor(sum, d, 64);
    __shared__ int wsums[4];
    int lane = tid & 63, w = tid >> 6;
    if (lane == 0) wsums[w] = sum;
    __syncthreads();
    if (tid == 0) part[g] = wsums[0] + wsums[1] + wsums[2] + wsums[3];
}

__global__ void scan_root_kernel(int* __restrict__ part, int G,
                                 int* __restrict__ off, int M) {
    int tid = threadIdx.x, lane = tid & 63, w = tid >> 6;
    int x = (tid < G) ? part[tid] : 0;
    int s = x;
#pragma unroll
    for (int d = 1; d < 64; d <<= 1) {
        int t = __shfl_up(s, d, 64);
        if (lane >= d) s += t;
    }
    __shared__ int ws[16];
    if (lane == 63) ws[w] = s;
    __syncthreads();
    if (w == 0 && lane < 16) {
        int v = ws[lane];
#pragma unroll
        for (int d = 1; d < 16; d <<= 1) {
            int t = __shfl_up(v, d, 64);
            if (lane >= d) v += t;
        }
        ws[lane] = v;
    }
    __syncthreads();
    int excl = s - x + (w > 0 ? ws[w - 1] : 0);
    if (tid < G) part[tid] = excl;
    if (tid == 1023) off[M] = ws[15];
}

__global__ void scan_apply_kernel(int* __restrict__ tot, const int* __restrict__ part,
                                  int* __restrict__ off, int M) {
    int g = blockIdx.x, tid = threadIdx.x, lane = tid & 63, w = tid >> 6;
    int base = g * 2048 + tid * 8;
    int e[8]; int s = 0;
#pragma unroll
    for (int j = 0; j < 8; ++j) {
        int i = base + j;
        e[j] = (i < M) ? tot[i] : 0;
        s += e[j];
    }
    int si = s;
#pragma unroll
    for (int d = 1; d < 64; d <<= 1) {
        int t = __shfl_up(si, d, 64);
        if (lane >= d) si += t;
    }
    __shared__ int wsum[4];
    if (lane == 63) wsum[w] = si;
    __syncthreads();
    int wbase = 0;
    for (int ww = 0; ww < w; ++ww) wbase += wsum[ww];
    int run = part[g] + wbase + si - s;
#pragma unroll
    for (int j = 0; j < 8; ++j) {
        int i = base + j;
        if (i < M) off[i] = run;
        run += e[j];
    }
}

__global__ void copy_kernel(const int* __restrict__ src, int* __restrict__ dst, int n) {
    int i = blockIdx.x * blockDim.x + threadIdx.x;
    if (i < n) dst[i] = src[i];
}

__global__ void scatter_atomic_kernel(const void* __restrict__ edges,
                                      const void* __restrict__ vertex,
                                      const int* __restrict__ flags,
                                      int* __restrict__ cur, int* __restrict__ dest,
                                      int E, int nnz) {
    int i = blockIdx.x * blockDim.x + threadIdx.x;
    if (i >= nnz) return;
    int imode = flags[1];
    int e = loadI(edges, i, imode);
    int v = loadI(vertex, i, imode);
    dest[atomicAdd(&cur[e], 1)]     = v;
    dest[atomicAdd(&cur[E + v], 1)] = e;
}

// ------- Xe[e,:] = mean_{v in e} Xpb[v,:]  (4 incidences/instr: 4 groups x 16)
__global__ void edge_mean_kernel(const unsigned short* __restrict__ Xpb,
                                 const int* __restrict__ off,
                                 const int* __restrict__ sorted,
                                 unsigned short* __restrict__ Xe, int E) {
    int wid  = (blockIdx.x * blockDim.x + threadIdx.x) >> 6;
    int lane = threadIdx.x & 63;
    if (wid >= E) return;
    int g = lane >> 4, c = lane & 15;         // group g handles edges start+g+4k
    unsigned co = (unsigned)c << 3;           // byte offset of lane's uint2 in row
    int start = off[wid], end = off[wid + 1];
    float a0 = 0.f, a1 = 0.f, a2 = 0.f, a3 = 0.f;
    const char* Xb = (const char*)Xpb;
    for (int j = start + g; j < end; j += 4) {
        int v = sorted[j];
        uint2 u = *(const uint2*)(Xb + (((unsigned)v << 7) + co));
        a0 += bflo(u.x); a1 += bfhi(u.x);
        a2 += bflo(u.y); a3 += bfhi(u.y);
    }
    a0 += __shfl_xor(a0, 16, 64); a0 += __shfl_xor(a0, 32, 64);
    a1 += __shfl_xor(a1, 16, 64); a1 += __shfl_xor(a1, 32, 64);
    a2 += __shfl_xor(a2, 16, 64); a2 += __shfl_xor(a2, 32, 64);
    a3 += __shfl_xor(a3, 16, 64); a3 += __shfl_xor(a3, 32, 64);
    if (g == 0) {
        float inv = 1.f / fmaxf((float)(end - start), 1.f);
        unsigned p0 = (unsigned)f2bf(a0 * inv) | ((unsigned)f2bf(a1 * inv) << 16);
        unsigned p1 = (unsigned)f2bf(a2 * inv) | ((unsigned)f2bf(a3 * inv) << 16);
        *(uint2*)((char*)Xe + (((unsigned)wid << 7) + co)) = make_uint2(p0, p1);
    }
}

// -- out[v,:] = rowL2norm( Xp + (sum h*Xe)/(sum h) )  (4 incidences/instr) ----
__global__ void vertex_out_kernel(const float* __restrict__ Xp,
                                  const unsigned short* __restrict__ Xe,
                                  const int* __restrict__ off,
                                  const int* __restrict__ sorted,
                                  const float* __restrict__ homof,
                                  float* __restrict__ out, int E, int N) {
    int wid  = (blockIdx.x * blockDim.x + threadIdx.x) >> 6;
    int lane = threadIdx.x & 63;
    if (wid >= N) return;
    int g = lane >> 4, c = lane & 15;
    unsigned co = (unsigned)c << 3;
    int start = off[E + wid], end = off[E + wid + 1];
    float a0 = 0.f, a1 = 0.f, a2 = 0.f, a3 = 0.f, hs = 0.f;
    const char* Xb = (const char*)Xe;
    for (int j = start + g; j < end; j += 4) {
        int e = sorted[j];
        float h = homof[e];
        uint2 u = *(const uint2*)(Xb + (((unsigned)e << 7) + co));
        a0 = fmaf(h, bflo(u.x), a0); a1 = fmaf(h, bfhi(u.x), a1);
        a2 = fmaf(h, bflo(u.y), a2); a3 = fmaf(h, bfhi(u.y), a3);
        hs += h;
    }
    a0 += __shfl_xor(a0, 16, 64); a0 += __shfl_xor(a0, 32, 64);
    a1 += __shfl_xor(a1, 16, 64); a1 += __shfl_xor(a1, 32, 64);
    a2 += __shfl_xor(a2, 16, 64); a2 += __shfl_xor(a2, 32, 64);
    a3 += __shfl_xor(a3, 16, 64); a3 += __shfl_xor(a3, 32, 64);
    hs += __shfl_xor(hs, 16, 64); hs += __shfl_xor(hs, 32, 64);
    if (g == 0) {
        float inv = (hs > 0.f) ? 1.f / hs : 0.f;
        float4 xp = *(const float4*)((const char*)Xp + (((unsigned)wid << 8) + (co << 1)));
        float r0 = xp.x + a0 * inv, r1 = xp.y + a1 * inv;
        float r2 = xp.z + a2 * inv, r3 = xp.w + a3 * inv;
        float ss = r0 * r0 + r1 * r1 + r2 * r2 + r3 * r3;
        ss += __shfl_xor(ss, 1, 64); ss += __shfl_xor(ss, 2, 64);
        ss += __shfl_xor(ss, 4, 64); ss += __shfl_xor(ss, 8, 64);
        float rn    = sqrtf(ss);
        float scale = (rn > 0.f) ? 1.f / fmaxf(rn, 1e-30f) : 0.f;
        float4 o = make_float4(r0 * scale, r1 * scale, r2 * scale, r3 * scale);
        *(float4*)((char*)out + (((unsigned)wid << 8) + (co << 1))) = o;
    }
}

static inline int ceil_bits(int n) {
    int v = n - 1;
    if (v < 1) v = 1;
    int b = 0;
    while ((1 << b) <= v) ++b;
    return b;
}

extern "C" void kernel_launch(void* const* d_in, const int* in_sizes, int n_in,
                              void* d_out, int out_size, void* d_ws, size_t ws_size,
                              hipStream_t stream) {
    const void* X      = d_in[0];
    const void* W      = d_in[1];
    const void* homo   = d_in[2];
    const void* vertex = d_in[3];
    const void* edges  = d_in[4];
    float* out = (float*)d_out;

    const int N   = in_sizes[0] / 64;
    const int E   = in_sizes[2];
    const int NNZ = in_sizes[3];
    const int M   = E + N;

    const int NBE = (E + (1 << SE_LOG) - 1) >> SE_LOG;
    const int NBV = (N + (1 << SV_LOG) - 1) >> SV_LOG;
    const int NBT = NBE + NBV;
    const int GC  = (NNZ + CH - 1) / CH;
    const int bitsN = ceil_bits(N);
    const int bitsE = ceil_bits(E);
    const int G   = (M + 2047) / 2048;  // fallback scan tiles

    char*  ws = (char*)d_ws;
    size_t o  = 0;
    auto alloc = [&](size_t bytes) -> void* {
        void* p = ws + o;
        o += (bytes + 255) & ~(size_t)255;
        return p;
    };
    int*            flags = (int*)alloc(2 * 4);
    int*            off   = (int*)alloc((size_t)(M + 1) * 4);
    int*            bbase = (int*)alloc((size_t)(NBT + 1) * 4);
    int*            bcur  = (int*)alloc((size_t)NBT * 4);
    int*            btot  = (int*)alloc((size_t)NBT * 4);
    float*          homof = (float*)alloc((size_t)E * 4);
    int*            buck  = (int*)alloc((size_t)2 * NNZ * 4);
    int*            sorted= (int*)alloc((size_t)2 * NNZ * 4);
    float*          Xp    = (float*)alloc((size_t)N * 64 * 4);
    unsigned short* Xpb   = (unsigned short*)alloc((size_t)N * 64 * 2);
    unsigned short* Xe    = (unsigned short*)alloc((size_t)E * 64 * 2);
    size_t o_common = o;
    bool fast = (o <= ws_size) && NBE <= MAXB && NBV <= MAXB &&
                (SE_LOG + bitsN <= 32) && (SV_LOG + bitsE <= 32) && G <= 1024;
    (void)n_in; (void)out_size;

    sniff_kernel<<<1, 64, 0, stream>>>(X, vertex, flags);
    homof_kernel<<<(E + 255) / 256, 256, 0, stream>>>(homo, flags, homof, E);
    gemm_kernel<<<512, 256, 0, stream>>>(X, W, flags, Xp, Xpb, N);

    if (fast) {
        hipMemsetAsync(btot, 0, (size_t)NBT * 4, stream);
        bhist_kernel<<<2 * GC, 1024, 0, stream>>>(edges, vertex, flags, btot,
                                                  NNZ, NBE, NBV, GC);
        bscan_kernel<<<1, 1024, 0, stream>>>(btot, bbase, bcur, NBT);
        bscatter_kernel<<<2 * GC, 1024, 0, stream>>>(edges, vertex, flags, bcur,
                                                     buck, NNZ, NBE, NBV, GC,
                                                     bitsN, bitsE);
        bfinal_kernel<<<NBT, 1024, 0, stream>>>(buck, bbase, off, sorted,
                                                NBE, NBV, E, N, bitsN, bitsE);
    } else {
        o = o_common;
        int* tot  = (int*)alloc((size_t)M * 4);
        int* part = (int*)alloc((size_t)(G + 1) * 4);
        int* cur  = (int*)alloc((size_t)M * 4);
        hipMemsetAsync(tot, 0, (size_t)M * 4, stream);
        int nb = (NNZ + 255) / 256;
        hist_atomic_kernel<<<nb, 256, 0, stream>>>(edges, vertex, flags, tot, E, NNZ);
        scan_part_kernel<<<G, 256, 0, stream>>>(tot, part, M);
        scan_root_kernel<<<1, 1024, 0, stream>>>(part, G, off, M);
        scan_apply_kernel<<<G, 256, 0, stream>>>(tot, part, off, M);
        copy_kernel<<<(M + 255) / 256, 256, 0, stream>>>(off, cur, M);
        scatter_atomic_kernel<<<nb, 256, 0, stream>>>(edges, vertex, flags, cur, sorted, E, NNZ);
    }

    edge_mean_kernel<<<(E + 3) / 4, 256, 0, stream>>>(Xpb, off, sorted, Xe, E);
    vertex_out_kernel<<<(N + 3) / 4, 256, 0, stream>>>(Xp, Xe, off, sorted,
                                                       homof, out, E, N);
}

// Round 9
// 286.252 us; speedup vs baseline: 1.8889x; 1.0951x over previous
//
#include <hip/hip_runtime.h>
#include <hip/hip_bf16.h>

// Hypergraph conv:  Xp = X@W;  Xe = mean_{v in e} Xp[v];
// Xv[v] = (sum_{e ∋ v} homo[e]*Xe[e]) / (sum_{e ∋ v} homo[e]);  out = rowL2norm(Xp+Xv)
//
// R8 counters: vertex_out 70us @ HBM 13%, VALU 44% -> un-hidden L2 latency on
// the sorted[j] -> row dependent chain. R9: (1) unroll x2 (two independent
// chains per group), (2) Ye = homo*Xe prescaled in edge_mean + hs[v] computed
// in bfinal (vertex_out inner loop: 2 loads + 4 adds per 4 incidences),
// (3) bhist count slab reused by bscatter (skips 16MB re-read).

#define SE_LOG 7          // edges per bucket = 128
#define SV_LOG 9          // vertices per bucket = 512
#define MAXB   2048       // max coarse buckets per side (LDS counters)
#define CH     16384      // incidences per pass-1 block

__device__ __forceinline__ float bf2f(unsigned short u) {
    union { unsigned int i; float f; } x;
    x.i = ((unsigned int)u) << 16;
    return x.f;
}

__device__ __forceinline__ float bflo(unsigned int u) {
    union { unsigned int i; float f; } x;
    x.i = u << 16;
    return x.f;
}

__device__ __forceinline__ float bfhi(unsigned int u) {
    union { unsigned int i; float f; } x;
    x.i = u & 0xffff0000u;
    return x.f;
}

__device__ __forceinline__ unsigned short f2bf(float f) {
    union { unsigned int i; float ff; } x;
    x.ff = f;
    unsigned int r = x.i + 0x7fff + ((x.i >> 16) & 1);
    return (unsigned short)(r >> 16);
}

__device__ __forceinline__ float loadF(const void* p, size_t i, int bf16mode) {
    return bf16mode ? bf2f(((const unsigned short*)p)[i]) : ((const float*)p)[i];
}

__device__ __forceinline__ int loadI(const void* p, size_t i, int i64mode) {
    return i64mode ? ((const int*)p)[2 * i] : ((const int*)p)[i];
}

// ---------------- dtype sniff: flags[0]=floats-are-bf16, flags[1]=indices-are-i64
__global__ void sniff_kernel(const void* X, const void* vtx, int* flags) {
    if (threadIdx.x != 0 || blockIdx.x != 0) return;
    const unsigned short* u = (const unsigned short*)X;
    int sane = 0;
    for (int i = 0; i < 64; ++i) {
        unsigned short lo = u[2 * i];
        int e = (lo >> 7) & 0xFF;
        if (e >= 110 && e <= 137) ++sane;
    }
    flags[0] = (sane >= 32) ? 1 : 0;
    const int* w = (const int*)vtx;
    int zeros = 0;
    for (int i = 0; i < 64; ++i)
        if (w[2 * i + 1] == 0) ++zeros;
    flags[1] = (zeros >= 32) ? 1 : 0;
}

// ---------------- homo -> f32 -------------------------------------------------
__global__ void homof_kernel(const void* __restrict__ homo,
                             const int* __restrict__ flags,
                             float* __restrict__ homof, int E) {
    int i = blockIdx.x * blockDim.x + threadIdx.x;
    if (i < E) homof[i] = loadF(homo, i, flags[0]);
}

// ---------------- GEMM: W in LDS, 4-row unroll; writes Xp f32 + Xpb bf16 ------
__global__ __launch_bounds__(256)
void gemm_kernel(const void* __restrict__ X, const void* __restrict__ W,
                 const int* __restrict__ flags,
                 float* __restrict__ Xp, unsigned short* __restrict__ Xpb, int N) {
    __shared__ float Ws[64 * 64];
    __shared__ float Xs[16][64];
    const int bmode = flags[0];
    int tid = threadIdx.x;
    for (int j = tid; j < 4096; j += 256) Ws[j] = loadF(W, j, bmode);
    __syncthreads();
    int lane = tid & 63, w = tid >> 6;
    int wid = (blockIdx.x * 256 + tid) >> 6;
    int nw  = (gridDim.x * 256) >> 6;
    for (int r0 = wid * 4; r0 < N; r0 += nw * 4) {
        if (r0 + 4 <= N) {
            float acc0 = 0.f, acc1 = 0.f, acc2 = 0.f, acc3 = 0.f;
#pragma unroll
            for (int j = 0; j < 4; ++j)
                Xs[w * 4 + j][lane] = loadF(X, (size_t)(r0 + j) * 64 + lane, bmode);
#pragma unroll
            for (int k4 = 0; k4 < 16; ++k4) {
                float4 x0 = *(const float4*)&Xs[w * 4 + 0][k4 * 4];
                float4 x1 = *(const float4*)&Xs[w * 4 + 1][k4 * 4];
                float4 x2 = *(const float4*)&Xs[w * 4 + 2][k4 * 4];
                float4 x3 = *(const float4*)&Xs[w * 4 + 3][k4 * 4];
#pragma unroll
                for (int kk = 0; kk < 4; ++kk) {
                    float wv = Ws[(k4 * 4 + kk) * 64 + lane];
                    acc0 = fmaf((&x0.x)[kk], wv, acc0);
                    acc1 = fmaf((&x1.x)[kk], wv, acc1);
                    acc2 = fmaf((&x2.x)[kk], wv, acc2);
                    acc3 = fmaf((&x3.x)[kk], wv, acc3);
                }
            }
            float a[4] = {acc0, acc1, acc2, acc3};
#pragma unroll
            for (int j = 0; j < 4; ++j) {
                Xp[(size_t)(r0 + j) * 64 + lane]  = a[j];
                Xpb[(size_t)(r0 + j) * 64 + lane] = f2bf(a[j]);
            }
        } else {
            for (int r = r0; r < N; ++r) {
                Xs[w * 4][lane] = loadF(X, (size_t)r * 64 + lane, bmode);
                float acc = 0.f;
                for (int k = 0; k < 64; ++k)
                    acc = fmaf(Xs[w * 4][k], Ws[k * 64 + lane], acc);
                Xp[(size_t)r * 64 + lane]  = acc;
                Xpb[(size_t)r * 64 + lane] = f2bf(acc);
            }
        }
    }
}

// ------- coarse-bucket histogram; also stores per-(chunk,bucket) counts -------
__global__ __launch_bounds__(1024)
void bhist_kernel(const void* __restrict__ edges, const void* __restrict__ vertex,
                  const int* __restrict__ flags, int* __restrict__ btot,
                  int* __restrict__ slabc, int sstride,
                  int nnz, int NBE, int NBV, int GC) {
    __shared__ int cnt[MAXB];
    int blk  = blockIdx.x;
    int side = (blk >= GC) ? 1 : 0;
    int b    = side ? blk - GC : blk;
    const void* keys = side ? vertex : edges;
    int sblog = side ? SV_LOG : SE_LOG;
    int nb    = side ? NBV : NBE;
    int bas   = side ? NBE : 0;
    int tid = threadIdx.x;
    for (int j = tid; j < nb; j += 1024) cnt[j] = 0;
    __syncthreads();
    int imode = flags[1];
    int c0 = b * CH, c1 = min(nnz, c0 + CH);
    for (int i = c0 + tid; i < c1; i += 1024)
        atomicAdd(&cnt[loadI(keys, i, imode) >> sblog], 1);
    __syncthreads();
    for (int j = tid; j < nb; j += 1024) {
        int c = cnt[j];
        slabc[(size_t)blk * sstride + j] = c;
        if (c) atomicAdd(&btot[bas + j], c);
    }
}

// ---------------- tiny scan over bucket totals -> bases + cursors ------------
__global__ void bscan_kernel(const int* __restrict__ btot, int* __restrict__ bbase,
                             int* __restrict__ bcur, int NBT) {
    __shared__ int wsum[16];
    __shared__ int carry_s;
    int tid = threadIdx.x, lane = tid & 63, w = tid >> 6;
    if (tid == 0) carry_s = 0;
    __syncthreads();
    for (int base = 0; base < NBT; base += 1024) {
        int i = base + tid;
        int x = (i < NBT) ? btot[i] : 0;
        int s = x;
#pragma unroll
        for (int d = 1; d < 64; d <<= 1) {
            int t = __shfl_up(s, d, 64);
            if (lane >= d) s += t;
        }
        if (lane == 63) wsum[w] = s;
        __syncthreads();
        if (w == 0 && lane < 16) {
            int v = wsum[lane];
#pragma unroll
            for (int d = 1; d < 16; d <<= 1) {
                int t = __shfl_up(v, d, 64);
                if (lane >= d) v += t;
            }
            wsum[lane] = v;
        }
        __syncthreads();
        int carry = carry_s;
        int excl  = carry + (w > 0 ? wsum[w - 1] : 0) + s - x;
        if (i < NBT) { bbase[i] = excl; bcur[i] = excl; }
        __syncthreads();
        if (tid == 1023) carry_s = carry + wsum[15];
        __syncthreads();
    }
    if (tid == 0) bbase[NBT] = carry_s;
}

// ------- pass1: chunk -> coarse buckets, packed (local_bin<<psh | payload) ----
// counts come from bhist's slab: no re-count pass.
__global__ __launch_bounds__(1024)
void bscatter_kernel(const void* __restrict__ edges, const void* __restrict__ vertex,
                     const int* __restrict__ flags, int* __restrict__ bcur,
                     const int* __restrict__ slabc, int sstride,
                     int* __restrict__ buck, int nnz, int NBE, int NBV, int GC,
                     int bitsN, int bitsE) {
    __shared__ int cnt[MAXB];
    __shared__ int gb[MAXB];
    int blk  = blockIdx.x;
    int side = (blk >= GC) ? 1 : 0;
    int b    = side ? blk - GC : blk;
    const void* keys = side ? vertex : edges;
    const void* pay  = side ? edges  : vertex;
    int sblog = side ? SV_LOG : SE_LOG;
    int psh   = side ? bitsE : bitsN;
    int nb    = side ? NBV : NBE;
    int bas   = side ? NBE : 0;
    int tid = threadIdx.x;
    for (int j = tid; j < nb; j += 1024) {
        int c = slabc[(size_t)blk * sstride + j];
        gb[j]  = c ? atomicAdd(&bcur[bas + j], c) : 0;
        cnt[j] = 0;
    }
    __syncthreads();
    int imode = flags[1];
    int c0 = b * CH, c1 = min(nnz, c0 + CH);
    int lmask = (1 << sblog) - 1;
    for (int i = c0 + tid; i < c1; i += 1024) {
        int k   = loadI(keys, i, imode);
        int bkt = k >> sblog;
        int r   = atomicAdd(&cnt[bkt], 1);
        buck[gb[bkt] + r] = ((k & lmask) << psh) | loadI(pay, i, imode);
    }
}

// ------- pass2: one block per bucket -> off[], dest[]; vertex side also hs[] --
__global__ __launch_bounds__(1024)
void bfinal_kernel(const int* __restrict__ buck, const int* __restrict__ bbase,
                   const float* __restrict__ homof,
                   int* __restrict__ off, int* __restrict__ dest,
                   float* __restrict__ hs,
                   int NBE, int NBV, int E, int N, int bitsN, int bitsE) {
    __shared__ int cnt[1 << SV_LOG];
    __shared__ int sexc[1 << SV_LOG];
    __shared__ float hsum[1 << SV_LOG];
    __shared__ int wsum[16];
    int g    = blockIdx.x;
    int side = (g >= NBE) ? 1 : 0;
    int b    = side ? g - NBE : g;
    int sblog = side ? SV_LOG : SE_LOG;
    int psh   = side ? bitsE : bitsN;
    int pmask = (1 << psh) - 1;
    int nside = side ? N : E;
    int bin0  = b << sblog;
    int nbins = min(1 << sblog, nside - bin0);
    int goff0 = (side ? E : 0) + bin0;
    int s0 = bbase[g], s1 = bbase[g + 1], size = s1 - s0;
    int tid = threadIdx.x, lane = tid & 63, w = tid >> 6;
    for (int j = tid; j < nbins; j += 1024) { cnt[j] = 0; hsum[j] = 0.f; }
    __syncthreads();
    for (int j = tid; j < size; j += 1024)
        atomicAdd(&cnt[buck[s0 + j] >> psh], 1);
    __syncthreads();
    {   // exclusive scan over nbins (<= 512 < 1024)
        int x = (tid < nbins) ? cnt[tid] : 0;
        int s = x;
#pragma unroll
        for (int d = 1; d < 64; d <<= 1) {
            int t = __shfl_up(s, d, 64);
            if (lane >= d) s += t;
        }
        if (lane == 63) wsum[w] = s;
        __syncthreads();
        if (w == 0 && lane < 16) {
            int v = wsum[lane];
#pragma unroll
            for (int d = 1; d < 16; d <<= 1) {
                int t = __shfl_up(v, d, 64);
                if (lane >= d) v += t;
            }
            wsum[lane] = v;
        }
        __syncthreads();
        int excl = s - x + (w > 0 ? wsum[w - 1] : 0);
        if (tid < nbins) { sexc[tid] = excl; off[goff0 + tid] = s0 + excl; }
    }
    if (side == 1 && b == NBV - 1 && tid == 0) off[E + N] = s1;
    __syncthreads();
    for (int j = tid; j < nbins; j += 1024) cnt[j] = sexc[j];
    __syncthreads();
    if (side == 1) {
        for (int j = tid; j < size; j += 1024) {
            int p  = buck[s0 + j];
            int lb = p >> psh;
            int r  = atomicAdd(&cnt[lb], 1);
            int e  = p & pmask;
            dest[s0 + r] = e;
            atomicAdd(&hsum[lb], homof[e]);
        }
        __syncthreads();
        for (int j = tid; j < nbins; j += 1024) hs[bin0 + j] = hsum[j];
    } else {
        for (int j = tid; j < size; j += 1024) {
            int p = buck[s0 + j];
            int r = atomicAdd(&cnt[p >> psh], 1);
            dest[s0 + r] = p & pmask;
        }
    }
}

// ---------------- fallback (global-atomic) CSR build -------------------------
__global__ void hist_atomic_kernel(const void* __restrict__ edges,
                                   const void* __restrict__ vertex,
                                   const int* __restrict__ flags,
                                   int* __restrict__ tot, int E, int nnz) {
    int i = blockIdx.x * blockDim.x + threadIdx.x;
    if (i >= nnz) return;
    int imode = flags[1];
    atomicAdd(&tot[loadI(edges, i, imode)], 1);
    atomicAdd(&tot[E + loadI(vertex, i, imode)], 1);
}

__global__ void scan_part_kernel(const int* __restrict__ tot, int* __restrict__ part, int M) {
    int g = blockIdx.x, tid = threadIdx.x;
    int base = g * 2048;
    int sum = 0;
    for (int j = tid; j < 2048; j += 256) {
        int i = base + j;
        sum += (i < M) ? tot[i] : 0;
    }
#pragma unroll
    for (int d = 32; d >= 1; d >>= 1) sum += __shfl_xor(sum, d, 64);
    __shared__ int wsums[4];
    int lane = tid & 63, w = tid >> 6;
    if (lane == 0) wsums[w] = sum;
    __syncthreads();
    if (tid == 0) part[g] = wsums[0] + wsums[1] + wsums[2] + wsums[3];
}

__global__ void scan_root_kernel(int* __restrict__ part, int G,
                                 int* __restrict__ off, int M) {
    int tid = threadIdx.x, lane = tid & 63, w = tid >> 6;
    int x = (tid < G) ? part[tid] : 0;
    int s = x;
#pragma unroll
    for (int d = 1; d < 64; d <<= 1) {
        int t = __shfl_up(s, d, 64);
        if (lane >= d) s += t;
    }
    __shared__ int ws[16];
    if (lane == 63) ws[w] = s;
    __syncthreads();
    if (w == 0 && lane < 16) {
        int v = ws[lane];
#pragma unroll
        for (int d = 1; d < 16; d <<= 1) {
            int t = __shfl_up(v, d, 64);
            if (lane >= d) v += t;
        }
        ws[lane] = v;
    }
    __syncthreads();
    int excl = s - x + (w > 0 ? ws[w - 1] : 0);
    if (tid < G) part[tid] = excl;
    if (tid == 1023) off[M] = ws[15];
}

__global__ void scan_apply_kernel(int* __restrict__ tot, const int* __restrict__ part,
                                  int* __restrict__ off, int M) {
    int g = blockIdx.x, tid = threadIdx.x, lane = tid & 63, w = tid >> 6;
    int base = g * 2048 + tid * 8;
    int e[8]; int s = 0;
#pragma unroll
    for (int j = 0; j < 8; ++j) {
        int i = base + j;
        e[j] = (i < M) ? tot[i] : 0;
        s += e[j];
    }
    int si = s;
#pragma unroll
    for (int d = 1; d < 64; d <<= 1) {
        int t = __shfl_up(si, d, 64);
        if (lane >= d) si += t;
    }
    __shared__ int wsum[4];
    if (lane == 63) wsum[w] = si;
    __syncthreads();
    int wbase = 0;
    for (int ww = 0; ww < w; ++ww) wbase += wsum[ww];
    int run = part[g] + wbase + si - s;
#pragma unroll
    for (int j = 0; j < 8; ++j) {
        int i = base + j;
        if (i < M) off[i] = run;
        run += e[j];
    }
}

__global__ void copy_kernel(const int* __restrict__ src, int* __restrict__ dst, int n) {
    int i = blockIdx.x * blockDim.x + threadIdx.x;
    if (i < n) dst[i] = src[i];
}

__global__ void scatter_atomic_kernel(const void* __restrict__ edges,
                                      const void* __restrict__ vertex,
                                      const int* __restrict__ flags,
                                      int* __restrict__ cur, int* __restrict__ dest,
                                      int E, int nnz) {
    int i = blockIdx.x * blockDim.x + threadIdx.x;
    if (i >= nnz) return;
    int imode = flags[1];
    int e = loadI(edges, i, imode);
    int v = loadI(vertex, i, imode);
    dest[atomicAdd(&cur[e], 1)]     = v;
    dest[atomicAdd(&cur[E + v], 1)] = e;
}

__global__ void hs_fallback_kernel(const int* __restrict__ off,
                                   const int* __restrict__ sorted,
                                   const float* __restrict__ homof,
                                   float* __restrict__ hs, int E, int N) {
    int v = blockIdx.x * blockDim.x + threadIdx.x;
    if (v >= N) return;
    int s = off[E + v], e = off[E + v + 1];
    float t = 0.f;
    for (int j = s; j < e; ++j) t += homof[sorted[j]];
    hs[v] = t;
}

// -- Ye[e,:] = homo[e] * mean_{v in e} Xpb[v,:]   (4 groups x 16, unroll x2) --
__global__ void edge_mean_kernel(const unsigned short* __restrict__ Xpb,
                                 const int* __restrict__ off,
                                 const int* __restrict__ sorted,
                                 const float* __restrict__ homof,
                                 unsigned short* __restrict__ Ye, int E) {
    int wid  = (blockIdx.x * blockDim.x + threadIdx.x) >> 6;
    int lane = threadIdx.x & 63;
    if (wid >= E) return;
    int g = lane >> 4, c = lane & 15;
    unsigned co = (unsigned)c << 3;
    int start = off[wid], end = off[wid + 1];
    float a0 = 0.f, a1 = 0.f, a2 = 0.f, a3 = 0.f;
    const char* Xb = (const char*)Xpb;
    int j = start + g;
    for (; j + 4 < end; j += 8) {        // two independent chains in flight
        int v1 = sorted[j];
        int v2 = sorted[j + 4];
        uint2 u1 = *(const uint2*)(Xb + (((unsigned)v1 << 7) + co));
        uint2 u2 = *(const uint2*)(Xb + (((unsigned)v2 << 7) + co));
        a0 += bflo(u1.x) + bflo(u2.x);
        a1 += bfhi(u1.x) + bfhi(u2.x);
        a2 += bflo(u1.y) + bflo(u2.y);
        a3 += bfhi(u1.y) + bfhi(u2.y);
    }
    if (j < end) {
        int v = sorted[j];
        uint2 u = *(const uint2*)(Xb + (((unsigned)v << 7) + co));
        a0 += bflo(u.x); a1 += bfhi(u.x);
        a2 += bflo(u.y); a3 += bfhi(u.y);
    }
    a0 += __shfl_xor(a0, 16, 64); a0 += __shfl_xor(a0, 32, 64);
    a1 += __shfl_xor(a1, 16, 64); a1 += __shfl_xor(a1, 32, 64);
    a2 += __shfl_xor(a2, 16, 64); a2 += __shfl_xor(a2, 32, 64);
    a3 += __shfl_xor(a3, 16, 64); a3 += __shfl_xor(a3, 32, 64);
    if (g == 0) {
        float inv = homof[wid] / fmaxf((float)(end - start), 1.f);
        unsigned p0 = (unsigned)f2bf(a0 * inv) | ((unsigned)f2bf(a1 * inv) << 16);
        unsigned p1 = (unsigned)f2bf(a2 * inv) | ((unsigned)f2bf(a3 * inv) << 16);
        *(uint2*)((char*)Ye + (((unsigned)wid << 7) + co)) = make_uint2(p0, p1);
    }
}

// -- out[v,:] = rowL2norm( Xp + (sum Ye)/hs[v] )  (unroll x2, no homo gather) -
__global__ void vertex_out_kernel(const float* __restrict__ Xp,
                                  const unsigned short* __restrict__ Ye,
                                  const int* __restrict__ off,
                                  const int* __restrict__ sorted,
                                  const float* __restrict__ hs,
                                  float* __restrict__ out, int E, int N) {
    int wid  = (blockIdx.x * blockDim.x + threadIdx.x) >> 6;
    int lane = threadIdx.x & 63;
    if (wid >= N) return;
    int g = lane >> 4, c = lane & 15;
    unsigned co = (unsigned)c << 3;
    int start = off[E + wid], end = off[E + wid + 1];
    float a0 = 0.f, a1 = 0.f, a2 = 0.f, a3 = 0.f;
    const char* Xb = (const char*)Ye;
    int j = start + g;
    for (; j + 4 < end; j += 8) {        // two independent chains in flight
        int e1 = sorted[j];
        int e2 = sorted[j + 4];
        uint2 u1 = *(const uint2*)(Xb + (((unsigned)e1 << 7) + co));
        uint2 u2 = *(const uint2*)(Xb + (((unsigned)e2 << 7) + co));
        a0 += bflo(u1.x) + bflo(u2.x);
        a1 += bfhi(u1.x) + bfhi(u2.x);
        a2 += bflo(u1.y) + bflo(u2.y);
        a3 += bfhi(u1.y) + bfhi(u2.y);
    }
    if (j < end) {
        int e = sorted[j];
        uint2 u = *(const uint2*)(Xb + (((unsigned)e << 7) + co));
        a0 += bflo(u.x); a1 += bfhi(u.x);
        a2 += bflo(u.y); a3 += bfhi(u.y);
    }
    a0 += __shfl_xor(a0, 16, 64); a0 += __shfl_xor(a0, 32, 64);
    a1 += __shfl_xor(a1, 16, 64); a1 += __shfl_xor(a1, 32, 64);
    a2 += __shfl_xor(a2, 16, 64); a2 += __shfl_xor(a2, 32, 64);
    a3 += __shfl_xor(a3, 16, 64); a3 += __shfl_xor(a3, 32, 64);
    if (g == 0) {
        float hsv = hs[wid];
        float inv = (hsv > 0.f) ? 1.f / hsv : 0.f;
        float4 xp = *(const float4*)((const char*)Xp + (((unsigned)wid << 8) + (co << 1)));
        float r0 = xp.x + a0 * inv, r1 = xp.y + a1 * inv;
        float r2 = xp.z + a2 * inv, r3 = xp.w + a3 * inv;
        float ss = r0 * r0 + r1 * r1 + r2 * r2 + r3 * r3;
        ss += __shfl_xor(ss, 1, 64); ss += __shfl_xor(ss, 2, 64);
        ss += __shfl_xor(ss, 4, 64); ss += __shfl_xor(ss, 8, 64);
        float rn    = sqrtf(ss);
        float scale = (rn > 0.f) ? 1.f / fmaxf(rn, 1e-30f) : 0.f;
        float4 o = make_float4(r0 * scale, r1 * scale, r2 * scale, r3 * scale);
        *(float4*)((char*)out + (((unsigned)wid << 8) + (co << 1))) = o;
    }
}

static inline int ceil_bits(int n) {
    int v = n - 1;
    if (v < 1) v = 1;
    int b = 0;
    while ((1 << b) <= v) ++b;
    return b;
}

extern "C" void kernel_launch(void* const* d_in, const int* in_sizes, int n_in,
                              void* d_out, int out_size, void* d_ws, size_t ws_size,
                              hipStream_t stream) {
    const void* X      = d_in[0];
    const void* W      = d_in[1];
    const void* homo   = d_in[2];
    const void* vertex = d_in[3];
    const void* edges  = d_in[4];
    float* out = (float*)d_out;

    const int N   = in_sizes[0] / 64;
    const int E   = in_sizes[2];
    const int NNZ = in_sizes[3];
    const int M   = E + N;

    const int NBE = (E + (1 << SE_LOG) - 1) >> SE_LOG;
    const int NBV = (N + (1 << SV_LOG) - 1) >> SV_LOG;
    const int NBT = NBE + NBV;
    const int GC  = (NNZ + CH - 1) / CH;
    const int SST = (NBE > NBV ? NBE : NBV);      // slab stride
    const int bitsN = ceil_bits(N);
    const int bitsE = ceil_bits(E);
    const int G   = (M + 2047) / 2048;  // fallback scan tiles

    char*  ws = (char*)d_ws;
    size_t o  = 0;
    auto alloc = [&](size_t bytes) -> void* {
        void* p = ws + o;
        o += (bytes + 255) & ~(size_t)255;
        return p;
    };
    int*            flags = (int*)alloc(2 * 4);
    int*            off   = (int*)alloc((size_t)(M + 1) * 4);
    int*            bbase = (int*)alloc((size_t)(NBT + 1) * 4);
    int*            bcur  = (int*)alloc((size_t)NBT * 4);
    int*            btot  = (int*)alloc((size_t)NBT * 4);
    float*          homof = (float*)alloc((size_t)E * 4);
    float*          hs    = (float*)alloc((size_t)N * 4);
    int*            buck  = (int*)alloc((size_t)2 * NNZ * 4);
    int*            sorted= (int*)alloc((size_t)2 * NNZ * 4);
    float*          Xp    = (float*)alloc((size_t)N * 64 * 4);
    unsigned short* Xpb   = (unsigned short*)alloc((size_t)N * 64 * 2);
    unsigned short* Ye    = (unsigned short*)alloc((size_t)E * 64 * 2);
    int*            slabc = (int*)alloc((size_t)2 * GC * SST * 4);
    size_t o_common = o;
    bool fast = (o <= ws_size) && NBE <= MAXB && NBV <= MAXB &&
                (SE_LOG + bitsN <= 32) && (SV_LOG + bitsE <= 32) && G <= 1024;
    (void)n_in; (void)out_size;

    sniff_kernel<<<1, 64, 0, stream>>>(X, vertex, flags);
    homof_kernel<<<(E + 255) / 256, 256, 0, stream>>>(homo, flags, homof, E);
    gemm_kernel<<<512, 256, 0, stream>>>(X, W, flags, Xp, Xpb, N);

    if (fast) {
        hipMemsetAsync(btot, 0, (size_t)NBT * 4, stream);
        bhist_kernel<<<2 * GC, 1024, 0, stream>>>(edges, vertex, flags, btot,
                                                  slabc, SST, NNZ, NBE, NBV, GC);
        bscan_kernel<<<1, 1024, 0, stream>>>(btot, bbase, bcur, NBT);
        bscatter_kernel<<<2 * GC, 1024, 0, stream>>>(edges, vertex, flags, bcur,
                                                     slabc, SST, buck, NNZ,
                                                     NBE, NBV, GC, bitsN, bitsE);
        bfinal_kernel<<<NBT, 1024, 0, stream>>>(buck, bbase, homof, off, sorted,
                                                hs, NBE, NBV, E, N, bitsN, bitsE);
    } else {
        o = o_common;
        int* tot  = (int*)alloc((size_t)M * 4);
        int* part = (int*)alloc((size_t)(G + 1) * 4);
        int* cur  = (int*)alloc((size_t)M * 4);
        hipMemsetAsync(tot, 0, (size_t)M * 4, stream);
        int nb = (NNZ + 255) / 256;
        hist_atomic_kernel<<<nb, 256, 0, stream>>>(edges, vertex, flags, tot, E, NNZ);
        scan_part_kernel<<<G, 256, 0, stream>>>(tot, part, M);
        scan_root_kernel<<<1, 1024, 0, stream>>>(part, G, off, M);
        scan_apply_kernel<<<G, 256, 0, stream>>>(tot, part, off, M);
        copy_kernel<<<(M + 255) / 256, 256, 0, stream>>>(off, cur, M);
        scatter_atomic_kernel<<<nb, 256, 0, stream>>>(edges, vertex, flags, cur, sorted, E, NNZ);
        hs_fallback_kernel<<<(N + 255) / 256, 256, 0, stream>>>(off, sorted, homof, hs, E, N);
    }

    edge_mean_kernel<<<(E + 3) / 4, 256, 0, stream>>>(Xpb, off, sorted, homof, Ye, E);
    vertex_out_kernel<<<(N + 3) / 4, 256, 0, stream>>>(Xp, Ye, off, sorted,
                                                       hs, out, E, N);
}

// Round 10
// 280.200 us; speedup vs baseline: 1.9297x; 1.0216x over previous
//
#include <hip/hip_runtime.h>
#include <hip/hip_bf16.h>

// Hypergraph conv:  Xp = X@W;  Xe = mean_{v in e} Xp[v];
// Xv[v] = (sum_{e ∋ v} homo[e]*Xe[e]) / (sum_{e ∋ v} homo[e]);  out = rowL2norm(Xp+Xv)
//
// R9 counters: vertex_out 54us @ VALU 52%, HBM 17% -> wave-latency bound
// (~2.5 serial L2 round-trips/wave, issue is only ~10us). R10: (1) drop Xp
// f32 — residual read from bf16 Xpb (halves vertex_out fetch, kills 25.6MB
// gemm write); (2) unroll x4 in both gather loops (16 chains in flight/wave).

#define SE_LOG 7          // edges per bucket = 128
#define SV_LOG 9          // vertices per bucket = 512
#define MAXB   2048       // max coarse buckets per side (LDS counters)
#define CH     16384      // incidences per pass-1 block

__device__ __forceinline__ float bf2f(unsigned short u) {
    union { unsigned int i; float f; } x;
    x.i = ((unsigned int)u) << 16;
    return x.f;
}

__device__ __forceinline__ float bflo(unsigned int u) {
    union { unsigned int i; float f; } x;
    x.i = u << 16;
    return x.f;
}

__device__ __forceinline__ float bfhi(unsigned int u) {
    union { unsigned int i; float f; } x;
    x.i = u & 0xffff0000u;
    return x.f;
}

__device__ __forceinline__ unsigned short f2bf(float f) {
    union { unsigned int i; float ff; } x;
    x.ff = f;
    unsigned int r = x.i + 0x7fff + ((x.i >> 16) & 1);
    return (unsigned short)(r >> 16);
}

__device__ __forceinline__ float loadF(const void* p, size_t i, int bf16mode) {
    return bf16mode ? bf2f(((const unsigned short*)p)[i]) : ((const float*)p)[i];
}

__device__ __forceinline__ int loadI(const void* p, size_t i, int i64mode) {
    return i64mode ? ((const int*)p)[2 * i] : ((const int*)p)[i];
}

// ---------------- dtype sniff: flags[0]=floats-are-bf16, flags[1]=indices-are-i64
__global__ void sniff_kernel(const void* X, const void* vtx, int* flags) {
    if (threadIdx.x != 0 || blockIdx.x != 0) return;
    const unsigned short* u = (const unsigned short*)X;
    int sane = 0;
    for (int i = 0; i < 64; ++i) {
        unsigned short lo = u[2 * i];
        int e = (lo >> 7) & 0xFF;
        if (e >= 110 && e <= 137) ++sane;
    }
    flags[0] = (sane >= 32) ? 1 : 0;
    const int* w = (const int*)vtx;
    int zeros = 0;
    for (int i = 0; i < 64; ++i)
        if (w[2 * i + 1] == 0) ++zeros;
    flags[1] = (zeros >= 32) ? 1 : 0;
}

// ---------------- homo -> f32 -------------------------------------------------
__global__ void homof_kernel(const void* __restrict__ homo,
                             const int* __restrict__ flags,
                             float* __restrict__ homof, int E) {
    int i = blockIdx.x * blockDim.x + threadIdx.x;
    if (i < E) homof[i] = loadF(homo, i, flags[0]);
}

// ---------------- GEMM: W in LDS, 4-row unroll; writes Xpb bf16 only ----------
__global__ __launch_bounds__(256)
void gemm_kernel(const void* __restrict__ X, const void* __restrict__ W,
                 const int* __restrict__ flags,
                 unsigned short* __restrict__ Xpb, int N) {
    __shared__ float Ws[64 * 64];
    __shared__ float Xs[16][64];
    const int bmode = flags[0];
    int tid = threadIdx.x;
    for (int j = tid; j < 4096; j += 256) Ws[j] = loadF(W, j, bmode);
    __syncthreads();
    int lane = tid & 63, w = tid >> 6;
    int wid = (blockIdx.x * 256 + tid) >> 6;
    int nw  = (gridDim.x * 256) >> 6;
    for (int r0 = wid * 4; r0 < N; r0 += nw * 4) {
        if (r0 + 4 <= N) {
            float acc0 = 0.f, acc1 = 0.f, acc2 = 0.f, acc3 = 0.f;
#pragma unroll
            for (int j = 0; j < 4; ++j)
                Xs[w * 4 + j][lane] = loadF(X, (size_t)(r0 + j) * 64 + lane, bmode);
#pragma unroll
            for (int k4 = 0; k4 < 16; ++k4) {
                float4 x0 = *(const float4*)&Xs[w * 4 + 0][k4 * 4];
                float4 x1 = *(const float4*)&Xs[w * 4 + 1][k4 * 4];
                float4 x2 = *(const float4*)&Xs[w * 4 + 2][k4 * 4];
                float4 x3 = *(const float4*)&Xs[w * 4 + 3][k4 * 4];
#pragma unroll
                for (int kk = 0; kk < 4; ++kk) {
                    float wv = Ws[(k4 * 4 + kk) * 64 + lane];
                    acc0 = fmaf((&x0.x)[kk], wv, acc0);
                    acc1 = fmaf((&x1.x)[kk], wv, acc1);
                    acc2 = fmaf((&x2.x)[kk], wv, acc2);
                    acc3 = fmaf((&x3.x)[kk], wv, acc3);
                }
            }
            float a[4] = {acc0, acc1, acc2, acc3};
#pragma unroll
            for (int j = 0; j < 4; ++j)
                Xpb[(size_t)(r0 + j) * 64 + lane] = f2bf(a[j]);
        } else {
            for (int r = r0; r < N; ++r) {
                Xs[w * 4][lane] = loadF(X, (size_t)r * 64 + lane, bmode);
                float acc = 0.f;
                for (int k = 0; k < 64; ++k)
                    acc = fmaf(Xs[w * 4][k], Ws[k * 64 + lane], acc);
                Xpb[(size_t)r * 64 + lane] = f2bf(acc);
            }
        }
    }
}

// ------- coarse-bucket histogram; also stores per-(chunk,bucket) counts -------
__global__ __launch_bounds__(1024)
void bhist_kernel(const void* __restrict__ edges, const void* __restrict__ vertex,
                  const int* __restrict__ flags, int* __restrict__ btot,
                  int* __restrict__ slabc, int sstride,
                  int nnz, int NBE, int NBV, int GC) {
    __shared__ int cnt[MAXB];
    int blk  = blockIdx.x;
    int side = (blk >= GC) ? 1 : 0;
    int b    = side ? blk - GC : blk;
    const void* keys = side ? vertex : edges;
    int sblog = side ? SV_LOG : SE_LOG;
    int nb    = side ? NBV : NBE;
    int bas   = side ? NBE : 0;
    int tid = threadIdx.x;
    for (int j = tid; j < nb; j += 1024) cnt[j] = 0;
    __syncthreads();
    int imode = flags[1];
    int c0 = b * CH, c1 = min(nnz, c0 + CH);
    for (int i = c0 + tid; i < c1; i += 1024)
        atomicAdd(&cnt[loadI(keys, i, imode) >> sblog], 1);
    __syncthreads();
    for (int j = tid; j < nb; j += 1024) {
        int c = cnt[j];
        slabc[(size_t)blk * sstride + j] = c;
        if (c) atomicAdd(&btot[bas + j], c);
    }
}

// ---------------- tiny scan over bucket totals -> bases + cursors ------------
__global__ void bscan_kernel(const int* __restrict__ btot, int* __restrict__ bbase,
                             int* __restrict__ bcur, int NBT) {
    __shared__ int wsum[16];
    __shared__ int carry_s;
    int tid = threadIdx.x, lane = tid & 63, w = tid >> 6;
    if (tid == 0) carry_s = 0;
    __syncthreads();
    for (int base = 0; base < NBT; base += 1024) {
        int i = base + tid;
        int x = (i < NBT) ? btot[i] : 0;
        int s = x;
#pragma unroll
        for (int d = 1; d < 64; d <<= 1) {
            int t = __shfl_up(s, d, 64);
            if (lane >= d) s += t;
        }
        if (lane == 63) wsum[w] = s;
        __syncthreads();
        if (w == 0 && lane < 16) {
            int v = wsum[lane];
#pragma unroll
            for (int d = 1; d < 16; d <<= 1) {
                int t = __shfl_up(v, d, 64);
                if (lane >= d) v += t;
            }
            wsum[lane] = v;
        }
        __syncthreads();
        int carry = carry_s;
        int excl  = carry + (w > 0 ? wsum[w - 1] : 0) + s - x;
        if (i < NBT) { bbase[i] = excl; bcur[i] = excl; }
        __syncthreads();
        if (tid == 1023) carry_s = carry + wsum[15];
        __syncthreads();
    }
    if (tid == 0) bbase[NBT] = carry_s;
}

// ------- pass1: chunk -> coarse buckets, packed (local_bin<<psh | payload) ----
__global__ __launch_bounds__(1024)
void bscatter_kernel(const void* __restrict__ edges, const void* __restrict__ vertex,
                     const int* __restrict__ flags, int* __restrict__ bcur,
                     const int* __restrict__ slabc, int sstride,
                     int* __restrict__ buck, int nnz, int NBE, int NBV, int GC,
                     int bitsN, int bitsE) {
    __shared__ int cnt[MAXB];
    __shared__ int gb[MAXB];
    int blk  = blockIdx.x;
    int side = (blk >= GC) ? 1 : 0;
    int b    = side ? blk - GC : blk;
    const void* keys = side ? vertex : edges;
    const void* pay  = side ? edges  : vertex;
    int sblog = side ? SV_LOG : SE_LOG;
    int psh   = side ? bitsE : bitsN;
    int nb    = side ? NBV : NBE;
    int bas   = side ? NBE : 0;
    int tid = threadIdx.x;
    for (int j = tid; j < nb; j += 1024) {
        int c = slabc[(size_t)blk * sstride + j];
        gb[j]  = c ? atomicAdd(&bcur[bas + j], c) : 0;
        cnt[j] = 0;
    }
    __syncthreads();
    int imode = flags[1];
    int c0 = b * CH, c1 = min(nnz, c0 + CH);
    int lmask = (1 << sblog) - 1;
    for (int i = c0 + tid; i < c1; i += 1024) {
        int k   = loadI(keys, i, imode);
        int bkt = k >> sblog;
        int r   = atomicAdd(&cnt[bkt], 1);
        buck[gb[bkt] + r] = ((k & lmask) << psh) | loadI(pay, i, imode);
    }
}

// ------- pass2: one block per bucket -> off[], dest[]; vertex side also hs[] --
__global__ __launch_bounds__(1024)
void bfinal_kernel(const int* __restrict__ buck, const int* __restrict__ bbase,
                   const float* __restrict__ homof,
                   int* __restrict__ off, int* __restrict__ dest,
                   float* __restrict__ hs,
                   int NBE, int NBV, int E, int N, int bitsN, int bitsE) {
    __shared__ int cnt[1 << SV_LOG];
    __shared__ int sexc[1 << SV_LOG];
    __shared__ float hsum[1 << SV_LOG];
    __shared__ int wsum[16];
    int g    = blockIdx.x;
    int side = (g >= NBE) ? 1 : 0;
    int b    = side ? g - NBE : g;
    int sblog = side ? SV_LOG : SE_LOG;
    int psh   = side ? bitsE : bitsN;
    int pmask = (1 << psh) - 1;
    int nside = side ? N : E;
    int bin0  = b << sblog;
    int nbins = min(1 << sblog, nside - bin0);
    int goff0 = (side ? E : 0) + bin0;
    int s0 = bbase[g], s1 = bbase[g + 1], size = s1 - s0;
    int tid = threadIdx.x, lane = tid & 63, w = tid >> 6;
    for (int j = tid; j < nbins; j += 1024) { cnt[j] = 0; hsum[j] = 0.f; }
    __syncthreads();
    for (int j = tid; j < size; j += 1024)
        atomicAdd(&cnt[buck[s0 + j] >> psh], 1);
    __syncthreads();
    {   // exclusive scan over nbins (<= 512 < 1024)
        int x = (tid < nbins) ? cnt[tid] : 0;
        int s = x;
#pragma unroll
        for (int d = 1; d < 64; d <<= 1) {
            int t = __shfl_up(s, d, 64);
            if (lane >= d) s += t;
        }
        if (lane == 63) wsum[w] = s;
        __syncthreads();
        if (w == 0 && lane < 16) {
            int v = wsum[lane];
#pragma unroll
            for (int d = 1; d < 16; d <<= 1) {
                int t = __shfl_up(v, d, 64);
                if (lane >= d) v += t;
            }
            wsum[lane] = v;
        }
        __syncthreads();
        int excl = s - x + (w > 0 ? wsum[w - 1] : 0);
        if (tid < nbins) { sexc[tid] = excl; off[goff0 + tid] = s0 + excl; }
    }
    if (side == 1 && b == NBV - 1 && tid == 0) off[E + N] = s1;
    __syncthreads();
    for (int j = tid; j < nbins; j += 1024) cnt[j] = sexc[j];
    __syncthreads();
    if (side == 1) {
        for (int j = tid; j < size; j += 1024) {
            int p  = buck[s0 + j];
            int lb = p >> psh;
            int r  = atomicAdd(&cnt[lb], 1);
            int e  = p & pmask;
            dest[s0 + r] = e;
            atomicAdd(&hsum[lb], homof[e]);
        }
        __syncthreads();
        for (int j = tid; j < nbins; j += 1024) hs[bin0 + j] = hsum[j];
    } else {
        for (int j = tid; j < size; j += 1024) {
            int p = buck[s0 + j];
            int r = atomicAdd(&cnt[p >> psh], 1);
            dest[s0 + r] = p & pmask;
        }
    }
}

// ---------------- fallback (global-atomic) CSR build -------------------------
__global__ void hist_atomic_kernel(const void* __restrict__ edges,
                                   const void* __restrict__ vertex,
                                   const int* __restrict__ flags,
                                   int* __restrict__ tot, int E, int nnz) {
    int i = blockIdx.x * blockDim.x + threadIdx.x;
    if (i >= nnz) return;
    int imode = flags[1];
    atomicAdd(&tot[loadI(edges, i, imode)], 1);
    atomicAdd(&tot[E + loadI(vertex, i, imode)], 1);
}

__global__ void scan_part_kernel(const int* __restrict__ tot, int* __restrict__ part, int M) {
    int g = blockIdx.x, tid = threadIdx.x;
    int base = g * 2048;
    int sum = 0;
    for (int j = tid; j < 2048; j += 256) {
        int i = base + j;
        sum += (i < M) ? tot[i] : 0;
    }
#pragma unroll
    for (int d = 32; d >= 1; d >>= 1) sum += __shfl_xor(sum, d, 64);
    __shared__ int wsums[4];
    int lane = tid & 63, w = tid >> 6;
    if (lane == 0) wsums[w] = sum;
    __syncthreads();
    if (tid == 0) part[g] = wsums[0] + wsums[1] + wsums[2] + wsums[3];
}

__global__ void scan_root_kernel(int* __restrict__ part, int G,
                                 int* __restrict__ off, int M) {
    int tid = threadIdx.x, lane = tid & 63, w = tid >> 6;
    int x = (tid < G) ? part[tid] : 0;
    int s = x;
#pragma unroll
    for (int d = 1; d < 64; d <<= 1) {
        int t = __shfl_up(s, d, 64);
        if (lane >= d) s += t;
    }
    __shared__ int ws[16];
    if (lane == 63) ws[w] = s;
    __syncthreads();
    if (w == 0 && lane < 16) {
        int v = ws[lane];
#pragma unroll
        for (int d = 1; d < 16; d <<= 1) {
            int t = __shfl_up(v, d, 64);
            if (lane >= d) v += t;
        }
        ws[lane] = v;
    }
    __syncthreads();
    int excl = s - x + (w > 0 ? ws[w - 1] : 0);
    if (tid < G) part[tid] = excl;
    if (tid == 1023) off[M] = ws[15];
}

__global__ void scan_apply_kernel(int* __restrict__ tot, const int* __restrict__ part,
                                  int* __restrict__ off, int M) {
    int g = blockIdx.x, tid = threadIdx.x, lane = tid & 63, w = tid >> 6;
    int base = g * 2048 + tid * 8;
    int e[8]; int s = 0;
#pragma unroll
    for (int j = 0; j < 8; ++j) {
        int i = base + j;
        e[j] = (i < M) ? tot[i] : 0;
        s += e[j];
    }
    int si = s;
#pragma unroll
    for (int d = 1; d < 64; d <<= 1) {
        int t = __shfl_up(si, d, 64);
        if (lane >= d) si += t;
    }
    __shared__ int wsum[4];
    if (lane == 63) wsum[w] = si;
    __syncthreads();
    int wbase = 0;
    for (int ww = 0; ww < w; ++ww) wbase += wsum[ww];
    int run = part[g] + wbase + si - s;
#pragma unroll
    for (int j = 0; j < 8; ++j) {
        int i = base + j;
        if (i < M) off[i] = run;
        run += e[j];
    }
}

__global__ void copy_kernel(const int* __restrict__ src, int* __restrict__ dst, int n) {
    int i = blockIdx.x * blockDim.x + threadIdx.x;
    if (i < n) dst[i] = src[i];
}

__global__ void scatter_atomic_kernel(const void* __restrict__ edges,
                                      const void* __restrict__ vertex,
                                      const int* __restrict__ flags,
                                      int* __restrict__ cur, int* __restrict__ dest,
                                      int E, int nnz) {
    int i = blockIdx.x * blockDim.x + threadIdx.x;
    if (i >= nnz) return;
    int imode = flags[1];
    int e = loadI(edges, i, imode);
    int v = loadI(vertex, i, imode);
    dest[atomicAdd(&cur[e], 1)]     = v;
    dest[atomicAdd(&cur[E + v], 1)] = e;
}

__global__ void hs_fallback_kernel(const int* __restrict__ off,
                                   const int* __restrict__ sorted,
                                   const float* __restrict__ homof,
                                   float* __restrict__ hs, int E, int N) {
    int v = blockIdx.x * blockDim.x + threadIdx.x;
    if (v >= N) return;
    int s = off[E + v], e = off[E + v + 1];
    float t = 0.f;
    for (int j = s; j < e; ++j) t += homof[sorted[j]];
    hs[v] = t;
}

// -- Ye[e,:] = homo[e] * mean_{v in e} Xpb[v,:]   (4 groups x 16, unroll x4) --
__global__ void edge_mean_kernel(const unsigned short* __restrict__ Xpb,
                                 const int* __restrict__ off,
                                 const int* __restrict__ sorted,
                                 const float* __restrict__ homof,
                                 unsigned short* __restrict__ Ye, int E) {
    int wid  = (blockIdx.x * blockDim.x + threadIdx.x) >> 6;
    int lane = threadIdx.x & 63;
    if (wid >= E) return;
    int g = lane >> 4, c = lane & 15;
    unsigned co = (unsigned)c << 3;
    int start = off[wid], end = off[wid + 1];
    float a0 = 0.f, a1 = 0.f, a2 = 0.f, a3 = 0.f;
    const char* Xb = (const char*)Xpb;
    int j = start + g;
    for (; j + 12 < end; j += 16) {      // four independent chains in flight
        int v0 = sorted[j];
        int v1 = sorted[j + 4];
        int v2 = sorted[j + 8];
        int v3 = sorted[j + 12];
        uint2 u0 = *(const uint2*)(Xb + (((unsigned)v0 << 7) + co));
        uint2 u1 = *(const uint2*)(Xb + (((unsigned)v1 << 7) + co));
        uint2 u2 = *(const uint2*)(Xb + (((unsigned)v2 << 7) + co));
        uint2 u3 = *(const uint2*)(Xb + (((unsigned)v3 << 7) + co));
        a0 += (bflo(u0.x) + bflo(u1.x)) + (bflo(u2.x) + bflo(u3.x));
        a1 += (bfhi(u0.x) + bfhi(u1.x)) + (bfhi(u2.x) + bfhi(u3.x));
        a2 += (bflo(u0.y) + bflo(u1.y)) + (bflo(u2.y) + bflo(u3.y));
        a3 += (bfhi(u0.y) + bfhi(u1.y)) + (bfhi(u2.y) + bfhi(u3.y));
    }
    for (; j < end; j += 4) {
        int v = sorted[j];
        uint2 u = *(const uint2*)(Xb + (((unsigned)v << 7) + co));
        a0 += bflo(u.x); a1 += bfhi(u.x);
        a2 += bflo(u.y); a3 += bfhi(u.y);
    }
    a0 += __shfl_xor(a0, 16, 64); a0 += __shfl_xor(a0, 32, 64);
    a1 += __shfl_xor(a1, 16, 64); a1 += __shfl_xor(a1, 32, 64);
    a2 += __shfl_xor(a2, 16, 64); a2 += __shfl_xor(a2, 32, 64);
    a3 += __shfl_xor(a3, 16, 64); a3 += __shfl_xor(a3, 32, 64);
    if (g == 0) {
        float inv = homof[wid] / fmaxf((float)(end - start), 1.f);
        unsigned p0 = (unsigned)f2bf(a0 * inv) | ((unsigned)f2bf(a1 * inv) << 16);
        unsigned p1 = (unsigned)f2bf(a2 * inv) | ((unsigned)f2bf(a3 * inv) << 16);
        *(uint2*)((char*)Ye + (((unsigned)wid << 7) + co)) = make_uint2(p0, p1);
    }
}

// -- out[v,:] = rowL2norm( Xpb + (sum Ye)/hs[v] )  (unroll x4, bf16 residual) -
__global__ void vertex_out_kernel(const unsigned short* __restrict__ Xpb,
                                  const unsigned short* __restrict__ Ye,
                                  const int* __restrict__ off,
                                  const int* __restrict__ sorted,
                                  const float* __restrict__ hs,
                                  float* __restrict__ out, int E, int N) {
    int wid  = (blockIdx.x * blockDim.x + threadIdx.x) >> 6;
    int lane = threadIdx.x & 63;
    if (wid >= N) return;
    int g = lane >> 4, c = lane & 15;
    unsigned co = (unsigned)c << 3;
    int start = off[E + wid], end = off[E + wid + 1];
    float a0 = 0.f, a1 = 0.f, a2 = 0.f, a3 = 0.f;
    const char* Xb = (const char*)Ye;
    int j = start + g;
    for (; j + 12 < end; j += 16) {      // four independent chains in flight
        int e0 = sorted[j];
        int e1 = sorted[j + 4];
        int e2 = sorted[j + 8];
        int e3 = sorted[j + 12];
        uint2 u0 = *(const uint2*)(Xb + (((unsigned)e0 << 7) + co));
        uint2 u1 = *(const uint2*)(Xb + (((unsigned)e1 << 7) + co));
        uint2 u2 = *(const uint2*)(Xb + (((unsigned)e2 << 7) + co));
        uint2 u3 = *(const uint2*)(Xb + (((unsigned)e3 << 7) + co));
        a0 += (bflo(u0.x) + bflo(u1.x)) + (bflo(u2.x) + bflo(u3.x));
        a1 += (bfhi(u0.x) + bfhi(u1.x)) + (bfhi(u2.x) + bfhi(u3.x));
        a2 += (bflo(u0.y) + bflo(u1.y)) + (bflo(u2.y) + bflo(u3.y));
        a3 += (bfhi(u0.y) + bfhi(u1.y)) + (bfhi(u2.y) + bfhi(u3.y));
    }
    for (; j < end; j += 4) {
        int e = sorted[j];
        uint2 u = *(const uint2*)(Xb + (((unsigned)e << 7) + co));
        a0 += bflo(u.x); a1 += bfhi(u.x);
        a2 += bflo(u.y); a3 += bfhi(u.y);
    }
    a0 += __shfl_xor(a0, 16, 64); a0 += __shfl_xor(a0, 32, 64);
    a1 += __shfl_xor(a1, 16, 64); a1 += __shfl_xor(a1, 32, 64);
    a2 += __shfl_xor(a2, 16, 64); a2 += __shfl_xor(a2, 32, 64);
    a3 += __shfl_xor(a3, 16, 64); a3 += __shfl_xor(a3, 32, 64);
    if (g == 0) {
        float hsv = hs[wid];
        float inv = (hsv > 0.f) ? 1.f / hsv : 0.f;
        uint2 xu = *(const uint2*)((const char*)Xpb + (((unsigned)wid << 7) + co));
        float r0 = bflo(xu.x) + a0 * inv, r1 = bfhi(xu.x) + a1 * inv;
        float r2 = bflo(xu.y) + a2 * inv, r3 = bfhi(xu.y) + a3 * inv;
        float ss = r0 * r0 + r1 * r1 + r2 * r2 + r3 * r3;
        ss += __shfl_xor(ss, 1, 64); ss += __shfl_xor(ss, 2, 64);
        ss += __shfl_xor(ss, 4, 64); ss += __shfl_xor(ss, 8, 64);
        float rn    = sqrtf(ss);
        float scale = (rn > 0.f) ? 1.f / fmaxf(rn, 1e-30f) : 0.f;
        float4 o = make_float4(r0 * scale, r1 * scale, r2 * scale, r3 * scale);
        *(float4*)((char*)out + (((unsigned)wid << 8) + (co << 1))) = o;
    }
}

static inline int ceil_bits(int n) {
    int v = n - 1;
    if (v < 1) v = 1;
    int b = 0;
    while ((1 << b) <= v) ++b;
    return b;
}

extern "C" void kernel_launch(void* const* d_in, const int* in_sizes, int n_in,
                              void* d_out, int out_size, void* d_ws, size_t ws_size,
                              hipStream_t stream) {
    const void* X      = d_in[0];
    const void* W      = d_in[1];
    const void* homo   = d_in[2];
    const void* vertex = d_in[3];
    const void* edges  = d_in[4];
    float* out = (float*)d_out;

    const int N   = in_sizes[0] / 64;
    const int E   = in_sizes[2];
    const int NNZ = in_sizes[3];
    const int M   = E + N;

    const int NBE = (E + (1 << SE_LOG) - 1) >> SE_LOG;
    const int NBV = (N + (1 << SV_LOG) - 1) >> SV_LOG;
    const int NBT = NBE + NBV;
    const int GC  = (NNZ + CH - 1) / CH;
    const int SST = (NBE > NBV ? NBE : NBV);      // slab stride
    const int bitsN = ceil_bits(N);
    const int bitsE = ceil_bits(E);
    const int G   = (M + 2047) / 2048;  // fallback scan tiles

    char*  ws = (char*)d_ws;
    size_t o  = 0;
    auto alloc = [&](size_t bytes) -> void* {
        void* p = ws + o;
        o += (bytes + 255) & ~(size_t)255;
        return p;
    };
    int*            flags = (int*)alloc(2 * 4);
    int*            off   = (int*)alloc((size_t)(M + 1) * 4);
    int*            bbase = (int*)alloc((size_t)(NBT + 1) * 4);
    int*            bcur  = (int*)alloc((size_t)NBT * 4);
    int*            btot  = (int*)alloc((size_t)NBT * 4);
    float*          homof = (float*)alloc((size_t)E * 4);
    float*          hs    = (float*)alloc((size_t)N * 4);
    int*            buck  = (int*)alloc((size_t)2 * NNZ * 4);
    int*            sorted= (int*)alloc((size_t)2 * NNZ * 4);
    unsigned short* Xpb   = (unsigned short*)alloc((size_t)N * 64 * 2);
    unsigned short* Ye    = (unsigned short*)alloc((size_t)E * 64 * 2);
    int*            slabc = (int*)alloc((size_t)2 * GC * SST * 4);
    size_t o_common = o;
    bool fast = (o <= ws_size) && NBE <= MAXB && NBV <= MAXB &&
                (SE_LOG + bitsN <= 32) && (SV_LOG + bitsE <= 32) && G <= 1024;
    (void)n_in; (void)out_size;

    sniff_kernel<<<1, 64, 0, stream>>>(X, vertex, flags);
    homof_kernel<<<(E + 255) / 256, 256, 0, stream>>>(homo, flags, homof, E);
    gemm_kernel<<<512, 256, 0, stream>>>(X, W, flags, Xpb, N);

    if (fast) {
        hipMemsetAsync(btot, 0, (size_t)NBT * 4, stream);
        bhist_kernel<<<2 * GC, 1024, 0, stream>>>(edges, vertex, flags, btot,
                                                  slabc, SST, NNZ, NBE, NBV, GC);
        bscan_kernel<<<1, 1024, 0, stream>>>(btot, bbase, bcur, NBT);
        bscatter_kernel<<<2 * GC, 1024, 0, stream>>>(edges, vertex, flags, bcur,
                                                     slabc, SST, buck, NNZ,
                                                     NBE, NBV, GC, bitsN, bitsE);
        bfinal_kernel<<<NBT, 1024, 0, stream>>>(buck, bbase, homof, off, sorted,
                                                hs, NBE, NBV, E, N, bitsN, bitsE);
    } else {
        o = o_common;
        int* tot  = (int*)alloc((size_t)M * 4);
        int* part = (int*)alloc((size_t)(G + 1) * 4);
        int* cur  = (int*)alloc((size_t)M * 4);
        hipMemsetAsync(tot, 0, (size_t)M * 4, stream);
        int nb = (NNZ + 255) / 256;
        hist_atomic_kernel<<<nb, 256, 0, stream>>>(edges, vertex, flags, tot, E, NNZ);
        scan_part_kernel<<<G, 256, 0, stream>>>(tot, part, M);
        scan_root_kernel<<<1, 1024, 0, stream>>>(part, G, off, M);
        scan_apply_kernel<<<G, 256, 0, stream>>>(tot, part, off, M);
        copy_kernel<<<(M + 255) / 256, 256, 0, stream>>>(off, cur, M);
        scatter_atomic_kernel<<<nb, 256, 0, stream>>>(edges, vertex, flags, cur, sorted, E, NNZ);
        hs_fallback_kernel<<<(N + 255) / 256, 256, 0, stream>>>(off, sorted, homof, hs, E, N);
    }

    edge_mean_kernel<<<(E + 3) / 4, 256, 0, stream>>>(Xpb, off, sorted, homof, Ye, E);
    vertex_out_kernel<<<(N + 3) / 4, 256, 0, stream>>>(Xpb, Ye, off, sorted,
                                                       hs, out, E, N);
}

// Round 11
// 264.840 us; speedup vs baseline: 2.0416x; 1.0580x over previous
//
#include <hip/hip_runtime.h>
#include <hip/hip_bf16.h>

// Hypergraph conv:  Xp = X@W;  Xe = mean_{v in e} Xp[v];
// Xv[v] = (sum_{e ∋ v} homo[e]*Xe[e]) / (sum_{e ∋ v} homo[e]);  out = rowL2norm(Xp+Xv)
//
// R10 lesson: vertex_out is wave-count/epilogue-bound, not bytes/chains-bound.
// R11: vertex_out = 8 groups x 8 lanes, group-per-vertex, uint4 row loads
// (no cross-group reductions, epilogue on all lanes, 12.5K waves not 100K).
// Sort stages get more blocks for CU coverage (CH 8192; smaller buckets).

#define SE_LOG 6          // edges per bucket = 64
#define SV_LOG 8          // vertices per bucket = 256
#define MAXB   2048       // max coarse buckets per side (LDS counters)
#define CH     8192       // incidences per pass-1 block

__device__ __forceinline__ float bf2f(unsigned short u) {
    union { unsigned int i; float f; } x;
    x.i = ((unsigned int)u) << 16;
    return x.f;
}

__device__ __forceinline__ float bflo(unsigned int u) {
    union { unsigned int i; float f; } x;
    x.i = u << 16;
    return x.f;
}

__device__ __forceinline__ float bfhi(unsigned int u) {
    union { unsigned int i; float f; } x;
    x.i = u & 0xffff0000u;
    return x.f;
}

__device__ __forceinline__ unsigned short f2bf(float f) {
    union { unsigned int i; float ff; } x;
    x.ff = f;
    unsigned int r = x.i + 0x7fff + ((x.i >> 16) & 1);
    return (unsigned short)(r >> 16);
}

__device__ __forceinline__ float loadF(const void* p, size_t i, int bf16mode) {
    return bf16mode ? bf2f(((const unsigned short*)p)[i]) : ((const float*)p)[i];
}

__device__ __forceinline__ int loadI(const void* p, size_t i, int i64mode) {
    return i64mode ? ((const int*)p)[2 * i] : ((const int*)p)[i];
}

// ---------------- dtype sniff: flags[0]=floats-are-bf16, flags[1]=indices-are-i64
__global__ void sniff_kernel(const void* X, const void* vtx, int* flags) {
    if (threadIdx.x != 0 || blockIdx.x != 0) return;
    const unsigned short* u = (const unsigned short*)X;
    int sane = 0;
    for (int i = 0; i < 64; ++i) {
        unsigned short lo = u[2 * i];
        int e = (lo >> 7) & 0xFF;
        if (e >= 110 && e <= 137) ++sane;
    }
    flags[0] = (sane >= 32) ? 1 : 0;
    const int* w = (const int*)vtx;
    int zeros = 0;
    for (int i = 0; i < 64; ++i)
        if (w[2 * i + 1] == 0) ++zeros;
    flags[1] = (zeros >= 32) ? 1 : 0;
}

// ---------------- homo -> f32 -------------------------------------------------
__global__ void homof_kernel(const void* __restrict__ homo,
                             const int* __restrict__ flags,
                             float* __restrict__ homof, int E) {
    int i = blockIdx.x * blockDim.x + threadIdx.x;
    if (i < E) homof[i] = loadF(homo, i, flags[0]);
}

// ---------------- GEMM: W in LDS, 4-row unroll; writes Xpb bf16 only ----------
__global__ __launch_bounds__(256)
void gemm_kernel(const void* __restrict__ X, const void* __restrict__ W,
                 const int* __restrict__ flags,
                 unsigned short* __restrict__ Xpb, int N) {
    __shared__ float Ws[64 * 64];
    __shared__ float Xs[16][64];
    const int bmode = flags[0];
    int tid = threadIdx.x;
    for (int j = tid; j < 4096; j += 256) Ws[j] = loadF(W, j, bmode);
    __syncthreads();
    int lane = tid & 63, w = tid >> 6;
    int wid = (blockIdx.x * 256 + tid) >> 6;
    int nw  = (gridDim.x * 256) >> 6;
    for (int r0 = wid * 4; r0 < N; r0 += nw * 4) {
        if (r0 + 4 <= N) {
            float acc0 = 0.f, acc1 = 0.f, acc2 = 0.f, acc3 = 0.f;
#pragma unroll
            for (int j = 0; j < 4; ++j)
                Xs[w * 4 + j][lane] = loadF(X, (size_t)(r0 + j) * 64 + lane, bmode);
#pragma unroll
            for (int k4 = 0; k4 < 16; ++k4) {
                float4 x0 = *(const float4*)&Xs[w * 4 + 0][k4 * 4];
                float4 x1 = *(const float4*)&Xs[w * 4 + 1][k4 * 4];
                float4 x2 = *(const float4*)&Xs[w * 4 + 2][k4 * 4];
                float4 x3 = *(const float4*)&Xs[w * 4 + 3][k4 * 4];
#pragma unroll
                for (int kk = 0; kk < 4; ++kk) {
                    float wv = Ws[(k4 * 4 + kk) * 64 + lane];
                    acc0 = fmaf((&x0.x)[kk], wv, acc0);
                    acc1 = fmaf((&x1.x)[kk], wv, acc1);
                    acc2 = fmaf((&x2.x)[kk], wv, acc2);
                    acc3 = fmaf((&x3.x)[kk], wv, acc3);
                }
            }
            float a[4] = {acc0, acc1, acc2, acc3};
#pragma unroll
            for (int j = 0; j < 4; ++j)
                Xpb[(size_t)(r0 + j) * 64 + lane] = f2bf(a[j]);
        } else {
            for (int r = r0; r < N; ++r) {
                Xs[w * 4][lane] = loadF(X, (size_t)r * 64 + lane, bmode);
                float acc = 0.f;
                for (int k = 0; k < 64; ++k)
                    acc = fmaf(Xs[w * 4][k], Ws[k * 64 + lane], acc);
                Xpb[(size_t)r * 64 + lane] = f2bf(acc);
            }
        }
    }
}

// ------- coarse-bucket histogram; also stores per-(chunk,bucket) counts -------
__global__ __launch_bounds__(1024)
void bhist_kernel(const void* __restrict__ edges, const void* __restrict__ vertex,
                  const int* __restrict__ flags, int* __restrict__ btot,
                  int* __restrict__ slabc, int sstride,
                  int nnz, int NBE, int NBV, int GC) {
    __shared__ int cnt[MAXB];
    int blk  = blockIdx.x;
    int side = (blk >= GC) ? 1 : 0;
    int b    = side ? blk - GC : blk;
    const void* keys = side ? vertex : edges;
    int sblog = side ? SV_LOG : SE_LOG;
    int nb    = side ? NBV : NBE;
    int bas   = side ? NBE : 0;
    int tid = threadIdx.x;
    for (int j = tid; j < nb; j += 1024) cnt[j] = 0;
    __syncthreads();
    int imode = flags[1];
    int c0 = b * CH, c1 = min(nnz, c0 + CH);
    for (int i = c0 + tid; i < c1; i += 1024)
        atomicAdd(&cnt[loadI(keys, i, imode) >> sblog], 1);
    __syncthreads();
    for (int j = tid; j < nb; j += 1024) {
        int c = cnt[j];
        slabc[(size_t)blk * sstride + j] = c;
        if (c) atomicAdd(&btot[bas + j], c);
    }
}

// ---------------- tiny scan over bucket totals -> bases + cursors ------------
__global__ void bscan_kernel(const int* __restrict__ btot, int* __restrict__ bbase,
                             int* __restrict__ bcur, int NBT) {
    __shared__ int wsum[16];
    __shared__ int carry_s;
    int tid = threadIdx.x, lane = tid & 63, w = tid >> 6;
    if (tid == 0) carry_s = 0;
    __syncthreads();
    for (int base = 0; base < NBT; base += 1024) {
        int i = base + tid;
        int x = (i < NBT) ? btot[i] : 0;
        int s = x;
#pragma unroll
        for (int d = 1; d < 64; d <<= 1) {
            int t = __shfl_up(s, d, 64);
            if (lane >= d) s += t;
        }
        if (lane == 63) wsum[w] = s;
        __syncthreads();
        if (w == 0 && lane < 16) {
            int v = wsum[lane];
#pragma unroll
            for (int d = 1; d < 16; d <<= 1) {
                int t = __shfl_up(v, d, 64);
                if (lane >= d) v += t;
            }
            wsum[lane] = v;
        }
        __syncthreads();
        int carry = carry_s;
        int excl  = carry + (w > 0 ? wsum[w - 1] : 0) + s - x;
        if (i < NBT) { bbase[i] = excl; bcur[i] = excl; }
        __syncthreads();
        if (tid == 1023) carry_s = carry + wsum[15];
        __syncthreads();
    }
    if (tid == 0) bbase[NBT] = carry_s;
}

// ------- pass1: chunk -> coarse buckets, packed (local_bin<<psh | payload) ----
__global__ __launch_bounds__(1024)
void bscatter_kernel(const void* __restrict__ edges, const void* __restrict__ vertex,
                     const int* __restrict__ flags, int* __restrict__ bcur,
                     const int* __restrict__ slabc, int sstride,
                     int* __restrict__ buck, int nnz, int NBE, int NBV, int GC,
                     int bitsN, int bitsE) {
    __shared__ int cnt[MAXB];
    __shared__ int gb[MAXB];
    int blk  = blockIdx.x;
    int side = (blk >= GC) ? 1 : 0;
    int b    = side ? blk - GC : blk;
    const void* keys = side ? vertex : edges;
    const void* pay  = side ? edges  : vertex;
    int sblog = side ? SV_LOG : SE_LOG;
    int psh   = side ? bitsE : bitsN;
    int nb    = side ? NBV : NBE;
    int bas   = side ? NBE : 0;
    int tid = threadIdx.x;
    for (int j = tid; j < nb; j += 1024) {
        int c = slabc[(size_t)blk * sstride + j];
        gb[j]  = c ? atomicAdd(&bcur[bas + j], c) : 0;
        cnt[j] = 0;
    }
    __syncthreads();
    int imode = flags[1];
    int c0 = b * CH, c1 = min(nnz, c0 + CH);
    int lmask = (1 << sblog) - 1;
    for (int i = c0 + tid; i < c1; i += 1024) {
        int k   = loadI(keys, i, imode);
        int bkt = k >> sblog;
        int r   = atomicAdd(&cnt[bkt], 1);
        buck[gb[bkt] + r] = ((k & lmask) << psh) | loadI(pay, i, imode);
    }
}

// ------- pass2: one block per bucket -> off[], dest[]; vertex side also hs[] --
__global__ __launch_bounds__(1024)
void bfinal_kernel(const int* __restrict__ buck, const int* __restrict__ bbase,
                   const float* __restrict__ homof,
                   int* __restrict__ off, int* __restrict__ dest,
                   float* __restrict__ hs,
                   int NBE, int NBV, int E, int N, int bitsN, int bitsE) {
    __shared__ int cnt[1 << SV_LOG];
    __shared__ int sexc[1 << SV_LOG];
    __shared__ float hsum[1 << SV_LOG];
    __shared__ int wsum[16];
    int g    = blockIdx.x;
    int side = (g >= NBE) ? 1 : 0;
    int b    = side ? g - NBE : g;
    int sblog = side ? SV_LOG : SE_LOG;
    int psh   = side ? bitsE : bitsN;
    int pmask = (1 << psh) - 1;
    int nside = side ? N : E;
    int bin0  = b << sblog;
    int nbins = min(1 << sblog, nside - bin0);
    int goff0 = (side ? E : 0) + bin0;
    int s0 = bbase[g], s1 = bbase[g + 1], size = s1 - s0;
    int tid = threadIdx.x, lane = tid & 63, w = tid >> 6;
    for (int j = tid; j < nbins; j += 1024) { cnt[j] = 0; hsum[j] = 0.f; }
    __syncthreads();
    for (int j = tid; j < size; j += 1024)
        atomicAdd(&cnt[buck[s0 + j] >> psh], 1);
    __syncthreads();
    {   // exclusive scan over nbins (<= 256 < 1024)
        int x = (tid < nbins) ? cnt[tid] : 0;
        int s = x;
#pragma unroll
        for (int d = 1; d < 64; d <<= 1) {
            int t = __shfl_up(s, d, 64);
            if (lane >= d) s += t;
        }
        if (lane == 63) wsum[w] = s;
        __syncthreads();
        if (w == 0 && lane < 16) {
            int v = wsum[lane];
#pragma unroll
            for (int d = 1; d < 16; d <<= 1) {
                int t = __shfl_up(v, d, 64);
                if (lane >= d) v += t;
            }
            wsum[lane] = v;
        }
        __syncthreads();
        int excl = s - x + (w > 0 ? wsum[w - 1] : 0);
        if (tid < nbins) { sexc[tid] = excl; off[goff0 + tid] = s0 + excl; }
    }
    if (side == 1 && b == NBV - 1 && tid == 0) off[E + N] = s1;
    __syncthreads();
    for (int j = tid; j < nbins; j += 1024) cnt[j] = sexc[j];
    __syncthreads();
    if (side == 1) {
        for (int j = tid; j < size; j += 1024) {
            int p  = buck[s0 + j];
            int lb = p >> psh;
            int r  = atomicAdd(&cnt[lb], 1);
            int e  = p & pmask;
            dest[s0 + r] = e;
            atomicAdd(&hsum[lb], homof[e]);
        }
        __syncthreads();
        for (int j = tid; j < nbins; j += 1024) hs[bin0 + j] = hsum[j];
    } else {
        for (int j = tid; j < size; j += 1024) {
            int p = buck[s0 + j];
            int r = atomicAdd(&cnt[p >> psh], 1);
            dest[s0 + r] = p & pmask;
        }
    }
}

// ---------------- fallback (global-atomic) CSR build -------------------------
__global__ void hist_atomic_kernel(const void* __restrict__ edges,
                                   const void* __restrict__ vertex,
                                   const int* __restrict__ flags,
                                   int* __restrict__ tot, int E, int nnz) {
    int i = blockIdx.x * blockDim.x + threadIdx.x;
    if (i >= nnz) return;
    int imode = flags[1];
    atomicAdd(&tot[loadI(edges, i, imode)], 1);
    atomicAdd(&tot[E + loadI(vertex, i, imode)], 1);
}

__global__ void scan_part_kernel(const int* __restrict__ tot, int* __restrict__ part, int M) {
    int g = blockIdx.x, tid = threadIdx.x;
    int base = g * 2048;
    int sum = 0;
    for (int j = tid; j < 2048; j += 256) {
        int i = base + j;
        sum += (i < M) ? tot[i] : 0;
    }
#pragma unroll
    for (int d = 32; d >= 1; d >>= 1) sum += __shfl_xor(sum, d, 64);
    __shared__ int wsums[4];
    int lane = tid & 63, w = tid >> 6;
    if (lane == 0) wsums[w] = sum;
    __syncthreads();
    if (tid == 0) part[g] = wsums[0] + wsums[1] + wsums[2] + wsums[3];
}

__global__ void scan_root_kernel(int* __restrict__ part, int G,
                                 int* __restrict__ off, int M) {
    int tid = threadIdx.x, lane = tid & 63, w = tid >> 6;
    int x = (tid < G) ? part[tid] : 0;
    int s = x;
#pragma unroll
    for (int d = 1; d < 64; d <<= 1) {
        int t = __shfl_up(s, d, 64);
        if (lane >= d) s += t;
    }
    __shared__ int ws[16];
    if (lane == 63) ws[w] = s;
    __syncthreads();
    if (w == 0 && lane < 16) {
        int v = ws[lane];
#pragma unroll
        for (int d = 1; d < 16; d <<= 1) {
            int t = __shfl_up(v, d, 64);
            if (lane >= d) v += t;
        }
        ws[lane] = v;
    }
    __syncthreads();
    int excl = s - x + (w > 0 ? ws[w - 1] : 0);
    if (tid < G) part[tid] = excl;
    if (tid == 1023) off[M] = ws[15];
}

__global__ void scan_apply_kernel(int* __restrict__ tot, const int* __restrict__ part,
                                  int* __restrict__ off, int M) {
    int g = blockIdx.x, tid = threadIdx.x, lane = tid & 63, w = tid >> 6;
    int base = g * 2048 + tid * 8;
    int e[8]; int s = 0;
#pragma unroll
    for (int j = 0; j < 8; ++j) {
        int i = base + j;
        e[j] = (i < M) ? tot[i] : 0;
        s += e[j];
    }
    int si = s;
#pragma unroll
    for (int d = 1; d < 64; d <<= 1) {
        int t = __shfl_up(si, d, 64);
        if (lane >= d) si += t;
    }
    __shared__ int wsum[4];
    if (lane == 63) wsum[w] = si;
    __syncthreads();
    int wbase = 0;
    for (int ww = 0; ww < w; ++ww) wbase += wsum[ww];
    int run = part[g] + wbase + si - s;
#pragma unroll
    for (int j = 0; j < 8; ++j) {
        int i = base + j;
        if (i < M) off[i] = run;
        run += e[j];
    }
}

__global__ void copy_kernel(const int* __restrict__ src, int* __restrict__ dst, int n) {
    int i = blockIdx.x * blockDim.x + threadIdx.x;
    if (i < n) dst[i] = src[i];
}

__global__ void scatter_atomic_kernel(const void* __restrict__ edges,
                                      const void* __restrict__ vertex,
                                      const int* __restrict__ flags,
                                      int* __restrict__ cur, int* __restrict__ dest,
                                      int E, int nnz) {
    int i = blockIdx.x * blockDim.x + threadIdx.x;
    if (i >= nnz) return;
    int imode = flags[1];
    int e = loadI(edges, i, imode);
    int v = loadI(vertex, i, imode);
    dest[atomicAdd(&cur[e], 1)]     = v;
    dest[atomicAdd(&cur[E + v], 1)] = e;
}

__global__ void hs_fallback_kernel(const int* __restrict__ off,
                                   const int* __restrict__ sorted,
                                   const float* __restrict__ homof,
                                   float* __restrict__ hs, int E, int N) {
    int v = blockIdx.x * blockDim.x + threadIdx.x;
    if (v >= N) return;
    int s = off[E + v], e = off[E + v + 1];
    float t = 0.f;
    for (int j = s; j < e; ++j) t += homof[sorted[j]];
    hs[v] = t;
}

// -- Ye[e,:] = homo[e] * mean_{v in e} Xpb[v,:]   (4 groups x 16, unroll x4) --
__global__ void edge_mean_kernel(const unsigned short* __restrict__ Xpb,
                                 const int* __restrict__ off,
                                 const int* __restrict__ sorted,
                                 const float* __restrict__ homof,
                                 unsigned short* __restrict__ Ye, int E) {
    int wid  = (blockIdx.x * blockDim.x + threadIdx.x) >> 6;
    int lane = threadIdx.x & 63;
    if (wid >= E) return;
    int g = lane >> 4, c = lane & 15;
    unsigned co = (unsigned)c << 3;
    int start = off[wid], end = off[wid + 1];
    float a0 = 0.f, a1 = 0.f, a2 = 0.f, a3 = 0.f;
    const char* Xb = (const char*)Xpb;
    int j = start + g;
    for (; j + 12 < end; j += 16) {      // four independent chains in flight
        int v0 = sorted[j];
        int v1 = sorted[j + 4];
        int v2 = sorted[j + 8];
        int v3 = sorted[j + 12];
        uint2 u0 = *(const uint2*)(Xb + (((unsigned)v0 << 7) + co));
        uint2 u1 = *(const uint2*)(Xb + (((unsigned)v1 << 7) + co));
        uint2 u2 = *(const uint2*)(Xb + (((unsigned)v2 << 7) + co));
        uint2 u3 = *(const uint2*)(Xb + (((unsigned)v3 << 7) + co));
        a0 += (bflo(u0.x) + bflo(u1.x)) + (bflo(u2.x) + bflo(u3.x));
        a1 += (bfhi(u0.x) + bfhi(u1.x)) + (bfhi(u2.x) + bfhi(u3.x));
        a2 += (bflo(u0.y) + bflo(u1.y)) + (bflo(u2.y) + bflo(u3.y));
        a3 += (bfhi(u0.y) + bfhi(u1.y)) + (bfhi(u2.y) + bfhi(u3.y));
    }
    for (; j < end; j += 4) {
        int v = sorted[j];
        uint2 u = *(const uint2*)(Xb + (((unsigned)v << 7) + co));
        a0 += bflo(u.x); a1 += bfhi(u.x);
        a2 += bflo(u.y); a3 += bfhi(u.y);
    }
    a0 += __shfl_xor(a0, 16, 64); a0 += __shfl_xor(a0, 32, 64);
    a1 += __shfl_xor(a1, 16, 64); a1 += __shfl_xor(a1, 32, 64);
    a2 += __shfl_xor(a2, 16, 64); a2 += __shfl_xor(a2, 32, 64);
    a3 += __shfl_xor(a3, 16, 64); a3 += __shfl_xor(a3, 32, 64);
    if (g == 0) {
        float inv = homof[wid] / fmaxf((float)(end - start), 1.f);
        unsigned p0 = (unsigned)f2bf(a0 * inv) | ((unsigned)f2bf(a1 * inv) << 16);
        unsigned p1 = (unsigned)f2bf(a2 * inv) | ((unsigned)f2bf(a3 * inv) << 16);
        *(uint2*)((char*)Ye + (((unsigned)wid << 7) + co)) = make_uint2(p0, p1);
    }
}

// -- out[v,:] = rowL2norm( Xpb + (sum Ye)/hs[v] )
//    8 groups x 8 lanes, GROUP-PER-VERTEX, uint4 row loads, unroll x4 ---------
__global__ void vertex_out_kernel(const unsigned short* __restrict__ Xpb,
                                  const unsigned short* __restrict__ Ye,
                                  const int* __restrict__ off,
                                  const int* __restrict__ sorted,
                                  const float* __restrict__ hs,
                                  float* __restrict__ out, int E, int N) {
    int wv   = (blockIdx.x * blockDim.x + threadIdx.x) >> 6;
    int lane = threadIdx.x & 63;
    int g = lane >> 3, c = lane & 7;
    int vid = wv * 8 + g;
    if (vid >= N) return;               // per-group exit via exec mask
    unsigned co = (unsigned)c << 4;     // 16 B per lane (8 bf16 channels)
    int start = off[E + vid], end = off[E + vid + 1];
    float a0 = 0.f, a1 = 0.f, a2 = 0.f, a3 = 0.f;
    float a4 = 0.f, a5 = 0.f, a6 = 0.f, a7 = 0.f;
    const char* Yb = (const char*)Ye;
    int j = start;
    for (; j + 3 < end; j += 4) {       // four independent chains per group
        int e0 = sorted[j], e1 = sorted[j + 1], e2 = sorted[j + 2], e3 = sorted[j + 3];
        uint4 u0 = *(const uint4*)(Yb + (((unsigned)e0 << 7) + co));
        uint4 u1 = *(const uint4*)(Yb + (((unsigned)e1 << 7) + co));
        uint4 u2 = *(const uint4*)(Yb + (((unsigned)e2 << 7) + co));
        uint4 u3 = *(const uint4*)(Yb + (((unsigned)e3 << 7) + co));
        a0 += (bflo(u0.x) + bflo(u1.x)) + (bflo(u2.x) + bflo(u3.x));
        a1 += (bfhi(u0.x) + bfhi(u1.x)) + (bfhi(u2.x) + bfhi(u3.x));
        a2 += (bflo(u0.y) + bflo(u1.y)) + (bflo(u2.y) + bflo(u3.y));
        a3 += (bfhi(u0.y) + bfhi(u1.y)) + (bfhi(u2.y) + bfhi(u3.y));
        a4 += (bflo(u0.z) + bflo(u1.z)) + (bflo(u2.z) + bflo(u3.z));
        a5 += (bfhi(u0.z) + bfhi(u1.z)) + (bfhi(u2.z) + bfhi(u3.z));
        a6 += (bflo(u0.w) + bflo(u1.w)) + (bflo(u2.w) + bflo(u3.w));
        a7 += (bfhi(u0.w) + bfhi(u1.w)) + (bfhi(u2.w) + bfhi(u3.w));
    }
    for (; j < end; ++j) {
        int e = sorted[j];
        uint4 u = *(const uint4*)(Yb + (((unsigned)e << 7) + co));
        a0 += bflo(u.x); a1 += bfhi(u.x);
        a2 += bflo(u.y); a3 += bfhi(u.y);
        a4 += bflo(u.z); a5 += bfhi(u.z);
        a6 += bflo(u.w); a7 += bfhi(u.w);
    }
    float hsv = hs[vid];
    float inv = (hsv > 0.f) ? 1.f / hsv : 0.f;
    uint4 xu = *(const uint4*)((const char*)Xpb + (((unsigned)vid << 7) + co));
    float r0 = bflo(xu.x) + a0 * inv, r1 = bfhi(xu.x) + a1 * inv;
    float r2 = bflo(xu.y) + a2 * inv, r3 = bfhi(xu.y) + a3 * inv;
    float r4 = bflo(xu.z) + a4 * inv, r5 = bfhi(xu.z) + a5 * inv;
    float r6 = bflo(xu.w) + a6 * inv, r7 = bfhi(xu.w) + a7 * inv;
    float ss = ((r0 * r0 + r1 * r1) + (r2 * r2 + r3 * r3)) +
               ((r4 * r4 + r5 * r5) + (r6 * r6 + r7 * r7));
    ss += __shfl_xor(ss, 1, 64);        // reduce across the 8-lane group
    ss += __shfl_xor(ss, 2, 64);
    ss += __shfl_xor(ss, 4, 64);
    float rn    = sqrtf(ss);
    float scale = (rn > 0.f) ? 1.f / fmaxf(rn, 1e-30f) : 0.f;
    char* ob = (char*)out + (((unsigned)vid << 8) + (co << 1));
    *(float4*)ob        = make_float4(r0 * scale, r1 * scale, r2 * scale, r3 * scale);
    *(float4*)(ob + 16) = make_float4(r4 * scale, r5 * scale, r6 * scale, r7 * scale);
}

static inline int ceil_bits(int n) {
    int v = n - 1;
    if (v < 1) v = 1;
    int b = 0;
    while ((1 << b) <= v) ++b;
    return b;
}

extern "C" void kernel_launch(void* const* d_in, const int* in_sizes, int n_in,
                              void* d_out, int out_size, void* d_ws, size_t ws_size,
                              hipStream_t stream) {
    const void* X      = d_in[0];
    const void* W      = d_in[1];
    const void* homo   = d_in[2];
    const void* vertex = d_in[3];
    const void* edges  = d_in[4];
    float* out = (float*)d_out;

    const int N   = in_sizes[0] / 64;
    const int E   = in_sizes[2];
    const int NNZ = in_sizes[3];
    const int M   = E + N;

    const int NBE = (E + (1 << SE_LOG) - 1) >> SE_LOG;
    const int NBV = (N + (1 << SV_LOG) - 1) >> SV_LOG;
    const int NBT = NBE + NBV;
    const int GC  = (NNZ + CH - 1) / CH;
    const int SST = (NBE > NBV ? NBE : NBV);      // slab stride
    const int bitsN = ceil_bits(N);
    const int bitsE = ceil_bits(E);
    const int G   = (M + 2047) / 2048;  // fallback scan tiles

    char*  ws = (char*)d_ws;
    size_t o  = 0;
    auto alloc = [&](size_t bytes) -> void* {
        void* p = ws + o;
        o += (bytes + 255) & ~(size_t)255;
        return p;
    };
    int*            flags = (int*)alloc(2 * 4);
    int*            off   = (int*)alloc((size_t)(M + 1) * 4);
    int*            bbase = (int*)alloc((size_t)(NBT + 1) * 4);
    int*            bcur  = (int*)alloc((size_t)NBT * 4);
    int*            btot  = (int*)alloc((size_t)NBT * 4);
    float*          homof = (float*)alloc((size_t)E * 4);
    float*          hs    = (float*)alloc((size_t)N * 4);
    int*            buck  = (int*)alloc((size_t)2 * NNZ * 4);
    int*            sorted= (int*)alloc((size_t)2 * NNZ * 4);
    unsigned short* Xpb   = (unsigned short*)alloc((size_t)N * 64 * 2);
    unsigned short* Ye    = (unsigned short*)alloc((size_t)E * 64 * 2);
    int*            slabc = (int*)alloc((size_t)2 * GC * SST * 4);
    size_t o_common = o;
    bool fast = (o <= ws_size) && NBE <= MAXB && NBV <= MAXB &&
                (SE_LOG + bitsN <= 32) && (SV_LOG + bitsE <= 32) && G <= 1024;
    (void)n_in; (void)out_size;

    sniff_kernel<<<1, 64, 0, stream>>>(X, vertex, flags);
    homof_kernel<<<(E + 255) / 256, 256, 0, stream>>>(homo, flags, homof, E);
    gemm_kernel<<<512, 256, 0, stream>>>(X, W, flags, Xpb, N);

    if (fast) {
        hipMemsetAsync(btot, 0, (size_t)NBT * 4, stream);
        bhist_kernel<<<2 * GC, 1024, 0, stream>>>(edges, vertex, flags, btot,
                                                  slabc, SST, NNZ, NBE, NBV, GC);
        bscan_kernel<<<1, 1024, 0, stream>>>(btot, bbase, bcur, NBT);
        bscatter_kernel<<<2 * GC, 1024, 0, stream>>>(edges, vertex, flags, bcur,
                                                     slabc, SST, buck, NNZ,
                                                     NBE, NBV, GC, bitsN, bitsE);
        bfinal_kernel<<<NBT, 1024, 0, stream>>>(buck, bbase, homof, off, sorted,
                                                hs, NBE, NBV, E, N, bitsN, bitsE);
    } else {
        o = o_common;
        int* tot  = (int*)alloc((size_t)M * 4);
        int* part = (int*)alloc((size_t)(G + 1) * 4);
        int* cur  = (int*)alloc((size_t)M * 4);
        hipMemsetAsync(tot, 0, (size_t)M * 4, stream);
        int nb = (NNZ + 255) / 256;
        hist_atomic_kernel<<<nb, 256, 0, stream>>>(edges, vertex, flags, tot, E, NNZ);
        scan_part_kernel<<<G, 256, 0, stream>>>(tot, part, M);
        scan_root_kernel<<<1, 1024, 0, stream>>>(part, G, off, M);
        scan_apply_kernel<<<G, 256, 0, stream>>>(tot, part, off, M);
        copy_kernel<<<(M + 255) / 256, 256, 0, stream>>>(off, cur, M);
        scatter_atomic_kernel<<<nb, 256, 0, stream>>>(edges, vertex, flags, cur, sorted, E, NNZ);
        hs_fallback_kernel<<<(N + 255) / 256, 256, 0, stream>>>(off, sorted, homof, hs, E, N);
    }

    edge_mean_kernel<<<(E + 3) / 4, 256, 0, stream>>>(Xpb, off, sorted, homof, Ye, E);
    int vwaves  = (N + 7) / 8;
    int vblocks = (vwaves * 64 + 255) / 256;
    vertex_out_kernel<<<vblocks, 256, 0, stream>>>(Xpb, Ye, off, sorted,
                                                   hs, out, E, N);
}

// Round 12
// 253.976 us; speedup vs baseline: 2.1289x; 1.0428x over previous
//
#include <hip/hip_runtime.h>
#include <hip/hip_bf16.h>

// Hypergraph conv:  Xp = X@W;  Xe = mean_{v in e} Xp[v];
// Xv[v] = (sum_{e ∋ v} homo[e]*Xe[e]) / (sum_{e ∋ v} homo[e]);  out = rowL2norm(Xp+Xv)
//
// R11 counters: gemm 46us @ VALU 23%, occ 18% -> latency-bound VALU GEMM.
// R12: MFMA gemm (bf16 path): wave-per-16-rows, A frags from global
// (A[m=lane&15][k=quad*8+j]), W B-frags in regs, 8 mfma_f32_16x16x32_bf16 per
// tile, D re-tiled via per-wave LDS -> coalesced bf16 row stores. f32-input
// fallback keeps the old VALU gemm (device-side flag branch, both launched).

#define SE_LOG 6          // edges per bucket = 64
#define SV_LOG 8          // vertices per bucket = 256
#define MAXB   2048       // max coarse buckets per side (LDS counters)
#define CH     8192       // incidences per pass-1 block

typedef __attribute__((ext_vector_type(8))) short bf16x8;
typedef __attribute__((ext_vector_type(4))) float f32x4;

__device__ __forceinline__ float bf2f(unsigned short u) {
    union { unsigned int i; float f; } x;
    x.i = ((unsigned int)u) << 16;
    return x.f;
}

__device__ __forceinline__ float bflo(unsigned int u) {
    union { unsigned int i; float f; } x;
    x.i = u << 16;
    return x.f;
}

__device__ __forceinline__ float bfhi(unsigned int u) {
    union { unsigned int i; float f; } x;
    x.i = u & 0xffff0000u;
    return x.f;
}

__device__ __forceinline__ unsigned short f2bf(float f) {
    union { unsigned int i; float ff; } x;
    x.ff = f;
    unsigned int r = x.i + 0x7fff + ((x.i >> 16) & 1);
    return (unsigned short)(r >> 16);
}

__device__ __forceinline__ float loadF(const void* p, size_t i, int bf16mode) {
    return bf16mode ? bf2f(((const unsigned short*)p)[i]) : ((const float*)p)[i];
}

__device__ __forceinline__ int loadI(const void* p, size_t i, int i64mode) {
    return i64mode ? ((const int*)p)[2 * i] : ((const int*)p)[i];
}

// ---------------- dtype sniff: flags[0]=floats-are-bf16, flags[1]=indices-are-i64
__global__ void sniff_kernel(const void* X, const void* vtx, int* flags) {
    if (threadIdx.x != 0 || blockIdx.x != 0) return;
    const unsigned short* u = (const unsigned short*)X;
    int sane = 0;
    for (int i = 0; i < 64; ++i) {
        unsigned short lo = u[2 * i];
        int e = (lo >> 7) & 0xFF;
        if (e >= 110 && e <= 137) ++sane;
    }
    flags[0] = (sane >= 32) ? 1 : 0;
    const int* w = (const int*)vtx;
    int zeros = 0;
    for (int i = 0; i < 64; ++i)
        if (w[2 * i + 1] == 0) ++zeros;
    flags[1] = (zeros >= 32) ? 1 : 0;
}

// ---------------- homo -> f32 -------------------------------------------------
__global__ void homof_kernel(const void* __restrict__ homo,
                             const int* __restrict__ flags,
                             float* __restrict__ homof, int E) {
    int i = blockIdx.x * blockDim.x + threadIdx.x;
    if (i < E) homof[i] = loadF(homo, i, flags[0]);
}

// ---------------- MFMA GEMM (bf16 inputs): Xpb = bf16(X @ W) ------------------
__global__ __launch_bounds__(256)
void gemm_mfma_kernel(const unsigned short* __restrict__ X,
                      const unsigned short* __restrict__ W,
                      const int* __restrict__ flags,
                      unsigned short* __restrict__ Xpb, int N) {
    if (flags[0] == 0) return;          // f32 inputs: gemm_f32_kernel handles
    __shared__ float Ld[4][16 * 68];    // per-wave D staging, row stride 68
    int tid  = threadIdx.x;
    int lane = tid & 63, w = tid >> 6;
    int quad = lane >> 4, c16 = lane & 15;
    // B fragments: b[t][s][j] = W[k = s*32+quad*8+j][n = t*16+c16]
    bf16x8 bfrag[4][2];
#pragma unroll
    for (int t = 0; t < 4; ++t)
#pragma unroll
        for (int s = 0; s < 2; ++s)
#pragma unroll
            for (int j = 0; j < 8; ++j)
                bfrag[t][s][j] = (short)W[(s * 32 + quad * 8 + j) * 64 + t * 16 + c16];

    int tiles = (N + 15) >> 4;
    int wid = blockIdx.x * 4 + w;
    int nw  = gridDim.x * 4;
    int lr = lane >> 2, seg = lane & 3;  // writeback mapping: row lr, 16-col seg
    for (int tile = wid; tile < tiles; tile += nw) {
        int r0 = tile * 16;
        int rA = r0 + c16; if (rA > N - 1) rA = N - 1;   // clamped A-row
        // A fragments: a_s[j] = X[rA][s*32 + quad*8 + j]
        bf16x8 a0 = *(const bf16x8*)(X + (size_t)rA * 64 + quad * 8);
        bf16x8 a1 = *(const bf16x8*)(X + (size_t)rA * 64 + 32 + quad * 8);
#pragma unroll
        for (int t = 0; t < 4; ++t) {
            f32x4 z = {0.f, 0.f, 0.f, 0.f};
            z = __builtin_amdgcn_mfma_f32_16x16x32_bf16(a0, bfrag[t][0], z, 0, 0, 0);
            z = __builtin_amdgcn_mfma_f32_16x16x32_bf16(a1, bfrag[t][1], z, 0, 0, 0);
            // D: row = quad*4+i, col = t*16+c16
#pragma unroll
            for (int i = 0; i < 4; ++i)
                Ld[w][(quad * 4 + i) * 68 + t * 16 + c16] = z[i];
        }
        // same wave reads back its own region (compiler inserts lgkmcnt wait)
        int r = r0 + lr;
        if (r < N) {
            const float* src = &Ld[w][lr * 68 + seg * 16];
            unsigned int p[8];
#pragma unroll
            for (int i = 0; i < 8; ++i)
                p[i] = (unsigned)f2bf(src[2 * i]) | ((unsigned)f2bf(src[2 * i + 1]) << 16);
            uint4* dst = (uint4*)(Xpb + (size_t)r * 64 + seg * 16);
            dst[0] = make_uint4(p[0], p[1], p[2], p[3]);
            dst[1] = make_uint4(p[4], p[5], p[6], p[7]);
        }
    }
}

// ---------------- VALU GEMM fallback (f32 inputs only) ------------------------
__global__ __launch_bounds__(256)
void gemm_f32_kernel(const void* __restrict__ X, const void* __restrict__ W,
                     const int* __restrict__ flags,
                     unsigned short* __restrict__ Xpb, int N) {
    if (flags[0] == 1) return;          // bf16 inputs: MFMA kernel handles
    __shared__ float Ws[64 * 64];
    __shared__ float Xs[16][64];
    int tid = threadIdx.x;
    for (int j = tid; j < 4096; j += 256) Ws[j] = ((const float*)W)[j];
    __syncthreads();
    int lane = tid & 63, w = tid >> 6;
    int wid = (blockIdx.x * 256 + tid) >> 6;
    int nw  = (gridDim.x * 256) >> 6;
    for (int r0 = wid * 4; r0 < N; r0 += nw * 4) {
        if (r0 + 4 <= N) {
            float acc0 = 0.f, acc1 = 0.f, acc2 = 0.f, acc3 = 0.f;
#pragma unroll
            for (int j = 0; j < 4; ++j)
                Xs[w * 4 + j][lane] = ((const float*)X)[(size_t)(r0 + j) * 64 + lane];
#pragma unroll
            for (int k4 = 0; k4 < 16; ++k4) {
                float4 x0 = *(const float4*)&Xs[w * 4 + 0][k4 * 4];
                float4 x1 = *(const float4*)&Xs[w * 4 + 1][k4 * 4];
                float4 x2 = *(const float4*)&Xs[w * 4 + 2][k4 * 4];
                float4 x3 = *(const float4*)&Xs[w * 4 + 3][k4 * 4];
#pragma unroll
                for (int kk = 0; kk < 4; ++kk) {
                    float wv = Ws[(k4 * 4 + kk) * 64 + lane];
                    acc0 = fmaf((&x0.x)[kk], wv, acc0);
                    acc1 = fmaf((&x1.x)[kk], wv, acc1);
                    acc2 = fmaf((&x2.x)[kk], wv, acc2);
                    acc3 = fmaf((&x3.x)[kk], wv, acc3);
                }
            }
            float a[4] = {acc0, acc1, acc2, acc3};
#pragma unroll
            for (int j = 0; j < 4; ++j)
                Xpb[(size_t)(r0 + j) * 64 + lane] = f2bf(a[j]);
        } else {
            for (int r = r0; r < N; ++r) {
                Xs[w * 4][lane] = ((const float*)X)[(size_t)r * 64 + lane];
                float acc = 0.f;
                for (int k = 0; k < 64; ++k)
                    acc = fmaf(Xs[w * 4][k], Ws[k * 64 + lane], acc);
                Xpb[(size_t)r * 64 + lane] = f2bf(acc);
            }
        }
    }
}

// ------- coarse-bucket histogram; also stores per-(chunk,bucket) counts -------
__global__ __launch_bounds__(1024)
void bhist_kernel(const void* __restrict__ edges, const void* __restrict__ vertex,
                  const int* __restrict__ flags, int* __restrict__ btot,
                  int* __restrict__ slabc, int sstride,
                  int nnz, int NBE, int NBV, int GC) {
    __shared__ int cnt[MAXB];
    int blk  = blockIdx.x;
    int side = (blk >= GC) ? 1 : 0;
    int b    = side ? blk - GC : blk;
    const void* keys = side ? vertex : edges;
    int sblog = side ? SV_LOG : SE_LOG;
    int nb    = side ? NBV : NBE;
    int bas   = side ? NBE : 0;
    int tid = threadIdx.x;
    for (int j = tid; j < nb; j += 1024) cnt[j] = 0;
    __syncthreads();
    int imode = flags[1];
    int c0 = b * CH, c1 = min(nnz, c0 + CH);
    for (int i = c0 + tid; i < c1; i += 1024)
        atomicAdd(&cnt[loadI(keys, i, imode) >> sblog], 1);
    __syncthreads();
    for (int j = tid; j < nb; j += 1024) {
        int c = cnt[j];
        slabc[(size_t)blk * sstride + j] = c;
        if (c) atomicAdd(&btot[bas + j], c);
    }
}

// ---------------- tiny scan over bucket totals -> bases + cursors ------------
__global__ void bscan_kernel(const int* __restrict__ btot, int* __restrict__ bbase,
                             int* __restrict__ bcur, int NBT) {
    __shared__ int wsum[16];
    __shared__ int carry_s;
    int tid = threadIdx.x, lane = tid & 63, w = tid >> 6;
    if (tid == 0) carry_s = 0;
    __syncthreads();
    for (int base = 0; base < NBT; base += 1024) {
        int i = base + tid;
        int x = (i < NBT) ? btot[i] : 0;
        int s = x;
#pragma unroll
        for (int d = 1; d < 64; d <<= 1) {
            int t = __shfl_up(s, d, 64);
            if (lane >= d) s += t;
        }
        if (lane == 63) wsum[w] = s;
        __syncthreads();
        if (w == 0 && lane < 16) {
            int v = wsum[lane];
#pragma unroll
            for (int d = 1; d < 16; d <<= 1) {
                int t = __shfl_up(v, d, 64);
                if (lane >= d) v += t;
            }
            wsum[lane] = v;
        }
        __syncthreads();
        int carry = carry_s;
        int excl  = carry + (w > 0 ? wsum[w - 1] : 0) + s - x;
        if (i < NBT) { bbase[i] = excl; bcur[i] = excl; }
        __syncthreads();
        if (tid == 1023) carry_s = carry + wsum[15];
        __syncthreads();
    }
    if (tid == 0) bbase[NBT] = carry_s;
}

// ------- pass1: chunk -> coarse buckets, packed (local_bin<<psh | payload) ----
__global__ __launch_bounds__(1024)
void bscatter_kernel(const void* __restrict__ edges, const void* __restrict__ vertex,
                     const int* __restrict__ flags, int* __restrict__ bcur,
                     const int* __restrict__ slabc, int sstride,
                     int* __restrict__ buck, int nnz, int NBE, int NBV, int GC,
                     int bitsN, int bitsE) {
    __shared__ int cnt[MAXB];
    __shared__ int gb[MAXB];
    int blk  = blockIdx.x;
    int side = (blk >= GC) ? 1 : 0;
    int b    = side ? blk - GC : blk;
    const void* keys = side ? vertex : edges;
    const void* pay  = side ? edges  : vertex;
    int sblog = side ? SV_LOG : SE_LOG;
    int psh   = side ? bitsE : bitsN;
    int nb    = side ? NBV : NBE;
    int bas   = side ? NBE : 0;
    int tid = threadIdx.x;
    for (int j = tid; j < nb; j += 1024) {
        int c = slabc[(size_t)blk * sstride + j];
        gb[j]  = c ? atomicAdd(&bcur[bas + j], c) : 0;
        cnt[j] = 0;
    }
    __syncthreads();
    int imode = flags[1];
    int c0 = b * CH, c1 = min(nnz, c0 + CH);
    int lmask = (1 << sblog) - 1;
    for (int i = c0 + tid; i < c1; i += 1024) {
        int k   = loadI(keys, i, imode);
        int bkt = k >> sblog;
        int r   = atomicAdd(&cnt[bkt], 1);
        buck[gb[bkt] + r] = ((k & lmask) << psh) | loadI(pay, i, imode);
    }
}

// ------- pass2: one block per bucket -> off[], dest[]; vertex side also hs[] --
__global__ __launch_bounds__(1024)
void bfinal_kernel(const int* __restrict__ buck, const int* __restrict__ bbase,
                   const float* __restrict__ homof,
                   int* __restrict__ off, int* __restrict__ dest,
                   float* __restrict__ hs,
                   int NBE, int NBV, int E, int N, int bitsN, int bitsE) {
    __shared__ int cnt[1 << SV_LOG];
    __shared__ int sexc[1 << SV_LOG];
    __shared__ float hsum[1 << SV_LOG];
    __shared__ int wsum[16];
    int g    = blockIdx.x;
    int side = (g >= NBE) ? 1 : 0;
    int b    = side ? g - NBE : g;
    int sblog = side ? SV_LOG : SE_LOG;
    int psh   = side ? bitsE : bitsN;
    int pmask = (1 << psh) - 1;
    int nside = side ? N : E;
    int bin0  = b << sblog;
    int nbins = min(1 << sblog, nside - bin0);
    int goff0 = (side ? E : 0) + bin0;
    int s0 = bbase[g], s1 = bbase[g + 1], size = s1 - s0;
    int tid = threadIdx.x, lane = tid & 63, w = tid >> 6;
    for (int j = tid; j < nbins; j += 1024) { cnt[j] = 0; hsum[j] = 0.f; }
    __syncthreads();
    for (int j = tid; j < size; j += 1024)
        atomicAdd(&cnt[buck[s0 + j] >> psh], 1);
    __syncthreads();
    {   // exclusive scan over nbins (<= 256 < 1024)
        int x = (tid < nbins) ? cnt[tid] : 0;
        int s = x;
#pragma unroll
        for (int d = 1; d < 64; d <<= 1) {
            int t = __shfl_up(s, d, 64);
            if (lane >= d) s += t;
        }
        if (lane == 63) wsum[w] = s;
        __syncthreads();
        if (w == 0 && lane < 16) {
            int v = wsum[lane];
#pragma unroll
            for (int d = 1; d < 16; d <<= 1) {
                int t = __shfl_up(v, d, 64);
                if (lane >= d) v += t;
            }
            wsum[lane] = v;
        }
        __syncthreads();
        int excl = s - x + (w > 0 ? wsum[w - 1] : 0);
        if (tid < nbins) { sexc[tid] = excl; off[goff0 + tid] = s0 + excl; }
    }
    if (side == 1 && b == NBV - 1 && tid == 0) off[E + N] = s1;
    __syncthreads();
    for (int j = tid; j < nbins; j += 1024) cnt[j] = sexc[j];
    __syncthreads();
    if (side == 1) {
        for (int j = tid; j < size; j += 1024) {
            int p  = buck[s0 + j];
            int lb = p >> psh;
            int r  = atomicAdd(&cnt[lb], 1);
            int e  = p & pmask;
            dest[s0 + r] = e;
            atomicAdd(&hsum[lb], homof[e]);
        }
        __syncthreads();
        for (int j = tid; j < nbins; j += 1024) hs[bin0 + j] = hsum[j];
    } else {
        for (int j = tid; j < size; j += 1024) {
            int p = buck[s0 + j];
            int r = atomicAdd(&cnt[p >> psh], 1);
            dest[s0 + r] = p & pmask;
        }
    }
}

// ---------------- fallback (global-atomic) CSR build -------------------------
__global__ void hist_atomic_kernel(const void* __restrict__ edges,
                                   const void* __restrict__ vertex,
                                   const int* __restrict__ flags,
                                   int* __restrict__ tot, int E, int nnz) {
    int i = blockIdx.x * blockDim.x + threadIdx.x;
    if (i >= nnz) return;
    int imode = flags[1];
    atomicAdd(&tot[loadI(edges, i, imode)], 1);
    atomicAdd(&tot[E + loadI(vertex, i, imode)], 1);
}

__global__ void scan_part_kernel(const int* __restrict__ tot, int* __restrict__ part, int M) {
    int g = blockIdx.x, tid = threadIdx.x;
    int base = g * 2048;
    int sum = 0;
    for (int j = tid; j < 2048; j += 256) {
        int i = base + j;
        sum += (i < M) ? tot[i] : 0;
    }
#pragma unroll
    for (int d = 32; d >= 1; d >>= 1) sum += __shfl_xor(sum, d, 64);
    __shared__ int wsums[4];
    int lane = tid & 63, w = tid >> 6;
    if (lane == 0) wsums[w] = sum;
    __syncthreads();
    if (tid == 0) part[g] = wsums[0] + wsums[1] + wsums[2] + wsums[3];
}

__global__ void scan_root_kernel(int* __restrict__ part, int G,
                                 int* __restrict__ off, int M) {
    int tid = threadIdx.x, lane = tid & 63, w = tid >> 6;
    int x = (tid < G) ? part[tid] : 0;
    int s = x;
#pragma unroll
    for (int d = 1; d < 64; d <<= 1) {
        int t = __shfl_up(s, d, 64);
        if (lane >= d) s += t;
    }
    __shared__ int ws[16];
    if (lane == 63) ws[w] = s;
    __syncthreads();
    if (w == 0 && lane < 16) {
        int v = ws[lane];
#pragma unroll
        for (int d = 1; d < 16; d <<= 1) {
            int t = __shfl_up(v, d, 64);
            if (lane >= d) v += t;
        }
        ws[lane] = v;
    }
    __syncthreads();
    int excl = s - x + (w > 0 ? ws[w - 1] : 0);
    if (tid < G) part[tid] = excl;
    if (tid == 1023) off[M] = ws[15];
}

__global__ void scan_apply_kernel(int* __restrict__ tot, const int* __restrict__ part,
                                  int* __restrict__ off, int M) {
    int g = blockIdx.x, tid = threadIdx.x, lane = tid & 63, w = tid >> 6;
    int base = g * 2048 + tid * 8;
    int e[8]; int s = 0;
#pragma unroll
    for (int j = 0; j < 8; ++j) {
        int i = base + j;
        e[j] = (i < M) ? tot[i] : 0;
        s += e[j];
    }
    int si = s;
#pragma unroll
    for (int d = 1; d < 64; d <<= 1) {
        int t = __shfl_up(si, d, 64);
        if (lane >= d) si += t;
    }
    __shared__ int wsum[4];
    if (lane == 63) wsum[w] = si;
    __syncthreads();
    int wbase = 0;
    for (int ww = 0; ww < w; ++ww) wbase += wsum[ww];
    int run = part[g] + wbase + si - s;
#pragma unroll
    for (int j = 0; j < 8; ++j) {
        int i = base + j;
        if (i < M) off[i] = run;
        run += e[j];
    }
}

__global__ void copy_kernel(const int* __restrict__ src, int* __restrict__ dst, int n) {
    int i = blockIdx.x * blockDim.x + threadIdx.x;
    if (i < n) dst[i] = src[i];
}

__global__ void scatter_atomic_kernel(const void* __restrict__ edges,
                                      const void* __restrict__ vertex,
                                      const int* __restrict__ flags,
                                      int* __restrict__ cur, int* __restrict__ dest,
                                      int E, int nnz) {
    int i = blockIdx.x * blockDim.x + threadIdx.x;
    if (i >= nnz) return;
    int imode = flags[1];
    int e = loadI(edges, i, imode);
    int v = loadI(vertex, i, imode);
    dest[atomicAdd(&cur[e], 1)]     = v;
    dest[atomicAdd(&cur[E + v], 1)] = e;
}

__global__ void hs_fallback_kernel(const int* __restrict__ off,
                                   const int* __restrict__ sorted,
                                   const float* __restrict__ homof,
                                   float* __restrict__ hs, int E, int N) {
    int v = blockIdx.x * blockDim.x + threadIdx.x;
    if (v >= N) return;
    int s = off[E + v], e = off[E + v + 1];
    float t = 0.f;
    for (int j = s; j < e; ++j) t += homof[sorted[j]];
    hs[v] = t;
}

// -- Ye[e,:] = homo[e] * mean_{v in e} Xpb[v,:]   (4 groups x 16, unroll x4) --
__global__ void edge_mean_kernel(const unsigned short* __restrict__ Xpb,
                                 const int* __restrict__ off,
                                 const int* __restrict__ sorted,
                                 const float* __restrict__ homof,
                                 unsigned short* __restrict__ Ye, int E) {
    int wid  = (blockIdx.x * blockDim.x + threadIdx.x) >> 6;
    int lane = threadIdx.x & 63;
    if (wid >= E) return;
    int g = lane >> 4, c = lane & 15;
    unsigned co = (unsigned)c << 3;
    int start = off[wid], end = off[wid + 1];
    float a0 = 0.f, a1 = 0.f, a2 = 0.f, a3 = 0.f;
    const char* Xb = (const char*)Xpb;
    int j = start + g;
    for (; j + 12 < end; j += 16) {      // four independent chains in flight
        int v0 = sorted[j];
        int v1 = sorted[j + 4];
        int v2 = sorted[j + 8];
        int v3 = sorted[j + 12];
        uint2 u0 = *(const uint2*)(Xb + (((unsigned)v0 << 7) + co));
        uint2 u1 = *(const uint2*)(Xb + (((unsigned)v1 << 7) + co));
        uint2 u2 = *(const uint2*)(Xb + (((unsigned)v2 << 7) + co));
        uint2 u3 = *(const uint2*)(Xb + (((unsigned)v3 << 7) + co));
        a0 += (bflo(u0.x) + bflo(u1.x)) + (bflo(u2.x) + bflo(u3.x));
        a1 += (bfhi(u0.x) + bfhi(u1.x)) + (bfhi(u2.x) + bfhi(u3.x));
        a2 += (bflo(u0.y) + bflo(u1.y)) + (bflo(u2.y) + bflo(u3.y));
        a3 += (bfhi(u0.y) + bfhi(u1.y)) + (bfhi(u2.y) + bfhi(u3.y));
    }
    for (; j < end; j += 4) {
        int v = sorted[j];
        uint2 u = *(const uint2*)(Xb + (((unsigned)v << 7) + co));
        a0 += bflo(u.x); a1 += bfhi(u.x);
        a2 += bflo(u.y); a3 += bfhi(u.y);
    }
    a0 += __shfl_xor(a0, 16, 64); a0 += __shfl_xor(a0, 32, 64);
    a1 += __shfl_xor(a1, 16, 64); a1 += __shfl_xor(a1, 32, 64);
    a2 += __shfl_xor(a2, 16, 64); a2 += __shfl_xor(a2, 32, 64);
    a3 += __shfl_xor(a3, 16, 64); a3 += __shfl_xor(a3, 32, 64);
    if (g == 0) {
        float inv = homof[wid] / fmaxf((float)(end - start), 1.f);
        unsigned p0 = (unsigned)f2bf(a0 * inv) | ((unsigned)f2bf(a1 * inv) << 16);
        unsigned p1 = (unsigned)f2bf(a2 * inv) | ((unsigned)f2bf(a3 * inv) << 16);
        *(uint2*)((char*)Ye + (((unsigned)wid << 7) + co)) = make_uint2(p0, p1);
    }
}

// -- out[v,:] = rowL2norm( Xpb + (sum Ye)/hs[v] )
//    8 groups x 8 lanes, GROUP-PER-VERTEX, uint4 row loads, unroll x4 ---------
__global__ void vertex_out_kernel(const unsigned short* __restrict__ Xpb,
                                  const unsigned short* __restrict__ Ye,
                                  const int* __restrict__ off,
                                  const int* __restrict__ sorted,
                                  const float* __restrict__ hs,
                                  float* __restrict__ out, int E, int N) {
    int wv   = (blockIdx.x * blockDim.x + threadIdx.x) >> 6;
    int lane = threadIdx.x & 63;
    int g = lane >> 3, c = lane & 7;
    int vid = wv * 8 + g;
    if (vid >= N) return;               // per-group exit via exec mask
    unsigned co = (unsigned)c << 4;     // 16 B per lane (8 bf16 channels)
    int start = off[E + vid], end = off[E + vid + 1];
    float a0 = 0.f, a1 = 0.f, a2 = 0.f, a3 = 0.f;
    float a4 = 0.f, a5 = 0.f, a6 = 0.f, a7 = 0.f;
    const char* Yb = (const char*)Ye;
    int j = start;
    for (; j + 3 < end; j += 4) {       // four independent chains per group
        int e0 = sorted[j], e1 = sorted[j + 1], e2 = sorted[j + 2], e3 = sorted[j + 3];
        uint4 u0 = *(const uint4*)(Yb + (((unsigned)e0 << 7) + co));
        uint4 u1 = *(const uint4*)(Yb + (((unsigned)e1 << 7) + co));
        uint4 u2 = *(const uint4*)(Yb + (((unsigned)e2 << 7) + co));
        uint4 u3 = *(const uint4*)(Yb + (((unsigned)e3 << 7) + co));
        a0 += (bflo(u0.x) + bflo(u1.x)) + (bflo(u2.x) + bflo(u3.x));
        a1 += (bfhi(u0.x) + bfhi(u1.x)) + (bfhi(u2.x) + bfhi(u3.x));
        a2 += (bflo(u0.y) + bflo(u1.y)) + (bflo(u2.y) + bflo(u3.y));
        a3 += (bfhi(u0.y) + bfhi(u1.y)) + (bfhi(u2.y) + bfhi(u3.y));
        a4 += (bflo(u0.z) + bflo(u1.z)) + (bflo(u2.z) + bflo(u3.z));
        a5 += (bfhi(u0.z) + bfhi(u1.z)) + (bfhi(u2.z) + bfhi(u3.z));
        a6 += (bflo(u0.w) + bflo(u1.w)) + (bflo(u2.w) + bflo(u3.w));
        a7 += (bfhi(u0.w) + bfhi(u1.w)) + (bfhi(u2.w) + bfhi(u3.w));
    }
    for (; j < end; ++j) {
        int e = sorted[j];
        uint4 u = *(const uint4*)(Yb + (((unsigned)e << 7) + co));
        a0 += bflo(u.x); a1 += bfhi(u.x);
        a2 += bflo(u.y); a3 += bfhi(u.y);
        a4 += bflo(u.z); a5 += bfhi(u.z);
        a6 += bflo(u.w); a7 += bfhi(u.w);
    }
    float hsv = hs[vid];
    float inv = (hsv > 0.f) ? 1.f / hsv : 0.f;
    uint4 xu = *(const uint4*)((const char*)Xpb + (((unsigned)vid << 7) + co));
    float r0 = bflo(xu.x) + a0 * inv, r1 = bfhi(xu.x) + a1 * inv;
    float r2 = bflo(xu.y) + a2 * inv, r3 = bfhi(xu.y) + a3 * inv;
    float r4 = bflo(xu.z) + a4 * inv, r5 = bfhi(xu.z) + a5 * inv;
    float r6 = bflo(xu.w) + a6 * inv, r7 = bfhi(xu.w) + a7 * inv;
    float ss = ((r0 * r0 + r1 * r1) + (r2 * r2 + r3 * r3)) +
               ((r4 * r4 + r5 * r5) + (r6 * r6 + r7 * r7));
    ss += __shfl_xor(ss, 1, 64);        // reduce across the 8-lane group
    ss += __shfl_xor(ss, 2, 64);
    ss += __shfl_xor(ss, 4, 64);
    float rn    = sqrtf(ss);
    float scale = (rn > 0.f) ? 1.f / fmaxf(rn, 1e-30f) : 0.f;
    char* ob = (char*)out + (((unsigned)vid << 8) + (co << 1));
    *(float4*)ob        = make_float4(r0 * scale, r1 * scale, r2 * scale, r3 * scale);
    *(float4*)(ob + 16) = make_float4(r4 * scale, r5 * scale, r6 * scale, r7 * scale);
}

static inline int ceil_bits(int n) {
    int v = n - 1;
    if (v < 1) v = 1;
    int b = 0;
    while ((1 << b) <= v) ++b;
    return b;
}

extern "C" void kernel_launch(void* const* d_in, const int* in_sizes, int n_in,
                              void* d_out, int out_size, void* d_ws, size_t ws_size,
                              hipStream_t stream) {
    const void* X      = d_in[0];
    const void* W      = d_in[1];
    const void* homo   = d_in[2];
    const void* vertex = d_in[3];
    const void* edges  = d_in[4];
    float* out = (float*)d_out;

    const int N   = in_sizes[0] / 64;
    const int E   = in_sizes[2];
    const int NNZ = in_sizes[3];
    const int M   = E + N;

    const int NBE = (E + (1 << SE_LOG) - 1) >> SE_LOG;
    const int NBV = (N + (1 << SV_LOG) - 1) >> SV_LOG;
    const int NBT = NBE + NBV;
    const int GC  = (NNZ + CH - 1) / CH;
    const int SST = (NBE > NBV ? NBE : NBV);      // slab stride
    const int bitsN = ceil_bits(N);
    const int bitsE = ceil_bits(E);
    const int G   = (M + 2047) / 2048;  // fallback scan tiles

    char*  ws = (char*)d_ws;
    size_t o  = 0;
    auto alloc = [&](size_t bytes) -> void* {
        void* p = ws + o;
        o += (bytes + 255) & ~(size_t)255;
        return p;
    };
    int*            flags = (int*)alloc(2 * 4);
    int*            off   = (int*)alloc((size_t)(M + 1) * 4);
    int*            bbase = (int*)alloc((size_t)(NBT + 1) * 4);
    int*            bcur  = (int*)alloc((size_t)NBT * 4);
    int*            btot  = (int*)alloc((size_t)NBT * 4);
    float*          homof = (float*)alloc((size_t)E * 4);
    float*          hs    = (float*)alloc((size_t)N * 4);
    int*            buck  = (int*)alloc((size_t)2 * NNZ * 4);
    int*            sorted= (int*)alloc((size_t)2 * NNZ * 4);
    unsigned short* Xpb   = (unsigned short*)alloc((size_t)N * 64 * 2);
    unsigned short* Ye    = (unsigned short*)alloc((size_t)E * 64 * 2);
    int*            slabc = (int*)alloc((size_t)2 * GC * SST * 4);
    size_t o_common = o;
    bool fast = (o <= ws_size) && NBE <= MAXB && NBV <= MAXB &&
                (SE_LOG + bitsN <= 32) && (SV_LOG + bitsE <= 32) && G <= 1024;
    (void)n_in; (void)out_size;

    sniff_kernel<<<1, 64, 0, stream>>>(X, vertex, flags);
    homof_kernel<<<(E + 255) / 256, 256, 0, stream>>>(homo, flags, homof, E);
    // both gemms launched; each early-exits unless its dtype flag matches
    gemm_mfma_kernel<<<1024, 256, 0, stream>>>((const unsigned short*)X,
                                               (const unsigned short*)W,
                                               flags, Xpb, N);
    gemm_f32_kernel<<<512, 256, 0, stream>>>(X, W, flags, Xpb, N);

    if (fast) {
        hipMemsetAsync(btot, 0, (size_t)NBT * 4, stream);
        bhist_kernel<<<2 * GC, 1024, 0, stream>>>(edges, vertex, flags, btot,
                                                  slabc, SST, NNZ, NBE, NBV, GC);
        bscan_kernel<<<1, 1024, 0, stream>>>(btot, bbase, bcur, NBT);
        bscatter_kernel<<<2 * GC, 1024, 0, stream>>>(edges, vertex, flags, bcur,
                                                     slabc, SST, buck, NNZ,
                                                     NBE, NBV, GC, bitsN, bitsE);
        bfinal_kernel<<<NBT, 1024, 0, stream>>>(buck, bbase, homof, off, sorted,
                                                hs, NBE, NBV, E, N, bitsN, bitsE);
    } else {
        o = o_common;
        int* tot  = (int*)alloc((size_t)M * 4);
        int* part = (int*)alloc((size_t)(G + 1) * 4);
        int* cur  = (int*)alloc((size_t)M * 4);
        hipMemsetAsync(tot, 0, (size_t)M * 4, stream);
        int nb = (NNZ + 255) / 256;
        hist_atomic_kernel<<<nb, 256, 0, stream>>>(edges, vertex, flags, tot, E, NNZ);
        scan_part_kernel<<<G, 256, 0, stream>>>(tot, part, M);
        scan_root_kernel<<<1, 1024, 0, stream>>>(part, G, off, M);
        scan_apply_kernel<<<G, 256, 0, stream>>>(tot, part, off, M);
        copy_kernel<<<(M + 255) / 256, 256, 0, stream>>>(off, cur, M);
        scatter_atomic_kernel<<<nb, 256, 0, stream>>>(edges, vertex, flags, cur, sorted, E, NNZ);
        hs_fallback_kernel<<<(N + 255) / 256, 256, 0, stream>>>(off, sorted, homof, hs, E, N);
    }

    edge_mean_kernel<<<(E + 3) / 4, 256, 0, stream>>>(Xpb, off, sorted, homof, Ye, E);
    int vwaves  = (N + 7) / 8;
    int vblocks = (vwaves * 64 + 255) / 256;
    vertex_out_kernel<<<vblocks, 256, 0, stream>>>(Xpb, Ye, off, sorted,
                                                   hs, out, E, N);
}

// Round 13
// 245.682 us; speedup vs baseline: 2.2008x; 1.0338x over previous
//
#include <hip/hip_runtime.h>
#include <hip/hip_bf16.h>

// Hypergraph conv:  Xp = X@W;  Xe = mean_{v in e} Xp[v];
// Xv[v] = (sum_{e ∋ v} homo[e]*Xe[e]) / (sum_{e ∋ v} homo[e]);  out = rowL2norm(Xp+Xv)
//
// R12: top-5 is now harness poison fill; kernels all <43us. R13: fuse gathers
// into bucket pass-2 (bucket payload ~20KB fits LDS): bfe computes Ye rows,
// bfv computes final output, directly from LDS-sorted buckets. sorted/off/hs
// global arrays deleted from fast path. bhist/bscatter do both sides in one
// data pass. Fallback path keeps old (verified) kernels.

#define SE_LOG 6          // edges per bucket = 64
#define SV_LOG 8          // vertices per bucket = 256
#define CH     4096       // incidences per chunk block (both sides)
#define CAPB   12288      // LDS payload capacity (48 KB); avg ~5120, spill else

typedef __attribute__((ext_vector_type(8))) short bf16x8;
typedef __attribute__((ext_vector_type(4))) float f32x4;

__device__ __forceinline__ float bf2f(unsigned short u) {
    union { unsigned int i; float f; } x;
    x.i = ((unsigned int)u) << 16;
    return x.f;
}

__device__ __forceinline__ float bflo(unsigned int u) {
    union { unsigned int i; float f; } x;
    x.i = u << 16;
    return x.f;
}

__device__ __forceinline__ float bfhi(unsigned int u) {
    union { unsigned int i; float f; } x;
    x.i = u & 0xffff0000u;
    return x.f;
}

__device__ __forceinline__ unsigned short f2bf(float f) {
    union { unsigned int i; float ff; } x;
    x.ff = f;
    unsigned int r = x.i + 0x7fff + ((x.i >> 16) & 1);
    return (unsigned short)(r >> 16);
}

__device__ __forceinline__ float loadF(const void* p, size_t i, int bf16mode) {
    return bf16mode ? bf2f(((const unsigned short*)p)[i]) : ((const float*)p)[i];
}

__device__ __forceinline__ int loadI(const void* p, size_t i, int i64mode) {
    return i64mode ? ((const int*)p)[2 * i] : ((const int*)p)[i];
}

// ---------------- dtype sniff: flags[0]=floats-are-bf16, flags[1]=indices-are-i64
__global__ void sniff_kernel(const void* X, const void* vtx, int* flags) {
    if (threadIdx.x != 0 || blockIdx.x != 0) return;
    const unsigned short* u = (const unsigned short*)X;
    int sane = 0;
    for (int i = 0; i < 64; ++i) {
        unsigned short lo = u[2 * i];
        int e = (lo >> 7) & 0xFF;
        if (e >= 110 && e <= 137) ++sane;
    }
    flags[0] = (sane >= 32) ? 1 : 0;
    const int* w = (const int*)vtx;
    int zeros = 0;
    for (int i = 0; i < 64; ++i)
        if (w[2 * i + 1] == 0) ++zeros;
    flags[1] = (zeros >= 32) ? 1 : 0;
}

// ---------------- homo -> f32 -------------------------------------------------
__global__ void homof_kernel(const void* __restrict__ homo,
                             const int* __restrict__ flags,
                             float* __restrict__ homof, int E) {
    int i = blockIdx.x * blockDim.x + threadIdx.x;
    if (i < E) homof[i] = loadF(homo, i, flags[0]);
}

// ---------------- MFMA GEMM (bf16 inputs): Xpb = bf16(X @ W) ------------------
__global__ __launch_bounds__(256)
void gemm_mfma_kernel(const unsigned short* __restrict__ X,
                      const unsigned short* __restrict__ W,
                      const int* __restrict__ flags,
                      unsigned short* __restrict__ Xpb, int N) {
    if (flags[0] == 0) return;
    __shared__ float Ld[4][16 * 68];
    int tid  = threadIdx.x;
    int lane = tid & 63, w = tid >> 6;
    int quad = lane >> 4, c16 = lane & 15;
    bf16x8 bfrag[4][2];
#pragma unroll
    for (int t = 0; t < 4; ++t)
#pragma unroll
        for (int s = 0; s < 2; ++s)
#pragma unroll
            for (int j = 0; j < 8; ++j)
                bfrag[t][s][j] = (short)W[(s * 32 + quad * 8 + j) * 64 + t * 16 + c16];

    int tiles = (N + 15) >> 4;
    int wid = blockIdx.x * 4 + w;
    int nw  = gridDim.x * 4;
    int lr = lane >> 2, seg = lane & 3;
    for (int tile = wid; tile < tiles; tile += nw) {
        int r0 = tile * 16;
        int rA = r0 + c16; if (rA > N - 1) rA = N - 1;
        bf16x8 a0 = *(const bf16x8*)(X + (size_t)rA * 64 + quad * 8);
        bf16x8 a1 = *(const bf16x8*)(X + (size_t)rA * 64 + 32 + quad * 8);
#pragma unroll
        for (int t = 0; t < 4; ++t) {
            f32x4 z = {0.f, 0.f, 0.f, 0.f};
            z = __builtin_amdgcn_mfma_f32_16x16x32_bf16(a0, bfrag[t][0], z, 0, 0, 0);
            z = __builtin_amdgcn_mfma_f32_16x16x32_bf16(a1, bfrag[t][1], z, 0, 0, 0);
#pragma unroll
            for (int i = 0; i < 4; ++i)
                Ld[w][(quad * 4 + i) * 68 + t * 16 + c16] = z[i];
        }
        int r = r0 + lr;
        if (r < N) {
            const float* src = &Ld[w][lr * 68 + seg * 16];
            unsigned int p[8];
#pragma unroll
            for (int i = 0; i < 8; ++i)
                p[i] = (unsigned)f2bf(src[2 * i]) | ((unsigned)f2bf(src[2 * i + 1]) << 16);
            uint4* dst = (uint4*)(Xpb + (size_t)r * 64 + seg * 16);
            dst[0] = make_uint4(p[0], p[1], p[2], p[3]);
            dst[1] = make_uint4(p[4], p[5], p[6], p[7]);
        }
    }
}

// ---------------- VALU GEMM fallback (f32 inputs only) ------------------------
__global__ __launch_bounds__(256)
void gemm_f32_kernel(const void* __restrict__ X, const void* __restrict__ W,
                     const int* __restrict__ flags,
                     unsigned short* __restrict__ Xpb, int N) {
    if (flags[0] == 1) return;
    __shared__ float Ws[64 * 64];
    __shared__ float Xs[16][64];
    int tid = threadIdx.x;
    for (int j = tid; j < 4096; j += 256) Ws[j] = ((const float*)W)[j];
    __syncthreads();
    int lane = tid & 63, w = tid >> 6;
    int wid = (blockIdx.x * 256 + tid) >> 6;
    int nw  = (gridDim.x * 256) >> 6;
    for (int r0 = wid * 4; r0 < N; r0 += nw * 4) {
        if (r0 + 4 <= N) {
            float acc0 = 0.f, acc1 = 0.f, acc2 = 0.f, acc3 = 0.f;
#pragma unroll
            for (int j = 0; j < 4; ++j)
                Xs[w * 4 + j][lane] = ((const float*)X)[(size_t)(r0 + j) * 64 + lane];
#pragma unroll
            for (int k4 = 0; k4 < 16; ++k4) {
                float4 x0 = *(const float4*)&Xs[w * 4 + 0][k4 * 4];
                float4 x1 = *(const float4*)&Xs[w * 4 + 1][k4 * 4];
                float4 x2 = *(const float4*)&Xs[w * 4 + 2][k4 * 4];
                float4 x3 = *(const float4*)&Xs[w * 4 + 3][k4 * 4];
#pragma unroll
                for (int kk = 0; kk < 4; ++kk) {
                    float wv = Ws[(k4 * 4 + kk) * 64 + lane];
                    acc0 = fmaf((&x0.x)[kk], wv, acc0);
                    acc1 = fmaf((&x1.x)[kk], wv, acc1);
                    acc2 = fmaf((&x2.x)[kk], wv, acc2);
                    acc3 = fmaf((&x3.x)[kk], wv, acc3);
                }
            }
            float a[4] = {acc0, acc1, acc2, acc3};
#pragma unroll
            for (int j = 0; j < 4; ++j)
                Xpb[(size_t)(r0 + j) * 64 + lane] = f2bf(a[j]);
        } else {
            for (int r = r0; r < N; ++r) {
                Xs[w * 4][lane] = ((const float*)X)[(size_t)r * 64 + lane];
                float acc = 0.f;
                for (int k = 0; k < 64; ++k)
                    acc = fmaf(Xs[w * 4][k], Ws[k * 64 + lane], acc);
                Xpb[(size_t)r * 64 + lane] = f2bf(acc);
            }
        }
    }
}

// -------- bhist2: both sides per chunk block; one data pass -------------------
__global__ __launch_bounds__(1024)
void bhist2_kernel(const void* __restrict__ edges, const void* __restrict__ vertex,
                   const int* __restrict__ flags, int* __restrict__ btot,
                   int* __restrict__ slabc, int nnz, int NBE, int NBT) {
    __shared__ int cnt[2048];
    int tid = threadIdx.x, b = blockIdx.x;
    for (int j = tid; j < NBT; j += 1024) cnt[j] = 0;
    __syncthreads();
    int imode = flags[1];
    int c0 = b * CH, c1 = min(nnz, c0 + CH);
    for (int i = c0 + tid; i < c1; i += 1024) {
        int e = loadI(edges, i, imode);
        int v = loadI(vertex, i, imode);
        atomicAdd(&cnt[e >> SE_LOG], 1);
        atomicAdd(&cnt[NBE + (v >> SV_LOG)], 1);
    }
    __syncthreads();
    for (int j = tid; j < NBT; j += 1024) {
        int c = cnt[j];
        slabc[(size_t)b * NBT + j] = c;
        if (c) atomicAdd(&btot[j], c);
    }
}

// ---------------- tiny scan over bucket totals -> bases + cursors ------------
__global__ void bscan_kernel(const int* __restrict__ btot, int* __restrict__ bbase,
                             int* __restrict__ bcur, int NBT) {
    __shared__ int wsum[16];
    __shared__ int carry_s;
    int tid = threadIdx.x, lane = tid & 63, w = tid >> 6;
    if (tid == 0) carry_s = 0;
    __syncthreads();
    for (int base = 0; base < NBT; base += 1024) {
        int i = base + tid;
        int x = (i < NBT) ? btot[i] : 0;
        int s = x;
#pragma unroll
        for (int d = 1; d < 64; d <<= 1) {
            int t = __shfl_up(s, d, 64);
            if (lane >= d) s += t;
        }
        if (lane == 63) wsum[w] = s;
        __syncthreads();
        if (w == 0 && lane < 16) {
            int v = wsum[lane];
#pragma unroll
            for (int d = 1; d < 16; d <<= 1) {
                int t = __shfl_up(v, d, 64);
                if (lane >= d) v += t;
            }
            wsum[lane] = v;
        }
        __syncthreads();
        int carry = carry_s;
        int excl  = carry + (w > 0 ? wsum[w - 1] : 0) + s - x;
        if (i < NBT) { bbase[i] = excl; bcur[i] = excl; }
        __syncthreads();
        if (tid == 1023) carry_s = carry + wsum[15];
        __syncthreads();
    }
    if (tid == 0) bbase[NBT] = carry_s;
}

// -------- bscatter2: both sides per chunk block; one data pass ----------------
__global__ __launch_bounds__(1024)
void bscatter2_kernel(const void* __restrict__ edges, const void* __restrict__ vertex,
                      const int* __restrict__ flags, int* __restrict__ bcur,
                      const int* __restrict__ slabc, int* __restrict__ buck,
                      int nnz, int NBE, int NBT, int bitsN, int bitsE) {
    __shared__ int cnt[2048];
    __shared__ int gb[2048];
    int tid = threadIdx.x, b = blockIdx.x;
    for (int j = tid; j < NBT; j += 1024) {
        int c = slabc[(size_t)b * NBT + j];
        gb[j]  = c ? atomicAdd(&bcur[j], c) : 0;
        cnt[j] = 0;
    }
    __syncthreads();
    int imode = flags[1];
    int c0 = b * CH, c1 = min(nnz, c0 + CH);
    for (int i = c0 + tid; i < c1; i += 1024) {
        int e = loadI(edges, i, imode);
        int v = loadI(vertex, i, imode);
        int be = e >> SE_LOG;
        int r  = atomicAdd(&cnt[be], 1);
        buck[gb[be] + r] = ((e & ((1 << SE_LOG) - 1)) << bitsN) | v;
        int bv = NBE + (v >> SV_LOG);
        int r2 = atomicAdd(&cnt[bv], 1);
        buck[gb[bv] + r2] = ((v & ((1 << SV_LOG) - 1)) << bitsE) | e;
    }
}

// -------- bfe: per edge-bucket: LDS sort -> compute Ye rows directly ----------
__global__ __launch_bounds__(1024)
void bfe_kernel(const int* __restrict__ buck, const int* __restrict__ bbase,
                const float* __restrict__ homof, int* __restrict__ spill,
                const unsigned short* __restrict__ Xpb,
                unsigned short* __restrict__ Ye, int E, int bitsN) {
    __shared__ int list[CAPB];
    __shared__ int cnt[1 << SE_LOG];
    __shared__ int sexc[1 << SE_LOG];
    __shared__ int wsum[16];
    int g = blockIdx.x;
    int bin0 = g << SE_LOG;
    int nbins = min(1 << SE_LOG, E - bin0);
    int s0 = bbase[g], s1 = bbase[g + 1], size = s1 - s0;
    int tid = threadIdx.x, lane = tid & 63, w = tid >> 6;
    bool sp = (size > CAPB);
    int pmask = (1 << bitsN) - 1;
    for (int j = tid; j < nbins; j += 1024) cnt[j] = 0;
    __syncthreads();
    for (int j = tid; j < size; j += 1024)
        atomicAdd(&cnt[buck[s0 + j] >> bitsN], 1);
    __syncthreads();
    {   // exclusive scan over nbins (<= 64)
        int x = (tid < nbins) ? cnt[tid] : 0;
        int s = x;
#pragma unroll
        for (int d = 1; d < 64; d <<= 1) {
            int t = __shfl_up(s, d, 64);
            if (lane >= d) s += t;
        }
        if (lane == 63) wsum[w] = s;
        __syncthreads();
        if (w == 0 && lane < 16) {
            int v = wsum[lane];
#pragma unroll
            for (int d = 1; d < 16; d <<= 1) {
                int t = __shfl_up(v, d, 64);
                if (lane >= d) v += t;
            }
            wsum[lane] = v;
        }
        __syncthreads();
        int excl = s - x + (w > 0 ? wsum[w - 1] : 0);
        if (tid < nbins) sexc[tid] = excl;
    }
    __syncthreads();
    if (tid < nbins) cnt[tid] = sexc[tid];   // cursors
    __syncthreads();
    for (int j = tid; j < size; j += 1024) {
        int p  = buck[s0 + j];
        int lb = p >> bitsN;
        int r  = atomicAdd(&cnt[lb], 1);
        int v  = p & pmask;
        if (sp) spill[s0 + r] = v; else list[r] = v;
    }
    __syncthreads();
    // compute: 64 groups x 16 lanes; group owns one edge; lane owns 4 channels
    int grp = (w << 2) | (lane >> 4);
    int c = lane & 15;
    unsigned co = (unsigned)c << 3;
    if (grp < nbins) {
        int start = sexc[grp], end = cnt[grp];   // cursor == segment end
        const char* Xb = (const char*)Xpb;
        float a0 = 0.f, a1 = 0.f, a2 = 0.f, a3 = 0.f;
        int j = start;
        if (!sp) {
            for (; j + 3 < end; j += 4) {
                int v0 = list[j], v1 = list[j + 1], v2 = list[j + 2], v3 = list[j + 3];
                uint2 u0 = *(const uint2*)(Xb + (((unsigned)v0 << 7) + co));
                uint2 u1 = *(const uint2*)(Xb + (((unsigned)v1 << 7) + co));
                uint2 u2 = *(const uint2*)(Xb + (((unsigned)v2 << 7) + co));
                uint2 u3 = *(const uint2*)(Xb + (((unsigned)v3 << 7) + co));
                a0 += (bflo(u0.x) + bflo(u1.x)) + (bflo(u2.x) + bflo(u3.x));
                a1 += (bfhi(u0.x) + bfhi(u1.x)) + (bfhi(u2.x) + bfhi(u3.x));
                a2 += (bflo(u0.y) + bflo(u1.y)) + (bflo(u2.y) + bflo(u3.y));
                a3 += (bfhi(u0.y) + bfhi(u1.y)) + (bfhi(u2.y) + bfhi(u3.y));
            }
            for (; j < end; ++j) {
                int v = list[j];
                uint2 u = *(const uint2*)(Xb + (((unsigned)v << 7) + co));
                a0 += bflo(u.x); a1 += bfhi(u.x);
                a2 += bflo(u.y); a3 += bfhi(u.y);
            }
        } else {
            for (; j < end; ++j) {
                int v = spill[s0 + j];
                uint2 u = *(const uint2*)(Xb + (((unsigned)v << 7) + co));
                a0 += bflo(u.x); a1 += bfhi(u.x);
                a2 += bflo(u.y); a3 += bfhi(u.y);
            }
        }
        int e = bin0 + grp;
        float inv = homof[e] / fmaxf((float)(end - start), 1.f);
        unsigned p0 = (unsigned)f2bf(a0 * inv) | ((unsigned)f2bf(a1 * inv) << 16);
        unsigned p1 = (unsigned)f2bf(a2 * inv) | ((unsigned)f2bf(a3 * inv) << 16);
        *(uint2*)((char*)Ye + (((unsigned)e << 7) + co)) = make_uint2(p0, p1);
    }
}

// -------- bfv: per vertex-bucket: LDS sort -> final output rows ---------------
__global__ __launch_bounds__(1024)
void bfv_kernel(const int* __restrict__ buck, const int* __restrict__ bbase,
                const float* __restrict__ homof, int* __restrict__ spill,
                const unsigned short* __restrict__ Xpb,
                const unsigned short* __restrict__ Ye,
                float* __restrict__ out, int N, int NBE, int bitsE) {
    __shared__ int list[CAPB];
    __shared__ int cnt[1 << SV_LOG];
    __shared__ int sexc[1 << SV_LOG];
    __shared__ float hsum[1 << SV_LOG];
    __shared__ int wsum[16];
    int bv = blockIdx.x;
    int bin0 = bv << SV_LOG;
    int nbins = min(1 << SV_LOG, N - bin0);
    int s0 = bbase[NBE + bv], s1 = bbase[NBE + bv + 1], size = s1 - s0;
    int tid = threadIdx.x, lane = tid & 63, w = tid >> 6;
    bool sp = (size > CAPB);
    int pmask = (1 << bitsE) - 1;
    for (int j = tid; j < nbins; j += 1024) { cnt[j] = 0; hsum[j] = 0.f; }
    __syncthreads();
    for (int j = tid; j < size; j += 1024)
        atomicAdd(&cnt[buck[s0 + j] >> bitsE], 1);
    __syncthreads();
    {   // exclusive scan over nbins (<= 256)
        int x = (tid < nbins) ? cnt[tid] : 0;
        int s = x;
#pragma unroll
        for (int d = 1; d < 64; d <<= 1) {
            int t = __shfl_up(s, d, 64);
            if (lane >= d) s += t;
        }
        if (lane == 63) wsum[w] = s;
        __syncthreads();
        if (w == 0 && lane < 16) {
            int v = wsum[lane];
#pragma unroll
            for (int d = 1; d < 16; d <<= 1) {
                int t = __shfl_up(v, d, 64);
                if (lane >= d) v += t;
            }
            wsum[lane] = v;
        }
        __syncthreads();
        int excl = s - x + (w > 0 ? wsum[w - 1] : 0);
        if (tid < nbins) sexc[tid] = excl;
    }
    __syncthreads();
    if (tid < nbins) cnt[tid] = sexc[tid];
    __syncthreads();
    for (int j = tid; j < size; j += 1024) {
        int p  = buck[s0 + j];
        int lb = p >> bitsE;
        int r  = atomicAdd(&cnt[lb], 1);
        int e  = p & pmask;
        if (sp) spill[s0 + r] = e; else list[r] = e;
        atomicAdd(&hsum[lb], homof[e]);
    }
    __syncthreads();
    // compute: 128 groups x 8 lanes; group owns vertices grp, grp+128
    int grp = (w << 3) | (lane >> 3);
    int c = lane & 7;
    unsigned co = (unsigned)c << 4;
    const char* Yb = (const char*)Ye;
    for (int vl = grp; vl < nbins; vl += 128) {
        int start = sexc[vl], end = cnt[vl];
        float a0 = 0.f, a1 = 0.f, a2 = 0.f, a3 = 0.f;
        float a4 = 0.f, a5 = 0.f, a6 = 0.f, a7 = 0.f;
        int j = start;
        if (!sp) {
            for (; j + 3 < end; j += 4) {
                int e0 = list[j], e1 = list[j + 1], e2 = list[j + 2], e3 = list[j + 3];
                uint4 u0 = *(const uint4*)(Yb + (((unsigned)e0 << 7) + co));
                uint4 u1 = *(const uint4*)(Yb + (((unsigned)e1 << 7) + co));
                uint4 u2 = *(const uint4*)(Yb + (((unsigned)e2 << 7) + co));
                uint4 u3 = *(const uint4*)(Yb + (((unsigned)e3 << 7) + co));
                a0 += (bflo(u0.x) + bflo(u1.x)) + (bflo(u2.x) + bflo(u3.x));
                a1 += (bfhi(u0.x) + bfhi(u1.x)) + (bfhi(u2.x) + bfhi(u3.x));
                a2 += (bflo(u0.y) + bflo(u1.y)) + (bflo(u2.y) + bflo(u3.y));
                a3 += (bfhi(u0.y) + bfhi(u1.y)) + (bfhi(u2.y) + bfhi(u3.y));
                a4 += (bflo(u0.z) + bflo(u1.z)) + (bflo(u2.z) + bflo(u3.z));
                a5 += (bfhi(u0.z) + bfhi(u1.z)) + (bfhi(u2.z) + bfhi(u3.z));
                a6 += (bflo(u0.w) + bflo(u1.w)) + (bflo(u2.w) + bflo(u3.w));
                a7 += (bfhi(u0.w) + bfhi(u1.w)) + (bfhi(u2.w) + bfhi(u3.w));
            }
            for (; j < end; ++j) {
                int e = list[j];
                uint4 u = *(const uint4*)(Yb + (((unsigned)e << 7) + co));
                a0 += bflo(u.x); a1 += bfhi(u.x);
                a2 += bflo(u.y); a3 += bfhi(u.y);
                a4 += bflo(u.z); a5 += bfhi(u.z);
                a6 += bflo(u.w); a7 += bfhi(u.w);
            }
        } else {
            for (; j < end; ++j) {
                int e = spill[s0 + j];
                uint4 u = *(const uint4*)(Yb + (((unsigned)e << 7) + co));
                a0 += bflo(u.x); a1 += bfhi(u.x);
                a2 += bflo(u.y); a3 += bfhi(u.y);
                a4 += bflo(u.z); a5 += bfhi(u.z);
                a6 += bflo(u.w); a7 += bfhi(u.w);
            }
        }
        int vid = bin0 + vl;
        float hsv = hsum[vl];
        float inv = (hsv > 0.f) ? 1.f / hsv : 0.f;
        uint4 xu = *(const uint4*)((const char*)Xpb + (((unsigned)vid << 7) + co));
        float r0 = bflo(xu.x) + a0 * inv, r1 = bfhi(xu.x) + a1 * inv;
        float r2 = bflo(xu.y) + a2 * inv, r3 = bfhi(xu.y) + a3 * inv;
        float r4 = bflo(xu.z) + a4 * inv, r5 = bfhi(xu.z) + a5 * inv;
        float r6 = bflo(xu.w) + a6 * inv, r7 = bfhi(xu.w) + a7 * inv;
        float ss = ((r0 * r0 + r1 * r1) + (r2 * r2 + r3 * r3)) +
                   ((r4 * r4 + r5 * r5) + (r6 * r6 + r7 * r7));
        ss += __shfl_xor(ss, 1, 64);
        ss += __shfl_xor(ss, 2, 64);
        ss += __shfl_xor(ss, 4, 64);
        float rn    = sqrtf(ss);
        float scale = (rn > 0.f) ? 1.f / fmaxf(rn, 1e-30f) : 0.f;
        char* ob = (char*)out + (((unsigned)vid << 8) + (co << 1));
        *(float4*)ob        = make_float4(r0 * scale, r1 * scale, r2 * scale, r3 * scale);
        *(float4*)(ob + 16) = make_float4(r4 * scale, r5 * scale, r6 * scale, r7 * scale);
    }
}

// ================= fallback path (old, verified kernels) =====================
__global__ void hist_atomic_kernel(const void* __restrict__ edges,
                                   const void* __restrict__ vertex,
                                   const int* __restrict__ flags,
                                   int* __restrict__ tot, int E, int nnz) {
    int i = blockIdx.x * blockDim.x + threadIdx.x;
    if (i >= nnz) return;
    int imode = flags[1];
    atomicAdd(&tot[loadI(edges, i, imode)], 1);
    atomicAdd(&tot[E + loadI(vertex, i, imode)], 1);
}

__global__ void scan_part_kernel(const int* __restrict__ tot, int* __restrict__ part, int M) {
    int g = blockIdx.x, tid = threadIdx.x;
    int base = g * 2048;
    int sum = 0;
    for (int j = tid; j < 2048; j += 256) {
        int i = base + j;
        sum += (i < M) ? tot[i] : 0;
    }
#pragma unroll
    for (int d = 32; d >= 1; d >>= 1) sum += __shfl_xor(sum, d, 64);
    __shared__ int wsums[4];
    int lane = tid & 63, w = tid >> 6;
    if (lane == 0) wsums[w] = sum;
    __syncthreads();
    if (tid == 0) part[g] = wsums[0] + wsums[1] + wsums[2] + wsums[3];
}

__global__ void scan_root_kernel(int* __restrict__ part, int G,
                                 int* __restrict__ off, int M) {
    int tid = threadIdx.x, lane = tid & 63, w = tid >> 6;
    int x = (tid < G) ? part[tid] : 0;
    int s = x;
#pragma unroll
    for (int d = 1; d < 64; d <<= 1) {
        int t = __shfl_up(s, d, 64);
        if (lane >= d) s += t;
    }
    __shared__ int ws[16];
    if (lane == 63) ws[w] = s;
    __syncthreads();
    if (w == 0 && lane < 16) {
        int v = ws[lane];
#pragma unroll
        for (int d = 1; d < 16; d <<= 1) {
            int t = __shfl_up(v, d, 64);
            if (lane >= d) v += t;
        }
        ws[lane] = v;
    }
    __syncthreads();
    int excl = s - x + (w > 0 ? ws[w - 1] : 0);
    if (tid < G) part[tid] = excl;
    if (tid == 1023) off[M] = ws[15];
}

__global__ void scan_apply_kernel(int* __restrict__ tot, const int* __restrict__ part,
                                  int* __restrict__ off, int M) {
    int g = blockIdx.x, tid = threadIdx.x, lane = tid & 63, w = tid >> 6;
    int base = g * 2048 + tid * 8;
    int e[8]; int s = 0;
#pragma unroll
    for (int j = 0; j < 8; ++j) {
        int i = base + j;
        e[j] = (i < M) ? tot[i] : 0;
        s += e[j];
    }
    int si = s;
#pragma unroll
    for (int d = 1; d < 64; d <<= 1) {
        int t = __shfl_up(si, d, 64);
        if (lane >= d) si += t;
    }
    __shared__ int wsum[4];
    if (lane == 63) wsum[w] = si;
    __syncthreads();
    int wbase = 0;
    for (int ww = 0; ww < w; ++ww) wbase += wsum[ww];
    int run = part[g] + wbase + si - s;
#pragma unroll
    for (int j = 0; j < 8; ++j) {
        int i = base + j;
        if (i < M) off[i] = run;
        run += e[j];
    }
}

__global__ void copy_kernel(const int* __restrict__ src, int* __restrict__ dst, int n) {
    int i = blockIdx.x * blockDim.x + threadIdx.x;
    if (i < n) dst[i] = src[i];
}

__global__ void scatter_atomic_kernel(const void* __restrict__ edges,
                                      const void* __restrict__ vertex,
                                      const int* __restrict__ flags,
                                      int* __restrict__ cur, int* __restrict__ dest,
                                      int E, int nnz) {
    int i = blockIdx.x * blockDim.x + threadIdx.x;
    if (i >= nnz) return;
    int imode = flags[1];
    int e = loadI(edges, i, imode);
    int v = loadI(vertex, i, imode);
    dest[atomicAdd(&cur[e], 1)]     = v;
    dest[atomicAdd(&cur[E + v], 1)] = e;
}

__global__ void hs_fallback_kernel(const int* __restrict__ off,
                                   const int* __restrict__ sorted,
                                   const float* __restrict__ homof,
                                   float* __restrict__ hs, int E, int N) {
    int v = blockIdx.x * blockDim.x + threadIdx.x;
    if (v >= N) return;
    int s = off[E + v], e = off[E + v + 1];
    float t = 0.f;
    for (int j = s; j < e; ++j) t += homof[sorted[j]];
    hs[v] = t;
}

__global__ void edge_mean_kernel(const unsigned short* __restrict__ Xpb,
                                 const int* __restrict__ off,
                                 const int* __restrict__ sorted,
                                 const float* __restrict__ homof,
                                 unsigned short* __restrict__ Ye, int E) {
    int wid  = (blockIdx.x * blockDim.x + threadIdx.x) >> 6;
    int lane = threadIdx.x & 63;
    if (wid >= E) return;
    int g = lane >> 4, c = lane & 15;
    unsigned co = (unsigned)c << 3;
    int start = off[wid], end = off[wid + 1];
    float a0 = 0.f, a1 = 0.f, a2 = 0.f, a3 = 0.f;
    const char* Xb = (const char*)Xpb;
    for (int j = start + g; j < end; j += 4) {
        int v = sorted[j];
        uint2 u = *(const uint2*)(Xb + (((unsigned)v << 7) + co));
        a0 += bflo(u.x); a1 += bfhi(u.x);
        a2 += bflo(u.y); a3 += bfhi(u.y);
    }
    a0 += __shfl_xor(a0, 16, 64); a0 += __shfl_xor(a0, 32, 64);
    a1 += __shfl_xor(a1, 16, 64); a1 += __shfl_xor(a1, 32, 64);
    a2 += __shfl_xor(a2, 16, 64); a2 += __shfl_xor(a2, 32, 64);
    a3 += __shfl_xor(a3, 16, 64); a3 += __shfl_xor(a3, 32, 64);
    if (g == 0) {
        float inv = homof[wid] / fmaxf((float)(end - start), 1.f);
        unsigned p0 = (unsigned)f2bf(a0 * inv) | ((unsigned)f2bf(a1 * inv) << 16);
        unsigned p1 = (unsigned)f2bf(a2 * inv) | ((unsigned)f2bf(a3 * inv) << 16);
        *(uint2*)((char*)Ye + (((unsigned)wid << 7) + co)) = make_uint2(p0, p1);
    }
}

__global__ void vertex_out_kernel(const unsigned short* __restrict__ Xpb,
                                  const unsigned short* __restrict__ Ye,
                                  const int* __restrict__ off,
                                  const int* __restrict__ sorted,
                                  const float* __restrict__ hs,
                                  float* __restrict__ out, int E, int N) {
    int wv   = (blockIdx.x * blockDim.x + threadIdx.x) >> 6;
    int lane = threadIdx.x & 63;
    int g = lane >> 3, c = lane & 7;
    int vid = wv * 8 + g;
    if (vid >= N) return;
    unsigned co = (unsigned)c << 4;
    int start = off[E + vid], end = off[E + vid + 1];
    float a0 = 0.f, a1 = 0.f, a2 = 0.f, a3 = 0.f;
    float a4 = 0.f, a5 = 0.f, a6 = 0.f, a7 = 0.f;
    const char* Yb = (const char*)Ye;
    for (int j = start; j < end; ++j) {
        int e = sorted[j];
        uint4 u = *(const uint4*)(Yb + (((unsigned)e << 7) + co));
        a0 += bflo(u.x); a1 += bfhi(u.x);
        a2 += bflo(u.y); a3 += bfhi(u.y);
        a4 += bflo(u.z); a5 += bfhi(u.z);
        a6 += bflo(u.w); a7 += bfhi(u.w);
    }
    float hsv = hs[vid];
    float inv = (hsv > 0.f) ? 1.f / hsv : 0.f;
    uint4 xu = *(const uint4*)((const char*)Xpb + (((unsigned)vid << 7) + co));
    float r0 = bflo(xu.x) + a0 * inv, r1 = bfhi(xu.x) + a1 * inv;
    float r2 = bflo(xu.y) + a2 * inv, r3 = bfhi(xu.y) + a3 * inv;
    float r4 = bflo(xu.z) + a4 * inv, r5 = bfhi(xu.z) + a5 * inv;
    float r6 = bflo(xu.w) + a6 * inv, r7 = bfhi(xu.w) + a7 * inv;
    float ss = ((r0 * r0 + r1 * r1) + (r2 * r2 + r3 * r3)) +
               ((r4 * r4 + r5 * r5) + (r6 * r6 + r7 * r7));
    ss += __shfl_xor(ss, 1, 64);
    ss += __shfl_xor(ss, 2, 64);
    ss += __shfl_xor(ss, 4, 64);
    float rn    = sqrtf(ss);
    float scale = (rn > 0.f) ? 1.f / fmaxf(rn, 1e-30f) : 0.f;
    char* ob = (char*)out + (((unsigned)vid << 8) + (co << 1));
    *(float4*)ob        = make_float4(r0 * scale, r1 * scale, r2 * scale, r3 * scale);
    *(float4*)(ob + 16) = make_float4(r4 * scale, r5 * scale, r6 * scale, r7 * scale);
}

static inline int ceil_bits(int n) {
    int v = n - 1;
    if (v < 1) v = 1;
    int b = 0;
    while ((1 << b) <= v) ++b;
    return b;
}

extern "C" void kernel_launch(void* const* d_in, const int* in_sizes, int n_in,
                              void* d_out, int out_size, void* d_ws, size_t ws_size,
                              hipStream_t stream) {
    const void* X      = d_in[0];
    const void* W      = d_in[1];
    const void* homo   = d_in[2];
    const void* vertex = d_in[3];
    const void* edges  = d_in[4];
    float* out = (float*)d_out;

    const int N   = in_sizes[0] / 64;
    const int E   = in_sizes[2];
    const int NNZ = in_sizes[3];
    const int M   = E + N;

    const int NBE = (E + (1 << SE_LOG) - 1) >> SE_LOG;
    const int NBV = (N + (1 << SV_LOG) - 1) >> SV_LOG;
    const int NBT = NBE + NBV;
    const int GC  = (NNZ + CH - 1) / CH;
    const int bitsN = ceil_bits(N);
    const int bitsE = ceil_bits(E);
    const int G   = (M + 2047) / 2048;  // fallback scan tiles

    char*  ws = (char*)d_ws;
    size_t o  = 0;
    auto alloc = [&](size_t bytes) -> void* {
        void* p = ws + o;
        o += (bytes + 255) & ~(size_t)255;
        return p;
    };
    int*            flags = (int*)alloc(2 * 4);
    int*            bbase = (int*)alloc((size_t)(NBT + 1) * 4);
    int*            bcur  = (int*)alloc((size_t)NBT * 4);
    int*            btot  = (int*)alloc((size_t)NBT * 4);
    float*          homof = (float*)alloc((size_t)E * 4);
    int*            buck  = (int*)alloc((size_t)2 * NNZ * 4);
    int*            spill = (int*)alloc((size_t)2 * NNZ * 4);  // fallback: sorted
    unsigned short* Xpb   = (unsigned short*)alloc((size_t)N * 64 * 2);
    unsigned short* Ye    = (unsigned short*)alloc((size_t)E * 64 * 2);
    int*            slabc = (int*)alloc((size_t)GC * NBT * 4);
    size_t o_common = o;
    bool fast = (o <= ws_size) && NBT <= 2048 &&
                (SE_LOG + bitsN <= 31) && (SV_LOG + bitsE <= 31) && G <= 1024;
    (void)n_in; (void)out_size;

    sniff_kernel<<<1, 64, 0, stream>>>(X, vertex, flags);
    homof_kernel<<<(E + 255) / 256, 256, 0, stream>>>(homo, flags, homof, E);
    gemm_mfma_kernel<<<1024, 256, 0, stream>>>((const unsigned short*)X,
                                               (const unsigned short*)W,
                                               flags, Xpb, N);
    gemm_f32_kernel<<<512, 256, 0, stream>>>(X, W, flags, Xpb, N);

    if (fast) {
        hipMemsetAsync(btot, 0, (size_t)NBT * 4, stream);
        bhist2_kernel<<<GC, 1024, 0, stream>>>(edges, vertex, flags, btot,
                                               slabc, NNZ, NBE, NBT);
        bscan_kernel<<<1, 1024, 0, stream>>>(btot, bbase, bcur, NBT);
        bscatter2_kernel<<<GC, 1024, 0, stream>>>(edges, vertex, flags, bcur,
                                                  slabc, buck, NNZ, NBE, NBT,
                                                  bitsN, bitsE);
        bfe_kernel<<<NBE, 1024, 0, stream>>>(buck, bbase, homof, spill,
                                             Xpb, Ye, E, bitsN);
        bfv_kernel<<<NBV, 1024, 0, stream>>>(buck, bbase, homof, spill,
                                             Xpb, Ye, out, N, NBE, bitsE);
    } else {
        o = o_common;
        int* off  = (int*)alloc((size_t)(M + 1) * 4);
        float* hs = (float*)alloc((size_t)N * 4);
        int* tot  = (int*)alloc((size_t)M * 4);
        int* part = (int*)alloc((size_t)(G + 1) * 4);
        int* cur  = (int*)alloc((size_t)M * 4);
        int* sorted = spill;
        hipMemsetAsync(tot, 0, (size_t)M * 4, stream);
        int nb = (NNZ + 255) / 256;
        hist_atomic_kernel<<<nb, 256, 0, stream>>>(edges, vertex, flags, tot, E, NNZ);
        scan_part_kernel<<<G, 256, 0, stream>>>(tot, part, M);
        scan_root_kernel<<<1, 1024, 0, stream>>>(part, G, off, M);
        scan_apply_kernel<<<G, 256, 0, stream>>>(tot, part, off, M);
        copy_kernel<<<(M + 255) / 256, 256, 0, stream>>>(off, cur, M);
        scatter_atomic_kernel<<<nb, 256, 0, stream>>>(edges, vertex, flags, cur, sorted, E, NNZ);
        hs_fallback_kernel<<<(N + 255) / 256, 256, 0, stream>>>(off, sorted, homof, hs, E, N);
        edge_mean_kernel<<<(E + 3) / 4, 256, 0, stream>>>(Xpb, off, sorted, homof, Ye, E);
        int vwaves  = (N + 7) / 8;
        int vblocks = (vwaves * 64 + 255) / 256;
        vertex_out_kernel<<<vblocks, 256, 0, stream>>>(Xpb, Ye, off, sorted, hs, out, E, N);
    }
}